// Round 1
// baseline (2486.228 us; speedup 1.0000x reference)
//
#include <hip/hip_runtime.h>

#define BATCH 2
#define SEQL 2048
#define DM 1024
#define DSTATE 128
#define HD 64
#define CHUNK 256
#define DI 2048
#define NHEADS 32
#define CONVD 2304
#define DPROJ 4384
#define DFF 4096
#define NC 8
#define ROWS (BATCH*SEQL)

__device__ __forceinline__ float softplus_f(float v){
    return (v > 20.f) ? v : log1pf(expf(v));
}
__device__ __forceinline__ float silu_f(float v){
    return v / (1.f + expf(-v));
}

// ---------------------------------------------------------------- generic GEMM
// C[M,N] = A[M,K] @ B[K,N] + bias ; ACT: 0=none, 1=hardswish
// BM=BN=64, BK=16, 256 threads, 4x4 per thread. M%64==0, K%16==0; N guarded.
template<int ACT>
__global__ __launch_bounds__(256) void gemm_k(const float* __restrict__ A,
                                              const float* __restrict__ Bw,
                                              const float* __restrict__ bias,
                                              float* __restrict__ C,
                                              int M, int N, int K){
    __shared__ float As[64][17];
    __shared__ float Bs[16][64];
    int tid = threadIdx.x;
    int tx = tid & 15, ty = tid >> 4;
    int m0 = blockIdx.y * 64, n0 = blockIdx.x * 64;
    float acc[4][4] = {};
    for (int k0 = 0; k0 < K; k0 += 16){
        #pragma unroll
        for (int i = 0; i < 4; i++){
            int e = tid + i*256;
            int r = e >> 4, cc = e & 15;
            As[r][cc] = A[(size_t)(m0+r)*K + k0 + cc];
        }
        #pragma unroll
        for (int i = 0; i < 4; i++){
            int e = tid + i*256;
            int r = e >> 6, cc = e & 63;
            Bs[r][cc] = (n0+cc < N) ? Bw[(size_t)(k0+r)*N + n0 + cc] : 0.f;
        }
        __syncthreads();
        #pragma unroll
        for (int kk = 0; kk < 16; kk++){
            float a[4], b[4];
            #pragma unroll
            for (int i = 0; i < 4; i++) a[i] = As[ty*4+i][kk];
            #pragma unroll
            for (int j = 0; j < 4; j++) b[j] = Bs[kk][tx*4+j];
            #pragma unroll
            for (int i = 0; i < 4; i++)
                #pragma unroll
                for (int j = 0; j < 4; j++)
                    acc[i][j] += a[i]*b[j];
        }
        __syncthreads();
    }
    #pragma unroll
    for (int i = 0; i < 4; i++){
        int row = m0 + ty*4 + i;
        #pragma unroll
        for (int j = 0; j < 4; j++){
            int col = n0 + tx*4 + j;
            if (col < N){
                float v = acc[i][j] + bias[col];
                if (ACT == 1){
                    float t = v + 3.f;
                    t = fminf(fmaxf(t, 0.f), 6.f);
                    v = v * t * (1.f/6.f);
                }
                C[(size_t)row*N + col] = v;
            }
        }
    }
}

// ------------------------------------------------- depthwise causal conv + SiLU
__global__ __launch_bounds__(256) void conv_silu_k(const float* __restrict__ zx,
                                                   const float* __restrict__ conv_w,
                                                   const float* __restrict__ conv_b,
                                                   float* __restrict__ outp){
    int idx = blockIdx.x*256 + threadIdx.x;       // ROWS*CONVD total
    int c = idx % CONVD;
    int row = idx / CONVD;                        // b*SEQL + t
    int t = row & (SEQL-1);
    float acc = conv_b[c];
    #pragma unroll
    for (int k = 0; k < 4; k++){
        int tt = t + k - 3;
        if (tt >= 0)
            acc += zx[((size_t)(row + k - 3))*DPROJ + DI + c] * conv_w[c*4 + k];
    }
    outp[idx] = silu_f(acc);
}

// --------------------------------- dt = softplus(dt_raw+bias); dA; Acum (chunk cumsum)
__global__ __launch_bounds__(256) void dt_scan_k(const float* __restrict__ zx,
                                                 const float* __restrict__ time_diff,
                                                 const float* __restrict__ A_log,
                                                 const float* __restrict__ dt_bias,
                                                 const float* __restrict__ time_decay,
                                                 float* __restrict__ dt_out,
                                                 float* __restrict__ Acum){
    __shared__ float s[CHUNK];
    int bid = blockIdx.x;                          // b*NHEADS*NC
    int c = bid % NC;
    int h = (bid / NC) % NHEADS;
    int b = bid / (NC*NHEADS);
    int l = threadIdx.x;
    int t = c*CHUNK + l;
    float dtr = zx[((size_t)(b*SEQL + t))*DPROJ + (DPROJ-NHEADS) + h];
    float dtv = softplus_f(dtr + dt_bias[h]);
    float A = -expf(A_log[h]);
    float dA = dtv*A - softplus_f(time_decay[h]) * time_diff[b*SEQL + t];
    dt_out[(size_t)(b*SEQL + t)*NHEADS + h] = dtv;
    s[l] = dA;
    __syncthreads();
    for (int off = 1; off < CHUNK; off <<= 1){
        float v = (l >= off) ? s[l-off] : 0.f;
        __syncthreads();
        s[l] += v;
        __syncthreads();
    }
    Acum[((size_t)(b*NHEADS + h))*SEQL + t] = s[l];
}

// ------------------------------------------------------------------ xdt = xs * dt
__global__ __launch_bounds__(256) void xdt_k(const float* __restrict__ convb,
                                             const float* __restrict__ dt,
                                             float* __restrict__ xdt){
    int idx = blockIdx.x*256 + threadIdx.x;        // ROWS*DI total
    int d = idx & (DI-1);
    int row = idx >> 11;
    int h = d >> 6;
    xdt[idx] = convb[(size_t)row*CONVD + d] * dt[(size_t)row*NHEADS + h];
}

// ------------------------------------------------------- G[b,c,l,s] = C_l . B_s
__global__ __launch_bounds__(256) void g_nt_k(const float* __restrict__ convb,
                                              float* __restrict__ G){
    int bz = blockIdx.z;                   // b*NC + c
    int s0 = blockIdx.x * 64, l0 = blockIdx.y * 64;
    __shared__ float As[64][33];
    __shared__ float Bs[64][33];
    int tid = threadIdx.x;
    int tx = tid & 15, ty = tid >> 4;
    float acc[4][4] = {};
    const float* base = convb + ((size_t)bz*CHUNK)*CONVD;
    for (int k0 = 0; k0 < DSTATE; k0 += 32){
        #pragma unroll
        for (int i = 0; i < 8; i++){
            int e = tid + i*256;
            int r = e >> 5, cc = e & 31;
            As[r][cc] = base[(size_t)(l0+r)*CONVD + (DI+DSTATE) + k0 + cc];  // C rows
            Bs[r][cc] = base[(size_t)(s0+r)*CONVD + DI + k0 + cc];           // B rows
        }
        __syncthreads();
        #pragma unroll
        for (int kk = 0; kk < 32; kk++){
            float a[4], b[4];
            #pragma unroll
            for (int i = 0; i < 4; i++) a[i] = As[ty*4+i][kk];
            #pragma unroll
            for (int j = 0; j < 4; j++) b[j] = Bs[tx*4+j][kk];
            #pragma unroll
            for (int i = 0; i < 4; i++)
                #pragma unroll
                for (int j = 0; j < 4; j++)
                    acc[i][j] += a[i]*b[j];
        }
        __syncthreads();
    }
    float* g = G + (size_t)bz*CHUNK*CHUNK;
    #pragma unroll
    for (int i = 0; i < 4; i++)
        #pragma unroll
        for (int j = 0; j < 4; j++)
            g[(size_t)(l0+ty*4+i)*CHUNK + s0+tx*4+j] = acc[i][j];
}

// --------------- states[b,c,h,p,n] = sum_l B[l,n]*exp(AcL-Ac[l])*xdt[l,p]
__global__ __launch_bounds__(256) void states_k(const float* __restrict__ convb,
                                                const float* __restrict__ xdt,
                                                const float* __restrict__ Acum,
                                                float* __restrict__ states){
    __shared__ float Bt[64*128];
    __shared__ float wx[64*64];
    __shared__ float Acs[CHUNK];
    int bid = blockIdx.x;
    int h = bid % NHEADS;
    int c = (bid / NHEADS) % NC;
    int b = bid / (NHEADS*NC);
    int tid = threadIdx.x;
    const float* AcB = Acum + ((size_t)(b*NHEADS + h))*SEQL + c*CHUNK;
    Acs[tid] = AcB[tid];
    __syncthreads();
    float AcL = Acs[CHUNK-1];
    int tp = tid >> 5, tn = tid & 31;
    float acc[8][4] = {};
    const float* bbase = convb + ((size_t)(b*SEQL + c*CHUNK))*CONVD + DI;
    const float* xbase = xdt + ((size_t)(b*SEQL + c*CHUNK))*DI + h*HD;
    for (int l0 = 0; l0 < CHUNK; l0 += 64){
        #pragma unroll
        for (int i = 0; i < 32; i++){
            int e = tid + i*256; int l = e >> 7, n = e & 127;
            Bt[e] = bbase[(size_t)(l0+l)*CONVD + n];
        }
        #pragma unroll
        for (int i = 0; i < 16; i++){
            int e = tid + i*256; int l = e >> 6, p = e & 63;
            wx[e] = expf(AcL - Acs[l0+l]) * xbase[(size_t)(l0+l)*DI + p];
        }
        __syncthreads();
        for (int l = 0; l < 64; l++){
            float4 bv = ((const float4*)(Bt + l*128))[tn];
            #pragma unroll
            for (int i = 0; i < 8; i++){
                float w = wx[l*64 + tp*8 + i];
                acc[i][0] += w*bv.x; acc[i][1] += w*bv.y;
                acc[i][2] += w*bv.z; acc[i][3] += w*bv.w;
            }
        }
        __syncthreads();
    }
    float* outp = states + ((size_t)((b*NC + c)*NHEADS + h))*(HD*DSTATE);
    #pragma unroll
    for (int i = 0; i < 8; i++)
        #pragma unroll
        for (int j = 0; j < 4; j++)
            outp[(size_t)(tp*8+i)*DSTATE + tn*4 + j] = acc[i][j];
}

// ------------------------- inter-chunk recurrence: prev[c] = scan carry (8 steps)
__global__ __launch_bounds__(256) void prev_scan_k(const float* __restrict__ states,
                                                   const float* __restrict__ Acum,
                                                   float* __restrict__ prev){
    int bid = blockIdx.x;                  // B*NHEADS
    int h = bid % NHEADS, b = bid / NHEADS;
    int tid = threadIdx.x;
    const float* AcB = Acum + ((size_t)(b*NHEADS + h))*SEQL;
    float dec[NC];
    #pragma unroll
    for (int c = 0; c < NC; c++) dec[c] = expf(AcB[c*CHUNK + CHUNK-1]);
    for (int j = 0; j < 32; j++){
        int e = tid + j*256;
        float carry = 0.f;
        #pragma unroll
        for (int c = 0; c < NC; c++){
            size_t idx = ((size_t)((b*NC + c)*NHEADS + h))*(HD*DSTATE) + e;
            prev[idx] = carry;
            carry = carry*dec[c] + states[idx];
        }
    }
}

// ------ fused: Y = Y_off + Y_diag + D*xs, written in place over the xdt buffer
__global__ __launch_bounds__(256) void y_fused_k(const float* __restrict__ convb,
                                                 const float* __restrict__ G,
                                                 const float* __restrict__ Acum,
                                                 const float* __restrict__ prev,
                                                 const float* __restrict__ Dp,
                                                 float* __restrict__ Y){
    __shared__ float prev_s[HD*DSTATE];    // 32 KB
    __shared__ float xdt_s[64*HD];         // 16 KB
    __shared__ float Acs[CHUNK];
    int bid = blockIdx.x;
    int h = bid % NHEADS;
    int c = (bid / NHEADS) % NC;
    int b = bid / (NHEADS*NC);
    int tid = threadIdx.x;
    int l = tid;
    Acs[tid] = Acum[((size_t)(b*NHEADS + h))*SEQL + c*CHUNK + tid];
    {
        const float* pv = prev + ((size_t)((b*NC + c)*NHEADS + h))*(HD*DSTATE);
        #pragma unroll
        for (int i = 0; i < 32; i++) prev_s[tid + i*256] = pv[tid + i*256];
    }
    __syncthreads();
    float4 acc[16];
    #pragma unroll
    for (int q = 0; q < 16; q++) acc[q] = make_float4(0.f,0.f,0.f,0.f);

    int row = b*SEQL + c*CHUNK + l;
    // ---- phase 1: Y_off[l,p] = exp(Ac[l]) * sum_n C[l,n]*prev[p,n]
    {
        const float4* Crow4 = (const float4*)(convb + (size_t)row*CONVD + DI + DSTATE);
        const float4* prev4 = (const float4*)prev_s;
        for (int n4 = 0; n4 < 32; n4++){
            float4 c4 = Crow4[n4];
            #pragma unroll
            for (int q = 0; q < 16; q++){
                float4 p0 = prev4[(q*4+0)*32 + n4];
                float4 p1 = prev4[(q*4+1)*32 + n4];
                float4 p2 = prev4[(q*4+2)*32 + n4];
                float4 p3 = prev4[(q*4+3)*32 + n4];
                acc[q].x += c4.x*p0.x + c4.y*p0.y + c4.z*p0.z + c4.w*p0.w;
                acc[q].y += c4.x*p1.x + c4.y*p1.y + c4.z*p1.z + c4.w*p1.w;
                acc[q].z += c4.x*p2.x + c4.y*p2.y + c4.z*p2.z + c4.w*p2.w;
                acc[q].w += c4.x*p3.x + c4.y*p3.y + c4.z*p3.z + c4.w*p3.w;
            }
        }
        float el = expf(Acs[l]);
        #pragma unroll
        for (int q = 0; q < 16; q++){
            acc[q].x *= el; acc[q].y *= el; acc[q].z *= el; acc[q].w *= el;
        }
    }
    // ---- phase 2: Y_diag[l,p] = sum_{s<=l} G[l,s]*exp(Ac[l]-Ac[s])*xdt[s,p]
    const float* Grow = G + ((size_t)(b*NC + c))*(CHUNK*CHUNK) + (size_t)l*CHUNK;
    const float* xbase = Y + ((size_t)(b*SEQL + c*CHUNK))*DI + h*HD;
    for (int st = 0; st < 4; st++){
        __syncthreads();
        #pragma unroll
        for (int i = 0; i < 16; i++){
            int e = tid + i*256; int ss = e >> 6, p = e & 63;
            xdt_s[e] = xbase[(size_t)(st*64 + ss)*DI + p];
        }
        __syncthreads();
        int s0 = st*64;
        if (l >= s0){
            float Al = Acs[l];
            int send = (l < s0+63) ? l : (s0+63);
            for (int s = s0; s <= send; s++){
                float coef = Grow[s] * expf(Al - Acs[s]);
                const float4* x4 = (const float4*)(xdt_s + (s - s0)*HD);
                #pragma unroll
                for (int q = 0; q < 16; q++){
                    float4 xv = x4[q];
                    acc[q].x += coef*xv.x; acc[q].y += coef*xv.y;
                    acc[q].z += coef*xv.z; acc[q].w += coef*xv.w;
                }
            }
        }
    }
    // ---- phase 3: + D[h]*xs, write (all global reads of region done before last barrier)
    float Dv = Dp[h];
    const float4* xs4 = (const float4*)(convb + (size_t)row*CONVD + h*HD);
    float4* out4 = (float4*)(Y + (size_t)row*DI + h*HD);
    #pragma unroll
    for (int q = 0; q < 16; q++){
        float4 xv = xs4[q];
        float4 r;
        r.x = acc[q].x + Dv*xv.x; r.y = acc[q].y + Dv*xv.y;
        r.z = acc[q].z + Dv*xv.z; r.w = acc[q].w + Dv*xv.w;
        out4[q] = r;
    }
}

// ------------------------------------------- y = Y*silu(z); RMSNorm; * rms_w
__global__ __launch_bounds__(256) void gate_rms_k(const float* __restrict__ Yb,
                                                  const float* __restrict__ zx,
                                                  const float* __restrict__ rms_w,
                                                  float* __restrict__ yn){
    __shared__ float red[4];
    __shared__ float scale_s;
    int row = blockIdx.x; int tid = threadIdx.x;
    float v[8]; float ss = 0.f;
    #pragma unroll
    for (int i = 0; i < 8; i++){
        int d = tid + i*256;
        float g = Yb[(size_t)row*DI + d] * silu_f(zx[(size_t)row*DPROJ + d]);
        v[i] = g; ss += g*g;
    }
    #pragma unroll
    for (int off = 32; off > 0; off >>= 1) ss += __shfl_down(ss, off);
    int lane = tid & 63, wid = tid >> 6;
    if (lane == 0) red[wid] = ss;
    __syncthreads();
    if (tid == 0) scale_s = rsqrtf((red[0]+red[1]+red[2]+red[3])*(1.f/DI) + 1e-12f);
    __syncthreads();
    float sc = scale_s;
    #pragma unroll
    for (int i = 0; i < 8; i++){
        int d = tid + i*256;
        yn[(size_t)row*DI + d] = v[i]*sc*rms_w[d];
    }
}

// ----------------------------------------------- LayerNorm(a + resid)*g + b
__global__ __launch_bounds__(256) void ln_k(const float* __restrict__ a,
                                            const float* __restrict__ resid,
                                            const float* __restrict__ g,
                                            const float* __restrict__ bw,
                                            float* __restrict__ outp){
    __shared__ float redA[4], redB[4];
    __shared__ float mu_s, rs_s;
    int row = blockIdx.x; int tid = threadIdx.x;
    float u[4]; float s = 0.f, s2 = 0.f;
    #pragma unroll
    for (int i = 0; i < 4; i++){
        int d = tid + i*256;
        float val = a[(size_t)row*DM + d] + resid[(size_t)row*DM + d];
        u[i] = val; s += val; s2 += val*val;
    }
    #pragma unroll
    for (int off = 32; off > 0; off >>= 1){
        s  += __shfl_down(s,  off);
        s2 += __shfl_down(s2, off);
    }
    int lane = tid & 63, wid = tid >> 6;
    if (lane == 0){ redA[wid] = s; redB[wid] = s2; }
    __syncthreads();
    if (tid == 0){
        float S  = redA[0]+redA[1]+redA[2]+redA[3];
        float S2 = redB[0]+redB[1]+redB[2]+redB[3];
        float mu = S*(1.f/DM);
        float var = S2*(1.f/DM) - mu*mu;
        mu_s = mu; rs_s = rsqrtf(var + 1e-12f);
    }
    __syncthreads();
    float mu = mu_s, rs = rs_s;
    #pragma unroll
    for (int i = 0; i < 4; i++){
        int d = tid + i*256;
        outp[(size_t)row*DM + d] = (u[i]-mu)*rs*g[d] + bw[d];
    }
}

__global__ __launch_bounds__(256) void copy_td_k(const float* __restrict__ td,
                                                 float* __restrict__ outp){
    int idx = blockIdx.x*256 + threadIdx.x;
    outp[idx] = td[idx];
}

extern "C" void kernel_launch(void* const* d_in, const int* in_sizes, int n_in,
                              void* d_out, int out_size, void* d_ws, size_t ws_size,
                              hipStream_t stream){
    const float* x         = (const float*)d_in[0];
    const float* time_diff = (const float*)d_in[1];
    const float* W_in      = (const float*)d_in[2];
    const float* b_in      = (const float*)d_in[3];
    const float* conv_w    = (const float*)d_in[4];
    const float* conv_b    = (const float*)d_in[5];
    const float* A_log     = (const float*)d_in[6];
    const float* dt_bias   = (const float*)d_in[7];
    const float* Dp        = (const float*)d_in[8];
    const float* time_dec  = (const float*)d_in[9];
    const float* rms_w     = (const float*)d_in[10];
    const float* W_out     = (const float*)d_in[11];
    const float* b_out     = (const float*)d_in[12];
    const float* ln_g      = (const float*)d_in[13];
    const float* ln_b      = (const float*)d_in[14];
    const float* fc1_w     = (const float*)d_in[15];
    const float* fc1_b     = (const float*)d_in[16];
    const float* fc2_w     = (const float*)d_in[17];
    const float* fc2_b     = (const float*)d_in[18];
    const float* ln2_g     = (const float*)d_in[19];
    const float* ln2_b     = (const float*)d_in[20];

    float* ws   = (float*)d_ws;
    float* zx    = ws;                       // 17,956,864 (later: fc1 out "mid")
    float* convb = zx    + 17956864;         //  9,437,184 (later: hidden)
    float* dt    = convb + 9437184;          //    131,072
    float* Acum  = dt    + 131072;           //    131,072
    float* xdt   = Acum  + 131072;           //  8,388,608 (in-place Y)
    float* Gbuf  = xdt   + 8388608;          //  1,048,576 ┐
    float* stat  = Gbuf  + 1048576;          //  4,194,304 ├ later: yn (8.4M), then hid2
    float* prev  = stat  + 4194304;          //  4,194,304 ┘
    float* hbuf  = prev  + 4194304;          //  4,194,304
    // total 49,676,288 floats = ~190 MB
    float* yn     = Gbuf;
    float* hid2   = Gbuf;
    float* mid    = zx;
    float* hidden = convb;
    float* outp   = (float*)d_out;

    // 1. in-proj: zx = x @ W_in + b_in
    gemm_k<0><<<dim3((DPROJ+63)/64, ROWS/64), 256, 0, stream>>>(x, W_in, b_in, zx, ROWS, DPROJ, DM);
    // 2. causal conv + SiLU
    conv_silu_k<<<ROWS*CONVD/256, 256, 0, stream>>>(zx, conv_w, conv_b, convb);
    // 3. dt / dA / per-chunk cumsum
    dt_scan_k<<<BATCH*NHEADS*NC, 256, 0, stream>>>(zx, time_diff, A_log, dt_bias, time_dec, dt, Acum);
    // 4. xdt = xs * dt
    xdt_k<<<ROWS*DI/256, 256, 0, stream>>>(convb, dt, xdt);
    // 5. G = C @ B^T per (b,c)
    g_nt_k<<<dim3(4,4,BATCH*NC), 256, 0, stream>>>(convb, Gbuf);
    // 6. per-chunk states
    states_k<<<BATCH*NC*NHEADS, 256, 0, stream>>>(convb, xdt, Acum, stat);
    // 7. inter-chunk scan
    prev_scan_k<<<BATCH*NHEADS, 256, 0, stream>>>(stat, Acum, prev);
    // 8. fused Y (in place over xdt)
    y_fused_k<<<BATCH*NC*NHEADS, 256, 0, stream>>>(convb, Gbuf, Acum, prev, Dp, xdt);
    // 9. gate + RMSNorm
    gate_rms_k<<<ROWS, 256, 0, stream>>>(xdt, zx, rms_w, yn);
    // 10. out-proj: hidden = yn @ W_out + b_out
    gemm_k<0><<<dim3(DM/64, ROWS/64), 256, 0, stream>>>(yn, W_out, b_out, hidden, ROWS, DM, DI);
    // 11. h = LN(hidden + x)
    ln_k<<<ROWS, 256, 0, stream>>>(hidden, x, ln_g, ln_b, hbuf);
    // 12. fc1 + hardswish
    gemm_k<1><<<dim3(DFF/64, ROWS/64), 256, 0, stream>>>(hbuf, fc1_w, fc1_b, mid, ROWS, DFF, DM);
    // 13. fc2
    gemm_k<0><<<dim3(DM/64, ROWS/64), 256, 0, stream>>>(mid, fc2_w, fc2_b, hid2, ROWS, DM, DFF);
    // 14. out = LN(hid2 + h)
    ln_k<<<ROWS, 256, 0, stream>>>(hid2, hbuf, ln2_g, ln2_b, outp);
    // 15. second tuple output: time_diff passthrough
    copy_td_k<<<ROWS/256, 256, 0, stream>>>(time_diff, outp + (size_t)ROWS*DM);
}

// Round 2
// 742.794 us; speedup vs baseline: 3.3471x; 3.3471x over previous
//
#include <hip/hip_runtime.h>

#define BATCH 2
#define SEQL 2048
#define DM 1024
#define DSTATE 128
#define HD 64
#define CHUNK 256
#define DI 2048
#define NHEADS 32
#define CONVD 2304
#define DPROJ 4384
#define DFF 4096
#define NC 8
#define ROWS (BATCH*SEQL)

typedef unsigned short ushort_t;
typedef short bf16x8 __attribute__((ext_vector_type(8)));
typedef float f32x4 __attribute__((ext_vector_type(4)));

__device__ __forceinline__ float softplus_f(float v){
    return (v > 20.f) ? v : log1pf(expf(v));
}
__device__ __forceinline__ float silu_f(float v){
    return v / (1.f + expf(-v));
}
__device__ __forceinline__ ushort_t f2b(float v){
    union { float f; unsigned int u; } x; x.f = v;
    unsigned int r = x.u + 0x7fffu + ((x.u >> 16) & 1u);
    return (ushort_t)(r >> 16);
}

// ================================================================ MFMA GEMM
// C[M,N] = A[M,K](bf16) @ Bt[N,K](bf16)^T + bias.
// 128x128 tile, BK=64, 4 waves, each wave 64x64 via 4x4 mfma 16x16x32.
// ACT: 0 none, 1 hardswish. OUT_BF16: write Cb (ushort bf16) else Cf (f32).
template<int ACT, int OUT_BF16>
__global__ __launch_bounds__(256) void mfma_gemm_k(
    const ushort_t* __restrict__ A, const ushort_t* __restrict__ Bt,
    const float* __restrict__ bias, float* __restrict__ Cf,
    ushort_t* __restrict__ Cb, int M, int N, int K, int ldc)
{
    __shared__ ushort_t As[128*64];
    __shared__ ushort_t Bs[128*64];
    int tid = threadIdx.x;
    int lane = tid & 63, wave = tid >> 6;
    int m0 = blockIdx.y * 128, n0 = blockIdx.x * 128;
    int wave_m = (wave >> 1) * 64, wave_n = (wave & 1) * 64;
    int lrow = lane >> 3;               // 0..7
    int lcol = (lane & 7) * 8;          // element offset within 64
    const ushort_t* Abase = A  + (size_t)(m0 + wave*32 + lrow)*K + lcol;
    const ushort_t* Bbase = Bt + (size_t)(n0 + wave*32 + lrow)*K + lcol;
    ushort_t* AsW = &As[(wave*32)*64];
    ushort_t* BsW = &Bs[(wave*32)*64];
    f32x4 acc[4][4];
    #pragma unroll
    for (int i=0;i<4;i++)
        #pragma unroll
        for (int j=0;j<4;j++) acc[i][j] = (f32x4){0.f,0.f,0.f,0.f};
    int lm = lane & 15;
    int ko = (lane >> 4) * 8;
    for (int k0 = 0; k0 < K; k0 += 64){
        #pragma unroll
        for (int j = 0; j < 4; j++){
            __builtin_amdgcn_global_load_lds(
                (const __attribute__((address_space(1))) void*)(Abase + (size_t)(j*8)*K + k0),
                (__attribute__((address_space(3))) void*)(AsW + j*8*64), 16, 0, 0);
            __builtin_amdgcn_global_load_lds(
                (const __attribute__((address_space(1))) void*)(Bbase + (size_t)(j*8)*K + k0),
                (__attribute__((address_space(3))) void*)(BsW + j*8*64), 16, 0, 0);
        }
        __syncthreads();
        #pragma unroll
        for (int kk = 0; kk < 64; kk += 32){
            bf16x8 af[4], bfr[4];
            #pragma unroll
            for (int mt=0; mt<4; mt++)
                af[mt] = *(const bf16x8*)&As[(wave_m + mt*16 + lm)*64 + kk + ko];
            #pragma unroll
            for (int nt=0; nt<4; nt++)
                bfr[nt] = *(const bf16x8*)&Bs[(wave_n + nt*16 + lm)*64 + kk + ko];
            #pragma unroll
            for (int mt=0; mt<4; mt++)
                #pragma unroll
                for (int nt=0; nt<4; nt++)
                    acc[mt][nt] = __builtin_amdgcn_mfma_f32_16x16x32_bf16(af[mt], bfr[nt], acc[mt][nt], 0, 0, 0);
        }
        __syncthreads();
    }
    int crow0 = m0 + wave_m + (lane >> 4) * 4;
    int ccol0 = n0 + wave_n + lm;
    #pragma unroll
    for (int mt=0; mt<4; mt++){
        #pragma unroll
        for (int nt=0; nt<4; nt++){
            int col = ccol0 + nt*16;
            if (col < N){
                float bv = bias[col];
                #pragma unroll
                for (int r=0; r<4; r++){
                    int row = crow0 + mt*16 + r;
                    float v = acc[mt][nt][r] + bv;
                    if (ACT == 1){
                        float t = fminf(fmaxf(v + 3.f, 0.f), 6.f);
                        v = v * t * (1.f/6.f);
                    }
                    if (OUT_BF16) Cb[(size_t)row*ldc + col] = f2b(v);
                    else          Cf[(size_t)row*ldc + col] = v;
                }
            }
        }
    }
}

// -------------------- W[K,N] f32  ->  Wt[Npad,K] bf16 (zero-pad n >= N)
__global__ __launch_bounds__(256) void transpose_bf_k(const float* __restrict__ W,
                                                      ushort_t* __restrict__ Wt,
                                                      int K, int N){
    __shared__ ushort_t tile[32][33];
    int n0 = blockIdx.x*32, k0 = blockIdx.y*32;
    int tx = threadIdx.x & 31, ty = threadIdx.x >> 5;   // ty 0..7
    #pragma unroll
    for (int i = 0; i < 4; i++){
        int k = k0 + ty + i*8;
        int n = n0 + tx;
        float v = (n < N) ? W[(size_t)k*N + n] : 0.f;
        tile[ty + i*8][tx] = f2b(v);
    }
    __syncthreads();
    #pragma unroll
    for (int i = 0; i < 4; i++){
        Wt[(size_t)(n0 + ty + i*8)*K + k0 + tx] = tile[tx][ty + i*8];
    }
}

__global__ __launch_bounds__(256) void f2b_k(const float* __restrict__ in,
                                             ushort_t* __restrict__ outp, int n){
    int idx = blockIdx.x*256 + threadIdx.x;
    if (idx < n) outp[idx] = f2b(in[idx]);
}

// ------------------------------------------------- depthwise causal conv + SiLU
__global__ __launch_bounds__(256) void conv_silu_k(const float* __restrict__ zx,
                                                   const float* __restrict__ conv_w,
                                                   const float* __restrict__ conv_b,
                                                   float* __restrict__ outp){
    int idx = blockIdx.x*256 + threadIdx.x;       // ROWS*CONVD total
    int c = idx % CONVD;
    int row = idx / CONVD;                        // b*SEQL + t
    int t = row & (SEQL-1);
    float acc = conv_b[c];
    #pragma unroll
    for (int k = 0; k < 4; k++){
        int tt = t + k - 3;
        if (tt >= 0)
            acc += zx[((size_t)(row + k - 3))*DPROJ + DI + c] * conv_w[c*4 + k];
    }
    outp[idx] = silu_f(acc);
}

// --------------------------------- dt = softplus(dt_raw+bias); dA; chunk cumsum
__global__ __launch_bounds__(256) void dt_scan_k(const float* __restrict__ zx,
                                                 const float* __restrict__ time_diff,
                                                 const float* __restrict__ A_log,
                                                 const float* __restrict__ dt_bias,
                                                 const float* __restrict__ time_decay,
                                                 float* __restrict__ dt_out,
                                                 float* __restrict__ Acum){
    __shared__ float s[CHUNK];
    int bid = blockIdx.x;                          // b*NHEADS*NC
    int c = bid % NC;
    int h = (bid / NC) % NHEADS;
    int b = bid / (NC*NHEADS);
    int l = threadIdx.x;
    int t = c*CHUNK + l;
    float dtr = zx[((size_t)(b*SEQL + t))*DPROJ + (DPROJ-NHEADS) + h];
    float dtv = softplus_f(dtr + dt_bias[h]);
    float A = -expf(A_log[h]);
    float dA = dtv*A - softplus_f(time_decay[h]) * time_diff[b*SEQL + t];
    dt_out[(size_t)(b*SEQL + t)*NHEADS + h] = dtv;
    s[l] = dA;
    __syncthreads();
    for (int off = 1; off < CHUNK; off <<= 1){
        float v = (l >= off) ? s[l-off] : 0.f;
        __syncthreads();
        s[l] += v;
        __syncthreads();
    }
    Acum[((size_t)(b*NHEADS + h))*SEQL + t] = s[l];
}

// ------------------------------------------------------------------ xdt = xs * dt
__global__ __launch_bounds__(256) void xdt_k(const float* __restrict__ convb,
                                             const float* __restrict__ dt,
                                             float* __restrict__ xdt){
    int idx = blockIdx.x*256 + threadIdx.x;        // ROWS*DI total
    int d = idx & (DI-1);
    int row = idx >> 11;
    int h = d >> 6;
    xdt[idx] = convb[(size_t)row*CONVD + d] * dt[(size_t)row*NHEADS + h];
}

// ------------------------------------------------------- G[b,c,l,s] = C_l . B_s
__global__ __launch_bounds__(256) void g_nt_k(const float* __restrict__ convb,
                                              float* __restrict__ G){
    int bz = blockIdx.z;                   // b*NC + c
    int s0 = blockIdx.x * 64, l0 = blockIdx.y * 64;
    __shared__ float As[64][33];
    __shared__ float Bs[64][33];
    int tid = threadIdx.x;
    int tx = tid & 15, ty = tid >> 4;
    float acc[4][4] = {};
    const float* base = convb + ((size_t)bz*CHUNK)*CONVD;
    for (int k0 = 0; k0 < DSTATE; k0 += 32){
        #pragma unroll
        for (int i = 0; i < 8; i++){
            int e = tid + i*256;
            int r = e >> 5, cc = e & 31;
            As[r][cc] = base[(size_t)(l0+r)*CONVD + (DI+DSTATE) + k0 + cc];  // C rows
            Bs[r][cc] = base[(size_t)(s0+r)*CONVD + DI + k0 + cc];           // B rows
        }
        __syncthreads();
        #pragma unroll
        for (int kk = 0; kk < 32; kk++){
            float a[4], b[4];
            #pragma unroll
            for (int i = 0; i < 4; i++) a[i] = As[ty*4+i][kk];
            #pragma unroll
            for (int j = 0; j < 4; j++) b[j] = Bs[tx*4+j][kk];
            #pragma unroll
            for (int i = 0; i < 4; i++)
                #pragma unroll
                for (int j = 0; j < 4; j++)
                    acc[i][j] += a[i]*b[j];
        }
        __syncthreads();
    }
    float* g = G + (size_t)bz*CHUNK*CHUNK;
    #pragma unroll
    for (int i = 0; i < 4; i++)
        #pragma unroll
        for (int j = 0; j < 4; j++)
            g[(size_t)(l0+ty*4+i)*CHUNK + s0+tx*4+j] = acc[i][j];
}

// --------------- states[b,c,h,p,n] = sum_l B[l,n]*exp(AcL-Ac[l])*xdt[l,p]
__global__ __launch_bounds__(256) void states_k(const float* __restrict__ convb,
                                                const float* __restrict__ xdt,
                                                const float* __restrict__ Acum,
                                                float* __restrict__ states){
    __shared__ float Bt[64*128];
    __shared__ float wx[64*64];
    __shared__ float Acs[CHUNK];
    int bid = blockIdx.x;
    int h = bid % NHEADS;
    int c = (bid / NHEADS) % NC;
    int b = bid / (NHEADS*NC);
    int tid = threadIdx.x;
    const float* AcB = Acum + ((size_t)(b*NHEADS + h))*SEQL + c*CHUNK;
    Acs[tid] = AcB[tid];
    __syncthreads();
    float AcL = Acs[CHUNK-1];
    int tp = tid >> 5, tn = tid & 31;
    float acc[8][4] = {};
    const float* bbase = convb + ((size_t)(b*SEQL + c*CHUNK))*CONVD + DI;
    const float* xbase = xdt + ((size_t)(b*SEQL + c*CHUNK))*DI + h*HD;
    for (int l0 = 0; l0 < CHUNK; l0 += 64){
        #pragma unroll
        for (int i = 0; i < 32; i++){
            int e = tid + i*256; int l = e >> 7, n = e & 127;
            Bt[e] = bbase[(size_t)(l0+l)*CONVD + n];
        }
        #pragma unroll
        for (int i = 0; i < 16; i++){
            int e = tid + i*256; int l = e >> 6, p = e & 63;
            wx[e] = expf(AcL - Acs[l0+l]) * xbase[(size_t)(l0+l)*DI + p];
        }
        __syncthreads();
        for (int l = 0; l < 64; l++){
            float4 bv = ((const float4*)(Bt + l*128))[tn];
            #pragma unroll
            for (int i = 0; i < 8; i++){
                float w = wx[l*64 + tp*8 + i];
                acc[i][0] += w*bv.x; acc[i][1] += w*bv.y;
                acc[i][2] += w*bv.z; acc[i][3] += w*bv.w;
            }
        }
        __syncthreads();
    }
    float* outp = states + ((size_t)((b*NC + c)*NHEADS + h))*(HD*DSTATE);
    #pragma unroll
    for (int i = 0; i < 8; i++)
        #pragma unroll
        for (int j = 0; j < 4; j++)
            outp[(size_t)(tp*8+i)*DSTATE + tn*4 + j] = acc[i][j];
}

// ------------------------- inter-chunk recurrence: prev[c] = scan carry (8 steps)
__global__ __launch_bounds__(256) void prev_scan_k(const float* __restrict__ states,
                                                   const float* __restrict__ Acum,
                                                   float* __restrict__ prev){
    int bid = blockIdx.x;                  // B*NHEADS
    int h = bid % NHEADS, b = bid / NHEADS;
    int tid = threadIdx.x;
    const float* AcB = Acum + ((size_t)(b*NHEADS + h))*SEQL;
    float dec[NC];
    #pragma unroll
    for (int c = 0; c < NC; c++) dec[c] = expf(AcB[c*CHUNK + CHUNK-1]);
    for (int j = 0; j < 32; j++){
        int e = tid + j*256;
        float carry = 0.f;
        #pragma unroll
        for (int c = 0; c < NC; c++){
            size_t idx = ((size_t)((b*NC + c)*NHEADS + h))*(HD*DSTATE) + e;
            prev[idx] = carry;
            carry = carry*dec[c] + states[idx];
        }
    }
}

// ------ fused: Y = Y_off + Y_diag + D*xs, written in place over the xdt buffer
__global__ __launch_bounds__(256) void y_fused_k(const float* __restrict__ convb,
                                                 const float* __restrict__ G,
                                                 const float* __restrict__ Acum,
                                                 const float* __restrict__ prev,
                                                 const float* __restrict__ Dp,
                                                 float* __restrict__ Y){
    __shared__ float prev_s[HD*DSTATE];    // 32 KB
    __shared__ float xdt_s[64*HD];         // 16 KB
    __shared__ float Acs[CHUNK];
    int bid = blockIdx.x;
    int h = bid % NHEADS;
    int c = (bid / NHEADS) % NC;
    int b = bid / (NHEADS*NC);
    int tid = threadIdx.x;
    int l = tid;
    Acs[tid] = Acum[((size_t)(b*NHEADS + h))*SEQL + c*CHUNK + tid];
    {
        const float* pv = prev + ((size_t)((b*NC + c)*NHEADS + h))*(HD*DSTATE);
        #pragma unroll
        for (int i = 0; i < 32; i++) prev_s[tid + i*256] = pv[tid + i*256];
    }
    __syncthreads();
    float4 acc[16];
    #pragma unroll
    for (int q = 0; q < 16; q++) acc[q] = make_float4(0.f,0.f,0.f,0.f);

    int row = b*SEQL + c*CHUNK + l;
    // ---- phase 1: Y_off[l,p] = exp(Ac[l]) * sum_n C[l,n]*prev[p,n]
    {
        const float4* Crow4 = (const float4*)(convb + (size_t)row*CONVD + DI + DSTATE);
        const float4* prev4 = (const float4*)prev_s;
        for (int n4 = 0; n4 < 32; n4++){
            float4 c4 = Crow4[n4];
            #pragma unroll
            for (int q = 0; q < 16; q++){
                float4 p0 = prev4[(q*4+0)*32 + n4];
                float4 p1 = prev4[(q*4+1)*32 + n4];
                float4 p2 = prev4[(q*4+2)*32 + n4];
                float4 p3 = prev4[(q*4+3)*32 + n4];
                acc[q].x += c4.x*p0.x + c4.y*p0.y + c4.z*p0.z + c4.w*p0.w;
                acc[q].y += c4.x*p1.x + c4.y*p1.y + c4.z*p1.z + c4.w*p1.w;
                acc[q].z += c4.x*p2.x + c4.y*p2.y + c4.z*p2.z + c4.w*p2.w;
                acc[q].w += c4.x*p3.x + c4.y*p3.y + c4.z*p3.z + c4.w*p3.w;
            }
        }
        float el = expf(Acs[l]);
        #pragma unroll
        for (int q = 0; q < 16; q++){
            acc[q].x *= el; acc[q].y *= el; acc[q].z *= el; acc[q].w *= el;
        }
    }
    // ---- phase 2: Y_diag[l,p] = sum_{s<=l} G[l,s]*exp(Ac[l]-Ac[s])*xdt[s,p]
    const float* Grow = G + ((size_t)(b*NC + c))*(CHUNK*CHUNK) + (size_t)l*CHUNK;
    const float* xbase = Y + ((size_t)(b*SEQL + c*CHUNK))*DI + h*HD;
    for (int st = 0; st < 4; st++){
        __syncthreads();
        #pragma unroll
        for (int i = 0; i < 16; i++){
            int e = tid + i*256; int ss = e >> 6, p = e & 63;
            xdt_s[e] = xbase[(size_t)(st*64 + ss)*DI + p];
        }
        __syncthreads();
        int s0 = st*64;
        if (l >= s0){
            float Al = Acs[l];
            int send = (l < s0+63) ? l : (s0+63);
            for (int s = s0; s <= send; s++){
                float coef = Grow[s] * expf(Al - Acs[s]);
                const float4* x4 = (const float4*)(xdt_s + (s - s0)*HD);
                #pragma unroll
                for (int q = 0; q < 16; q++){
                    float4 xv = x4[q];
                    acc[q].x += coef*xv.x; acc[q].y += coef*xv.y;
                    acc[q].z += coef*xv.z; acc[q].w += coef*xv.w;
                }
            }
        }
    }
    // ---- phase 3: + D[h]*xs, write
    float Dv = Dp[h];
    const float4* xs4 = (const float4*)(convb + (size_t)row*CONVD + h*HD);
    float4* out4 = (float4*)(Y + (size_t)row*DI + h*HD);
    #pragma unroll
    for (int q = 0; q < 16; q++){
        float4 xv = xs4[q];
        float4 r;
        r.x = acc[q].x + Dv*xv.x; r.y = acc[q].y + Dv*xv.y;
        r.z = acc[q].z + Dv*xv.z; r.w = acc[q].w + Dv*xv.w;
        out4[q] = r;
    }
}

// ------------------------------- y = Y*silu(z); RMSNorm; * rms_w ; -> bf16
__global__ __launch_bounds__(256) void gate_rms_k(const float* __restrict__ Yb,
                                                  const float* __restrict__ zx,
                                                  const float* __restrict__ rms_w,
                                                  ushort_t* __restrict__ yn){
    __shared__ float red[4];
    __shared__ float scale_s;
    int row = blockIdx.x; int tid = threadIdx.x;
    float v[8]; float ss = 0.f;
    #pragma unroll
    for (int i = 0; i < 8; i++){
        int d = tid + i*256;
        float g = Yb[(size_t)row*DI + d] * silu_f(zx[(size_t)row*DPROJ + d]);
        v[i] = g; ss += g*g;
    }
    #pragma unroll
    for (int off = 32; off > 0; off >>= 1) ss += __shfl_down(ss, off);
    int lane = tid & 63, wid = tid >> 6;
    if (lane == 0) red[wid] = ss;
    __syncthreads();
    if (tid == 0) scale_s = rsqrtf((red[0]+red[1]+red[2]+red[3])*(1.f/DI) + 1e-12f);
    __syncthreads();
    float sc = scale_s;
    #pragma unroll
    for (int i = 0; i < 8; i++){
        int d = tid + i*256;
        yn[(size_t)row*DI + d] = f2b(v[i]*sc*rms_w[d]);
    }
}

// ----------------------------- LayerNorm(a + resid)*g + b (+ optional bf16 copy)
template<int WB>
__global__ __launch_bounds__(256) void ln_k(const float* __restrict__ a,
                                            const float* __restrict__ resid,
                                            const float* __restrict__ g,
                                            const float* __restrict__ bw,
                                            float* __restrict__ outp,
                                            ushort_t* __restrict__ bfout){
    __shared__ float redA[4], redB[4];
    __shared__ float mu_s, rs_s;
    int row = blockIdx.x; int tid = threadIdx.x;
    float u[4]; float s = 0.f, s2 = 0.f;
    #pragma unroll
    for (int i = 0; i < 4; i++){
        int d = tid + i*256;
        float val = a[(size_t)row*DM + d] + resid[(size_t)row*DM + d];
        u[i] = val; s += val; s2 += val*val;
    }
    #pragma unroll
    for (int off = 32; off > 0; off >>= 1){
        s  += __shfl_down(s,  off);
        s2 += __shfl_down(s2, off);
    }
    int lane = tid & 63, wid = tid >> 6;
    if (lane == 0){ redA[wid] = s; redB[wid] = s2; }
    __syncthreads();
    if (tid == 0){
        float S  = redA[0]+redA[1]+redA[2]+redA[3];
        float S2 = redB[0]+redB[1]+redB[2]+redB[3];
        float mu = S*(1.f/DM);
        float var = S2*(1.f/DM) - mu*mu;
        mu_s = mu; rs_s = rsqrtf(var + 1e-12f);
    }
    __syncthreads();
    float mu = mu_s, rs = rs_s;
    #pragma unroll
    for (int i = 0; i < 4; i++){
        int d = tid + i*256;
        float o = (u[i]-mu)*rs*g[d] + bw[d];
        outp[(size_t)row*DM + d] = o;
        if (WB) bfout[(size_t)row*DM + d] = f2b(o);
    }
}

__global__ __launch_bounds__(256) void copy_td_k(const float* __restrict__ td,
                                                 float* __restrict__ outp){
    int idx = blockIdx.x*256 + threadIdx.x;
    outp[idx] = td[idx];
}

extern "C" void kernel_launch(void* const* d_in, const int* in_sizes, int n_in,
                              void* d_out, int out_size, void* d_ws, size_t ws_size,
                              hipStream_t stream){
    const float* x         = (const float*)d_in[0];
    const float* time_diff = (const float*)d_in[1];
    const float* W_in      = (const float*)d_in[2];
    const float* b_in      = (const float*)d_in[3];
    const float* conv_w    = (const float*)d_in[4];
    const float* conv_b    = (const float*)d_in[5];
    const float* A_log     = (const float*)d_in[6];
    const float* dt_bias   = (const float*)d_in[7];
    const float* Dp        = (const float*)d_in[8];
    const float* time_dec  = (const float*)d_in[9];
    const float* rms_w     = (const float*)d_in[10];
    const float* W_out     = (const float*)d_in[11];
    const float* b_out     = (const float*)d_in[12];
    const float* ln_g      = (const float*)d_in[13];
    const float* ln_b      = (const float*)d_in[14];
    const float* fc1_w     = (const float*)d_in[15];
    const float* fc1_b     = (const float*)d_in[16];
    const float* fc2_w     = (const float*)d_in[17];
    const float* fc2_b     = (const float*)d_in[18];
    const float* ln2_g     = (const float*)d_in[19];
    const float* ln2_b     = (const float*)d_in[20];

    float* ws = (float*)d_ws;
    // Region layout (float units) — same 190 MB footprint as round 1:
    float* zx    = ws;                       // 17,956,864  region1
    float* convb = zx    + 17956864;         //  9,437,184  region2 (later: hidden)
    float* dt    = convb + 9437184;          //    131,072
    float* Acum  = dt    + 131072;           //    131,072
    float* xdt   = Acum  + 131072;           //  8,388,608  region4 (Y in-place)
    float* r5    = xdt   + 8388608;          //  9,437,184  region5 (G/stat/prev)
    float* hbuf  = r5    + 9437184;          //  4,194,304  region6
    // region4 aliases: x_bf+WinT (dead after GEMM1, before xdt written);
    //                  WoutT (after y-read done); hid2 (step 16)
    ushort_t* x_bf  = (ushort_t*)xdt;                 // 4,194,304 us
    ushort_t* WinT  = (ushort_t*)(xdt + 2097152);     // 4480*1024 us
    ushort_t* WoutT = (ushort_t*)(xdt + 4194304);     // 1024*2048 us
    float*    hid2  = xdt;                            // 4,194,304 f
    // region5 aliases:
    float* Gbuf = r5;                                 // 1,048,576 f
    float* stat = r5 + 1048576;                       // 4,194,304 f
    float* prev = stat + 4194304;                     // 4,194,304 f
    ushort_t* yn_bf = (ushort_t*)r5;                  // 4096*2048 us
    ushort_t* fc1T  = (ushort_t*)(r5 + 4194304);      // 4096*1024 us
    ushort_t* fc2T  = (ushort_t*)(r5 + 6291456);      // 1024*4096 us
    // region1 aliases (zx dead after gate_rms):
    ushort_t* mid_bf = (ushort_t*)zx;                 // 4096*4096 us
    ushort_t* h_bf   = (ushort_t*)(zx + 8388608);     // 4096*1024 us
    float* hidden = convb;
    float* outp   = (float*)d_out;

    // 1. bf16 conversions for in-proj
    f2b_k<<<(ROWS*DM)/256, 256, 0, stream>>>(x, x_bf, ROWS*DM);
    transpose_bf_k<<<dim3(4480/32, DM/32), 256, 0, stream>>>(W_in, WinT, DM, DPROJ);
    // 2. in-proj: zx = x @ W_in + b_in   (M=4096,N=4384,K=1024)
    mfma_gemm_k<0,0><<<dim3(35, ROWS/128), 256, 0, stream>>>(x_bf, WinT, b_in, zx, nullptr, ROWS, DPROJ, DM, DPROJ);
    // 3. causal conv + SiLU
    conv_silu_k<<<ROWS*CONVD/256, 256, 0, stream>>>(zx, conv_w, conv_b, convb);
    // 4. dt / dA / per-chunk cumsum
    dt_scan_k<<<BATCH*NHEADS*NC, 256, 0, stream>>>(zx, time_diff, A_log, dt_bias, time_dec, dt, Acum);
    // 5. xdt = xs * dt  (overwrites x_bf/WinT — both dead)
    xdt_k<<<ROWS*DI/256, 256, 0, stream>>>(convb, dt, xdt);
    // 6. G = C @ B^T per (b,c)
    g_nt_k<<<dim3(4,4,BATCH*NC), 256, 0, stream>>>(convb, Gbuf);
    // 7. per-chunk states
    states_k<<<BATCH*NC*NHEADS, 256, 0, stream>>>(convb, xdt, Acum, stat);
    // 8. inter-chunk scan
    prev_scan_k<<<BATCH*NHEADS, 256, 0, stream>>>(stat, Acum, prev);
    // 9. fused Y (in place over xdt)
    y_fused_k<<<BATCH*NC*NHEADS, 256, 0, stream>>>(convb, Gbuf, Acum, prev, Dp, xdt);
    // 10. gate + RMSNorm -> bf16 (overwrites Gbuf/stat — dead)
    gate_rms_k<<<ROWS, 256, 0, stream>>>(xdt, zx, rms_w, yn_bf);
    // 11. W_out transpose (into region4 upper half — Y reads done)
    transpose_bf_k<<<dim3(DM/32, DI/32), 256, 0, stream>>>(W_out, WoutT, DI, DM);
    // 12. out-proj: hidden = yn @ W_out + b_out   (M=4096,N=1024,K=2048)
    mfma_gemm_k<0,0><<<dim3(DM/128, ROWS/128), 256, 0, stream>>>(yn_bf, WoutT, b_out, hidden, nullptr, ROWS, DM, DI, DM);
    // 13. h = LN(hidden + x), plus bf16 copy (into region1 — zx dead)
    ln_k<1><<<ROWS, 256, 0, stream>>>(hidden, x, ln_g, ln_b, hbuf, h_bf);
    // 14. FFN weight transposes (into region5 upper — stat/prev dead)
    transpose_bf_k<<<dim3(DFF/32, DM/32), 256, 0, stream>>>(fc1_w, fc1T, DM, DFF);
    transpose_bf_k<<<dim3(DM/32, DFF/32), 256, 0, stream>>>(fc2_w, fc2T, DFF, DM);
    // 15. fc1 + hardswish -> bf16 mid  (M=4096,N=4096,K=1024)
    mfma_gemm_k<1,1><<<dim3(DFF/128, ROWS/128), 256, 0, stream>>>(h_bf, fc1T, fc1_b, nullptr, mid_bf, ROWS, DFF, DM, DFF);
    // 16. fc2: hid2 = mid @ fc2 + b    (M=4096,N=1024,K=4096)
    mfma_gemm_k<0,0><<<dim3(DM/128, ROWS/128), 256, 0, stream>>>(mid_bf, fc2T, fc2_b, hid2, nullptr, ROWS, DM, DFF, DM);
    // 17. out = LN(hid2 + h)
    ln_k<0><<<ROWS, 256, 0, stream>>>(hid2, hbuf, ln2_g, ln2_b, outp, nullptr);
    // 18. second tuple output: time_diff passthrough
    copy_td_k<<<ROWS/256, 256, 0, stream>>>(time_diff, outp + (size_t)ROWS*DM);
}

// Round 3
// 636.869 us; speedup vs baseline: 3.9038x; 1.1663x over previous
//
#include <hip/hip_runtime.h>

#define BATCH 2
#define SEQL 2048
#define DM 1024
#define DSTATE 128
#define HD 64
#define CHUNK 256
#define DI 2048
#define NHEADS 32
#define CONVD 2304
#define DPROJ 4384
#define DFF 4096
#define NC 8
#define ROWS (BATCH*SEQL)

typedef unsigned short ushort_t;
typedef short bf16x8 __attribute__((ext_vector_type(8)));
typedef float f32x4 __attribute__((ext_vector_type(4)));

__device__ __forceinline__ float softplus_f(float v){
    return (v > 20.f) ? v : log1pf(expf(v));
}
__device__ __forceinline__ float silu_f(float v){
    return v / (1.f + expf(-v));
}
__device__ __forceinline__ ushort_t f2b(float v){
    union { float f; unsigned int u; } x; x.f = v;
    unsigned int r = x.u + 0x7fffu + ((x.u >> 16) & 1u);
    return (ushort_t)(r >> 16);
}

// ================================================================ MFMA GEMM
// C[M,N] = A[M,K](bf16) @ Bt[N,K](bf16)^T + bias.
// 128x128 tile, BK=64, 4 waves, each wave 64x64 via 4x4 mfma 16x16x32.
template<int ACT, int OUT_BF16>
__global__ __launch_bounds__(256) void mfma_gemm_k(
    const ushort_t* __restrict__ A, const ushort_t* __restrict__ Bt,
    const float* __restrict__ bias, float* __restrict__ Cf,
    ushort_t* __restrict__ Cb, int M, int N, int K, int ldc)
{
    __shared__ ushort_t As[128*64];
    __shared__ ushort_t Bs[128*64];
    int tid = threadIdx.x;
    int lane = tid & 63, wave = tid >> 6;
    int m0 = blockIdx.y * 128, n0 = blockIdx.x * 128;
    int wave_m = (wave >> 1) * 64, wave_n = (wave & 1) * 64;
    int lrow = lane >> 3;               // 0..7
    int lcol = (lane & 7) * 8;          // element offset within 64
    const ushort_t* Abase = A  + (size_t)(m0 + wave*32 + lrow)*K + lcol;
    const ushort_t* Bbase = Bt + (size_t)(n0 + wave*32 + lrow)*K + lcol;
    ushort_t* AsW = &As[(wave*32)*64];
    ushort_t* BsW = &Bs[(wave*32)*64];
    f32x4 acc[4][4];
    #pragma unroll
    for (int i=0;i<4;i++)
        #pragma unroll
        for (int j=0;j<4;j++) acc[i][j] = (f32x4){0.f,0.f,0.f,0.f};
    int lm = lane & 15;
    int ko = (lane >> 4) * 8;
    for (int k0 = 0; k0 < K; k0 += 64){
        #pragma unroll
        for (int j = 0; j < 4; j++){
            __builtin_amdgcn_global_load_lds(
                (const __attribute__((address_space(1))) void*)(Abase + (size_t)(j*8)*K + k0),
                (__attribute__((address_space(3))) void*)(AsW + j*8*64), 16, 0, 0);
            __builtin_amdgcn_global_load_lds(
                (const __attribute__((address_space(1))) void*)(Bbase + (size_t)(j*8)*K + k0),
                (__attribute__((address_space(3))) void*)(BsW + j*8*64), 16, 0, 0);
        }
        __syncthreads();
        #pragma unroll
        for (int kk = 0; kk < 64; kk += 32){
            bf16x8 af[4], bfr[4];
            #pragma unroll
            for (int mt=0; mt<4; mt++)
                af[mt] = *(const bf16x8*)&As[(wave_m + mt*16 + lm)*64 + kk + ko];
            #pragma unroll
            for (int nt=0; nt<4; nt++)
                bfr[nt] = *(const bf16x8*)&Bs[(wave_n + nt*16 + lm)*64 + kk + ko];
            #pragma unroll
            for (int mt=0; mt<4; mt++)
                #pragma unroll
                for (int nt=0; nt<4; nt++)
                    acc[mt][nt] = __builtin_amdgcn_mfma_f32_16x16x32_bf16(af[mt], bfr[nt], acc[mt][nt], 0, 0, 0);
        }
        __syncthreads();
    }
    int crow0 = m0 + wave_m + (lane >> 4) * 4;
    int ccol0 = n0 + wave_n + lm;
    #pragma unroll
    for (int mt=0; mt<4; mt++){
        #pragma unroll
        for (int nt=0; nt<4; nt++){
            int col = ccol0 + nt*16;
            if (col < N){
                float bv = bias[col];
                #pragma unroll
                for (int r=0; r<4; r++){
                    int row = crow0 + mt*16 + r;
                    float v = acc[mt][nt][r] + bv;
                    if (ACT == 1){
                        float t = fminf(fmaxf(v + 3.f, 0.f), 6.f);
                        v = v * t * (1.f/6.f);
                    }
                    if (OUT_BF16) Cb[(size_t)row*ldc + col] = f2b(v);
                    else          Cf[(size_t)row*ldc + col] = v;
                }
            }
        }
    }
}

// -------------------- W[K,N] f32  ->  Wt[Npad,K] bf16 (zero-pad n >= N)
__global__ __launch_bounds__(256) void transpose_bf_k(const float* __restrict__ W,
                                                      ushort_t* __restrict__ Wt,
                                                      int K, int N){
    __shared__ ushort_t tile[32][33];
    int n0 = blockIdx.x*32, k0 = blockIdx.y*32;
    int tx = threadIdx.x & 31, ty = threadIdx.x >> 5;   // ty 0..7
    #pragma unroll
    for (int i = 0; i < 4; i++){
        int k = k0 + ty + i*8;
        int n = n0 + tx;
        float v = (n < N) ? W[(size_t)k*N + n] : 0.f;
        tile[ty + i*8][tx] = f2b(v);
    }
    __syncthreads();
    #pragma unroll
    for (int i = 0; i < 4; i++){
        Wt[(size_t)(n0 + ty + i*8)*K + k0 + tx] = tile[tx][ty + i*8];
    }
}

__global__ __launch_bounds__(256) void f2b_k(const float* __restrict__ in,
                                             ushort_t* __restrict__ outp, int n){
    int idx = blockIdx.x*256 + threadIdx.x;
    if (idx < n) outp[idx] = f2b(in[idx]);
}

// ------------------------------------------------- depthwise causal conv + SiLU
__global__ __launch_bounds__(256) void conv_silu_k(const float* __restrict__ zx,
                                                   const float* __restrict__ conv_w,
                                                   const float* __restrict__ conv_b,
                                                   float* __restrict__ outp){
    int idx = blockIdx.x*256 + threadIdx.x;       // ROWS*CONVD total
    int c = idx % CONVD;
    int row = idx / CONVD;                        // b*SEQL + t
    int t = row & (SEQL-1);
    float acc = conv_b[c];
    #pragma unroll
    for (int k = 0; k < 4; k++){
        int tt = t + k - 3;
        if (tt >= 0)
            acc += zx[((size_t)(row + k - 3))*DPROJ + DI + c] * conv_w[c*4 + k];
    }
    outp[idx] = silu_f(acc);
}

// --------------------------------- dt = softplus(dt_raw+bias); dA; chunk cumsum
__global__ __launch_bounds__(256) void dt_scan_k(const float* __restrict__ zx,
                                                 const float* __restrict__ time_diff,
                                                 const float* __restrict__ A_log,
                                                 const float* __restrict__ dt_bias,
                                                 const float* __restrict__ time_decay,
                                                 float* __restrict__ dt_out,
                                                 float* __restrict__ Acum){
    __shared__ float s[CHUNK];
    int bid = blockIdx.x;                          // b*NHEADS*NC
    int c = bid % NC;
    int h = (bid / NC) % NHEADS;
    int b = bid / (NC*NHEADS);
    int l = threadIdx.x;
    int t = c*CHUNK + l;
    float dtr = zx[((size_t)(b*SEQL + t))*DPROJ + (DPROJ-NHEADS) + h];
    float dtv = softplus_f(dtr + dt_bias[h]);
    float A = -expf(A_log[h]);
    float dA = dtv*A - softplus_f(time_decay[h]) * time_diff[b*SEQL + t];
    dt_out[(size_t)(b*SEQL + t)*NHEADS + h] = dtv;
    s[l] = dA;
    __syncthreads();
    for (int off = 1; off < CHUNK; off <<= 1){
        float v = (l >= off) ? s[l-off] : 0.f;
        __syncthreads();
        s[l] += v;
        __syncthreads();
    }
    Acum[((size_t)(b*NHEADS + h))*SEQL + t] = s[l];
}

// ------------------------------------------------------------------ xdt = xs * dt
__global__ __launch_bounds__(256) void xdt_k(const float* __restrict__ convb,
                                             const float* __restrict__ dt,
                                             float* __restrict__ xdt){
    int idx = blockIdx.x*256 + threadIdx.x;        // ROWS*DI total
    int d = idx & (DI-1);
    int row = idx >> 11;
    int h = d >> 6;
    xdt[idx] = convb[(size_t)row*CONVD + d] * dt[(size_t)row*NHEADS + h];
}

// ------------------------------------------------------- G[b,c,l,s] = C_l . B_s
__global__ __launch_bounds__(256) void g_nt_k(const float* __restrict__ convb,
                                              float* __restrict__ G){
    int bz = blockIdx.z;                   // b*NC + c
    int s0 = blockIdx.x * 64, l0 = blockIdx.y * 64;
    __shared__ float As[64][33];
    __shared__ float Bs[64][33];
    int tid = threadIdx.x;
    int tx = tid & 15, ty = tid >> 4;
    float acc[4][4] = {};
    const float* base = convb + ((size_t)bz*CHUNK)*CONVD;
    for (int k0 = 0; k0 < DSTATE; k0 += 32){
        #pragma unroll
        for (int i = 0; i < 8; i++){
            int e = tid + i*256;
            int r = e >> 5, cc = e & 31;
            As[r][cc] = base[(size_t)(l0+r)*CONVD + (DI+DSTATE) + k0 + cc];  // C rows
            Bs[r][cc] = base[(size_t)(s0+r)*CONVD + DI + k0 + cc];           // B rows
        }
        __syncthreads();
        #pragma unroll
        for (int kk = 0; kk < 32; kk++){
            float a[4], b[4];
            #pragma unroll
            for (int i = 0; i < 4; i++) a[i] = As[ty*4+i][kk];
            #pragma unroll
            for (int j = 0; j < 4; j++) b[j] = Bs[tx*4+j][kk];
            #pragma unroll
            for (int i = 0; i < 4; i++)
                #pragma unroll
                for (int j = 0; j < 4; j++)
                    acc[i][j] += a[i]*b[j];
        }
        __syncthreads();
    }
    float* g = G + (size_t)bz*CHUNK*CHUNK;
    #pragma unroll
    for (int i = 0; i < 4; i++)
        #pragma unroll
        for (int j = 0; j < 4; j++)
            g[(size_t)(l0+ty*4+i)*CHUNK + s0+tx*4+j] = acc[i][j];
}

// --------------- states[b,c,h,p,n] = sum_l B[l,n]*exp(AcL-Ac[l])*xdt[l,p]
__global__ __launch_bounds__(256) void states_k(const float* __restrict__ convb,
                                                const float* __restrict__ xdt,
                                                const float* __restrict__ Acum,
                                                float* __restrict__ states){
    __shared__ float Bt[64*128];
    __shared__ float wx[64*64];
    __shared__ float Acs[CHUNK];
    int bid = blockIdx.x;
    int h = bid % NHEADS;
    int c = (bid / NHEADS) % NC;
    int b = bid / (NHEADS*NC);
    int tid = threadIdx.x;
    const float* AcB = Acum + ((size_t)(b*NHEADS + h))*SEQL + c*CHUNK;
    Acs[tid] = AcB[tid];
    __syncthreads();
    float AcL = Acs[CHUNK-1];
    int tp = tid >> 5, tn = tid & 31;
    float acc[8][4] = {};
    const float* bbase = convb + ((size_t)(b*SEQL + c*CHUNK))*CONVD + DI;
    const float* xbase = xdt + ((size_t)(b*SEQL + c*CHUNK))*DI + h*HD;
    for (int l0 = 0; l0 < CHUNK; l0 += 64){
        #pragma unroll
        for (int i = 0; i < 32; i++){
            int e = tid + i*256; int l = e >> 7, n = e & 127;
            Bt[e] = bbase[(size_t)(l0+l)*CONVD + n];
        }
        #pragma unroll
        for (int i = 0; i < 16; i++){
            int e = tid + i*256; int l = e >> 6, p = e & 63;
            wx[e] = expf(AcL - Acs[l0+l]) * xbase[(size_t)(l0+l)*DI + p];
        }
        __syncthreads();
        for (int l = 0; l < 64; l++){
            float4 bv = ((const float4*)(Bt + l*128))[tn];
            #pragma unroll
            for (int i = 0; i < 8; i++){
                float w = wx[l*64 + tp*8 + i];
                acc[i][0] += w*bv.x; acc[i][1] += w*bv.y;
                acc[i][2] += w*bv.z; acc[i][3] += w*bv.w;
            }
        }
        __syncthreads();
    }
    float* outp = states + ((size_t)((b*NC + c)*NHEADS + h))*(HD*DSTATE);
    #pragma unroll
    for (int i = 0; i < 8; i++)
        #pragma unroll
        for (int j = 0; j < 4; j++)
            outp[(size_t)(tp*8+i)*DSTATE + tn*4 + j] = acc[i][j];
}

// ------------------------- inter-chunk recurrence: prev[c] = scan carry (8 steps)
__global__ __launch_bounds__(256) void prev_scan_k(const float* __restrict__ states,
                                                   const float* __restrict__ Acum,
                                                   float* __restrict__ prev){
    int bid = blockIdx.x;                  // B*NHEADS
    int h = bid % NHEADS, b = bid / NHEADS;
    int tid = threadIdx.x;
    const float* AcB = Acum + ((size_t)(b*NHEADS + h))*SEQL;
    float dec[NC];
    #pragma unroll
    for (int c = 0; c < NC; c++) dec[c] = expf(AcB[c*CHUNK + CHUNK-1]);
    for (int j = 0; j < 32; j++){
        int e = tid + j*256;
        float carry = 0.f;
        #pragma unroll
        for (int c = 0; c < NC; c++){
            size_t idx = ((size_t)((b*NC + c)*NHEADS + h))*(HD*DSTATE) + e;
            prev[idx] = carry;
            carry = carry*dec[c] + states[idx];
        }
    }
}

// ================= MFMA SSD output: Y = P@xdt + (e^A C)@prev^T + D*xs (in-place)
// Per (b,c,h). K = 256 (s, triangular) + 128 (n). 4 waves, wave-interleaved m-tiles.
#define RLX 264   // xdtT row len (shorts): 132 dw, stride%8==4 -> even bank spread
#define RLP 136   // prev row len (shorts): 68 dw, stride%8==4
__global__ __launch_bounds__(256) void y_mfma_k(const float* __restrict__ convb,
                                                const float* __restrict__ G,
                                                const float* __restrict__ Acum,
                                                const float* __restrict__ prev,
                                                const float* __restrict__ Dp,
                                                float* __restrict__ Y){
    __shared__ ushort_t xdtT[64*RLX];   // 33792 B
    __shared__ ushort_t prevs[64*RLP];  // 17408 B
    __shared__ float Acs[CHUNK];        // 1024 B
    int bid = blockIdx.x;
    int h = bid % NHEADS;
    int c = (bid / NHEADS) % NC;
    int b = bid / (NHEADS*NC);
    int tid = threadIdx.x;
    int lane = tid & 63, wave = tid >> 6;
    int lm = lane & 15, quad = lane >> 4;

    Acs[tid] = Acum[((size_t)(b*NHEADS + h))*SEQL + c*CHUNK + tid];
    // stage prev -> bf16 LDS [p][n]
    {
        const float* pv = prev + ((size_t)((b*NC + c)*NHEADS + h))*(HD*DSTATE);
        #pragma unroll
        for (int i = 0; i < 32; i++){
            int e = tid + i*256; int p = e >> 7, n = e & 127;
            prevs[p*RLP + n] = f2b(pv[e]);
        }
    }
    // stage xdt^T -> bf16 LDS [p][s]; wave w covers s in [w*64, w*64+64)
    {
        const float* xg = Y + ((size_t)(b*SEQL + c*CHUNK))*DI + h*HD;
        #pragma unroll
        for (int j8 = 0; j8 < 8; j8++){
            int s0 = wave*64 + j8*8;
            bf16x8 pk;
            #pragma unroll
            for (int j = 0; j < 8; j++)
                pk[j] = (short)f2b(xg[(size_t)(s0+j)*DI + lane]);
            *(bf16x8*)&xdtT[lane*RLX + s0] = pk;
        }
    }
    __syncthreads();

    // per-m-tile hoisted row values: rblk = mt*4 + wave
    int   lrow[4];  float Alr[4], eAlr[4];
    #pragma unroll
    for (int mt = 0; mt < 4; mt++){
        lrow[mt] = (mt*4 + wave)*16 + lm;
        Alr[mt]  = Acs[lrow[mt]];
        eAlr[mt] = expf(Alr[mt]);
    }
    const float* Gbase = G + ((size_t)(b*NC + c))*(CHUNK*CHUNK);

    f32x4 acc[4][4];
    #pragma unroll
    for (int i=0;i<4;i++)
        #pragma unroll
        for (int j=0;j<4;j++) acc[i][j] = (f32x4){0.f,0.f,0.f,0.f};

    // ---- triangular part: k = s in [0,256)
    for (int ks = 0; ks < 8; ks++){
        bf16x8 bfr[4];
        #pragma unroll
        for (int nt = 0; nt < 4; nt++)
            bfr[nt] = *(const bf16x8*)&xdtT[(nt*16+lm)*RLX + ks*32 + quad*8];
        #pragma unroll
        for (int mt = 0; mt < 4; mt++){
            int rblk = mt*4 + wave;
            int nst = rblk/2 + 1;
            if (ks < nst){
                int sbase = ks*32 + quad*8;
                const float4* G4 = (const float4*)(Gbase + (size_t)lrow[mt]*CHUNK + sbase);
                float4 g0 = G4[0], g1 = G4[1];
                const float4* A4 = (const float4*)(&Acs[sbase]);
                float4 a0 = A4[0], a1 = A4[1];
                float Al = Alr[mt]; int l = lrow[mt];
                float pv[8];
                pv[0] = (sbase+0 <= l) ? g0.x*expf(Al - a0.x) : 0.f;
                pv[1] = (sbase+1 <= l) ? g0.y*expf(Al - a0.y) : 0.f;
                pv[2] = (sbase+2 <= l) ? g0.z*expf(Al - a0.z) : 0.f;
                pv[3] = (sbase+3 <= l) ? g0.w*expf(Al - a0.w) : 0.f;
                pv[4] = (sbase+4 <= l) ? g1.x*expf(Al - a1.x) : 0.f;
                pv[5] = (sbase+5 <= l) ? g1.y*expf(Al - a1.y) : 0.f;
                pv[6] = (sbase+6 <= l) ? g1.z*expf(Al - a1.z) : 0.f;
                pv[7] = (sbase+7 <= l) ? g1.w*expf(Al - a1.w) : 0.f;
                bf16x8 af;
                #pragma unroll
                for (int j = 0; j < 8; j++) af[j] = (short)f2b(pv[j]);
                #pragma unroll
                for (int nt = 0; nt < 4; nt++)
                    acc[mt][nt] = __builtin_amdgcn_mfma_f32_16x16x32_bf16(af, bfr[nt], acc[mt][nt], 0, 0, 0);
            }
        }
    }
    // ---- state part: k = n in [0,128), A = e^{Al} * C[l,n], B = prev[p][n]
    for (int kc = 0; kc < 4; kc++){
        bf16x8 bfr[4];
        #pragma unroll
        for (int nt = 0; nt < 4; nt++)
            bfr[nt] = *(const bf16x8*)&prevs[(nt*16+lm)*RLP + kc*32 + quad*8];
        #pragma unroll
        for (int mt = 0; mt < 4; mt++){
            int rowg = b*SEQL + c*CHUNK + lrow[mt];
            const float4* C4 = (const float4*)(convb + (size_t)rowg*CONVD + DI + DSTATE + kc*32 + quad*8);
            float4 c0 = C4[0], c1 = C4[1];
            float e = eAlr[mt];
            bf16x8 af;
            af[0] = (short)f2b(e*c0.x); af[1] = (short)f2b(e*c0.y);
            af[2] = (short)f2b(e*c0.z); af[3] = (short)f2b(e*c0.w);
            af[4] = (short)f2b(e*c1.x); af[5] = (short)f2b(e*c1.y);
            af[6] = (short)f2b(e*c1.z); af[7] = (short)f2b(e*c1.w);
            #pragma unroll
            for (int nt = 0; nt < 4; nt++)
                acc[mt][nt] = __builtin_amdgcn_mfma_f32_16x16x32_bf16(af, bfr[nt], acc[mt][nt], 0, 0, 0);
        }
    }
    // ---- epilogue: + D*xs, write f32 (in place; block's slice is disjoint)
    float Dv = Dp[h];
    #pragma unroll
    for (int mt = 0; mt < 4; mt++){
        int l0 = (mt*4 + wave)*16 + quad*4;
        #pragma unroll
        for (int nt = 0; nt < 4; nt++){
            int p = nt*16 + lm;
            #pragma unroll
            for (int r = 0; r < 4; r++){
                int rowg = b*SEQL + c*CHUNK + l0 + r;
                float xs = convb[(size_t)rowg*CONVD + h*HD + p];
                Y[(size_t)rowg*DI + h*HD + p] = acc[mt][nt][r] + Dv*xs;
            }
        }
    }
}

// ------------------------------- y = Y*silu(z); RMSNorm; * rms_w ; -> bf16
__global__ __launch_bounds__(256) void gate_rms_k(const float* __restrict__ Yb,
                                                  const float* __restrict__ zx,
                                                  const float* __restrict__ rms_w,
                                                  ushort_t* __restrict__ yn){
    __shared__ float red[4];
    __shared__ float scale_s;
    int row = blockIdx.x; int tid = threadIdx.x;
    float v[8]; float ss = 0.f;
    #pragma unroll
    for (int i = 0; i < 8; i++){
        int d = tid + i*256;
        float g = Yb[(size_t)row*DI + d] * silu_f(zx[(size_t)row*DPROJ + d]);
        v[i] = g; ss += g*g;
    }
    #pragma unroll
    for (int off = 32; off > 0; off >>= 1) ss += __shfl_down(ss, off);
    int lane = tid & 63, wid = tid >> 6;
    if (lane == 0) red[wid] = ss;
    __syncthreads();
    if (tid == 0) scale_s = rsqrtf((red[0]+red[1]+red[2]+red[3])*(1.f/DI) + 1e-12f);
    __syncthreads();
    float sc = scale_s;
    #pragma unroll
    for (int i = 0; i < 8; i++){
        int d = tid + i*256;
        yn[(size_t)row*DI + d] = f2b(v[i]*sc*rms_w[d]);
    }
}

// ----------------------------- LayerNorm(a + resid)*g + b (+ optional bf16 copy)
template<int WB>
__global__ __launch_bounds__(256) void ln_k(const float* __restrict__ a,
                                            const float* __restrict__ resid,
                                            const float* __restrict__ g,
                                            const float* __restrict__ bw,
                                            float* __restrict__ outp,
                                            ushort_t* __restrict__ bfout){
    __shared__ float redA[4], redB[4];
    __shared__ float mu_s, rs_s;
    int row = blockIdx.x; int tid = threadIdx.x;
    float u[4]; float s = 0.f, s2 = 0.f;
    #pragma unroll
    for (int i = 0; i < 4; i++){
        int d = tid + i*256;
        float val = a[(size_t)row*DM + d] + resid[(size_t)row*DM + d];
        u[i] = val; s += val; s2 += val*val;
    }
    #pragma unroll
    for (int off = 32; off > 0; off >>= 1){
        s  += __shfl_down(s,  off);
        s2 += __shfl_down(s2, off);
    }
    int lane = tid & 63, wid = tid >> 6;
    if (lane == 0){ redA[wid] = s; redB[wid] = s2; }
    __syncthreads();
    if (tid == 0){
        float S  = redA[0]+redA[1]+redA[2]+redA[3];
        float S2 = redB[0]+redB[1]+redB[2]+redB[3];
        float mu = S*(1.f/DM);
        float var = S2*(1.f/DM) - mu*mu;
        mu_s = mu; rs_s = rsqrtf(var + 1e-12f);
    }
    __syncthreads();
    float mu = mu_s, rs = rs_s;
    #pragma unroll
    for (int i = 0; i < 4; i++){
        int d = tid + i*256;
        float o = (u[i]-mu)*rs*g[d] + bw[d];
        outp[(size_t)row*DM + d] = o;
        if (WB) bfout[(size_t)row*DM + d] = f2b(o);
    }
}

__global__ __launch_bounds__(256) void copy_td_k(const float* __restrict__ td,
                                                 float* __restrict__ outp){
    int idx = blockIdx.x*256 + threadIdx.x;
    outp[idx] = td[idx];
}

extern "C" void kernel_launch(void* const* d_in, const int* in_sizes, int n_in,
                              void* d_out, int out_size, void* d_ws, size_t ws_size,
                              hipStream_t stream){
    const float* x         = (const float*)d_in[0];
    const float* time_diff = (const float*)d_in[1];
    const float* W_in      = (const float*)d_in[2];
    const float* b_in      = (const float*)d_in[3];
    const float* conv_w    = (const float*)d_in[4];
    const float* conv_b    = (const float*)d_in[5];
    const float* A_log     = (const float*)d_in[6];
    const float* dt_bias   = (const float*)d_in[7];
    const float* Dp        = (const float*)d_in[8];
    const float* time_dec  = (const float*)d_in[9];
    const float* rms_w     = (const float*)d_in[10];
    const float* W_out     = (const float*)d_in[11];
    const float* b_out     = (const float*)d_in[12];
    const float* ln_g      = (const float*)d_in[13];
    const float* ln_b      = (const float*)d_in[14];
    const float* fc1_w     = (const float*)d_in[15];
    const float* fc1_b     = (const float*)d_in[16];
    const float* fc2_w     = (const float*)d_in[17];
    const float* fc2_b     = (const float*)d_in[18];
    const float* ln2_g     = (const float*)d_in[19];
    const float* ln2_b     = (const float*)d_in[20];

    float* ws = (float*)d_ws;
    float* zx    = ws;                       // 17,956,864  region1
    float* convb = zx    + 17956864;         //  9,437,184  region2 (later: hidden)
    float* dt    = convb + 9437184;          //    131,072
    float* Acum  = dt    + 131072;           //    131,072
    float* xdt   = Acum  + 131072;           //  8,388,608  region4 (Y in-place)
    float* r5    = xdt   + 8388608;          //  9,437,184  region5 (G/stat/prev)
    float* hbuf  = r5    + 9437184;          //  4,194,304  region6
    ushort_t* x_bf  = (ushort_t*)xdt;                 // region4 aliases
    ushort_t* WinT  = (ushort_t*)(xdt + 2097152);
    ushort_t* WoutT = (ushort_t*)(xdt + 4194304);
    float*    hid2  = xdt;
    float* Gbuf = r5;                                 // region5 aliases
    float* stat = r5 + 1048576;
    float* prev = stat + 4194304;
    ushort_t* yn_bf = (ushort_t*)r5;
    ushort_t* fc1T  = (ushort_t*)(r5 + 4194304);
    ushort_t* fc2T  = (ushort_t*)(r5 + 6291456);
    ushort_t* mid_bf = (ushort_t*)zx;                 // region1 aliases
    ushort_t* h_bf   = (ushort_t*)(zx + 8388608);
    float* hidden = convb;
    float* outp   = (float*)d_out;

    // 1. bf16 conversions for in-proj
    f2b_k<<<(ROWS*DM)/256, 256, 0, stream>>>(x, x_bf, ROWS*DM);
    transpose_bf_k<<<dim3(4480/32, DM/32), 256, 0, stream>>>(W_in, WinT, DM, DPROJ);
    // 2. in-proj
    mfma_gemm_k<0,0><<<dim3(35, ROWS/128), 256, 0, stream>>>(x_bf, WinT, b_in, zx, nullptr, ROWS, DPROJ, DM, DPROJ);
    // 3. causal conv + SiLU
    conv_silu_k<<<ROWS*CONVD/256, 256, 0, stream>>>(zx, conv_w, conv_b, convb);
    // 4. dt / dA / per-chunk cumsum
    dt_scan_k<<<BATCH*NHEADS*NC, 256, 0, stream>>>(zx, time_diff, A_log, dt_bias, time_dec, dt, Acum);
    // 5. xdt = xs * dt
    xdt_k<<<ROWS*DI/256, 256, 0, stream>>>(convb, dt, xdt);
    // 6. G = C @ B^T per (b,c)
    g_nt_k<<<dim3(4,4,BATCH*NC), 256, 0, stream>>>(convb, Gbuf);
    // 7. per-chunk states
    states_k<<<BATCH*NC*NHEADS, 256, 0, stream>>>(convb, xdt, Acum, stat);
    // 8. inter-chunk scan
    prev_scan_k<<<BATCH*NHEADS, 256, 0, stream>>>(stat, Acum, prev);
    // 9. MFMA SSD output (in place over xdt)
    y_mfma_k<<<BATCH*NC*NHEADS, 256, 0, stream>>>(convb, Gbuf, Acum, prev, Dp, xdt);
    // 10. gate + RMSNorm -> bf16
    gate_rms_k<<<ROWS, 256, 0, stream>>>(xdt, zx, rms_w, yn_bf);
    // 11. W_out transpose
    transpose_bf_k<<<dim3(DM/32, DI/32), 256, 0, stream>>>(W_out, WoutT, DI, DM);
    // 12. out-proj
    mfma_gemm_k<0,0><<<dim3(DM/128, ROWS/128), 256, 0, stream>>>(yn_bf, WoutT, b_out, hidden, nullptr, ROWS, DM, DI, DM);
    // 13. h = LN(hidden + x) + bf16 copy
    ln_k<1><<<ROWS, 256, 0, stream>>>(hidden, x, ln_g, ln_b, hbuf, h_bf);
    // 14. FFN weight transposes
    transpose_bf_k<<<dim3(DFF/32, DM/32), 256, 0, stream>>>(fc1_w, fc1T, DM, DFF);
    transpose_bf_k<<<dim3(DM/32, DFF/32), 256, 0, stream>>>(fc2_w, fc2T, DFF, DM);
    // 15. fc1 + hardswish -> bf16 mid
    mfma_gemm_k<1,1><<<dim3(DFF/128, ROWS/128), 256, 0, stream>>>(h_bf, fc1T, fc1_b, nullptr, mid_bf, ROWS, DFF, DM, DFF);
    // 16. fc2
    mfma_gemm_k<0,0><<<dim3(DM/128, ROWS/128), 256, 0, stream>>>(mid_bf, fc2T, fc2_b, hid2, nullptr, ROWS, DM, DFF, DM);
    // 17. out = LN(hid2 + h)
    ln_k<0><<<ROWS, 256, 0, stream>>>(hid2, hbuf, ln2_g, ln2_b, outp, nullptr);
    // 18. time_diff passthrough
    copy_td_k<<<ROWS/256, 256, 0, stream>>>(time_diff, outp + (size_t)ROWS*DM);
}

// Round 4
// 575.412 us; speedup vs baseline: 4.3208x; 1.1068x over previous
//
#include <hip/hip_runtime.h>

#define BATCH 2
#define SEQL 2048
#define DM 1024
#define DSTATE 128
#define HD 64
#define CHUNK 256
#define DI 2048
#define NHEADS 32
#define CONVD 2304
#define DPROJ 4384
#define DFF 4096
#define NC 8
#define ROWS (BATCH*SEQL)

typedef unsigned short ushort_t;
typedef short bf16x8 __attribute__((ext_vector_type(8)));
typedef float f32x4 __attribute__((ext_vector_type(4)));

__device__ __forceinline__ float softplus_f(float v){
    return (v > 20.f) ? v : log1pf(expf(v));
}
__device__ __forceinline__ float silu_f(float v){
    return v / (1.f + expf(-v));
}
__device__ __forceinline__ ushort_t f2b(float v){
    union { float f; unsigned int u; } x; x.f = v;
    unsigned int r = x.u + 0x7fffu + ((x.u >> 16) & 1u);
    return (ushort_t)(r >> 16);
}

// ================================================================ MFMA GEMM
// C[M,N] = A[M,K](bf16) @ Bt[N,K](bf16)^T + bias.
// BM=128, BN=TN (128 or 64), BK=64, 256 threads.
// XOR-swizzled LDS: row r's 16B chunk c stored at chunk position c^(r&7),
// achieved by lane i loading global chunk (i&7)^(i>>3) (global_load_lds's
// lane->LDS mapping is fixed; we permute the *source* instead).
template<int ACT, int OUT_BF16, int TN>
__global__ __launch_bounds__(256) void mfma_gemm_k(
    const ushort_t* __restrict__ A, const ushort_t* __restrict__ Bt,
    const float* __restrict__ bias, float* __restrict__ Cf,
    ushort_t* __restrict__ Cb, int M, int N, int K, int ldc)
{
    constexpr int NT = (TN == 128) ? 4 : 2;      // n-tiles per wave
    constexpr int BROWS = TN / 4;                // B rows staged per wave
    __shared__ ushort_t As[128*64];
    __shared__ ushort_t Bs[TN*64];
    int tid = threadIdx.x;
    int lane = tid & 63, wave = tid >> 6;
    int m0 = blockIdx.y * 128, n0 = blockIdx.x * TN;
    int wave_m = (TN==128) ? (wave >> 1)*64 : (wave & 1)*64;
    int wave_n = (TN==128) ? (wave & 1)*64 : (wave >> 1)*32;
    int lrow = lane >> 3;                        // 0..7
    int lcol = ((lane & 7) ^ lrow) * 8;          // swizzled k-chunk
    const ushort_t* Abase = A  + (size_t)(m0 + wave*32    + lrow)*K + lcol;
    const ushort_t* Bbase = Bt + (size_t)(n0 + wave*BROWS + lrow)*K + lcol;
    ushort_t* AsW = &As[(wave*32)*64];
    ushort_t* BsW = &Bs[(wave*BROWS)*64];
    f32x4 acc[4][NT];
    #pragma unroll
    for (int i=0;i<4;i++)
        #pragma unroll
        for (int j=0;j<NT;j++) acc[i][j] = (f32x4){0.f,0.f,0.f,0.f};
    int lm = lane & 15;
    int quad = lane >> 4;
    for (int k0 = 0; k0 < K; k0 += 64){
        #pragma unroll
        for (int j = 0; j < 4; j++)
            __builtin_amdgcn_global_load_lds(
                (const __attribute__((address_space(1))) void*)(Abase + (size_t)(j*8)*K + k0),
                (__attribute__((address_space(3))) void*)(AsW + j*8*64), 16, 0, 0);
        #pragma unroll
        for (int j = 0; j < BROWS/8; j++)
            __builtin_amdgcn_global_load_lds(
                (const __attribute__((address_space(1))) void*)(Bbase + (size_t)(j*8)*K + k0),
                (__attribute__((address_space(3))) void*)(BsW + j*8*64), 16, 0, 0);
        __syncthreads();
        #pragma unroll
        for (int kk = 0; kk < 64; kk += 32){
            int cb = kk >> 3;                    // chunk base: 0 or 4
            bf16x8 af[4], bfr[NT];
            #pragma unroll
            for (int mt=0; mt<4; mt++)
                af[mt] = *(const bf16x8*)&As[(wave_m + mt*16 + lm)*64 + (((cb + quad) ^ (lm & 7))*8)];
            #pragma unroll
            for (int nt=0; nt<NT; nt++)
                bfr[nt] = *(const bf16x8*)&Bs[(wave_n + nt*16 + lm)*64 + (((cb + quad) ^ (lm & 7))*8)];
            #pragma unroll
            for (int mt=0; mt<4; mt++)
                #pragma unroll
                for (int nt=0; nt<NT; nt++)
                    acc[mt][nt] = __builtin_amdgcn_mfma_f32_16x16x32_bf16(af[mt], bfr[nt], acc[mt][nt], 0, 0, 0);
        }
        __syncthreads();
    }
    int crow0 = m0 + wave_m + quad * 4;
    int ccol0 = n0 + wave_n + lm;
    #pragma unroll
    for (int mt=0; mt<4; mt++){
        #pragma unroll
        for (int nt=0; nt<NT; nt++){
            int col = ccol0 + nt*16;
            if (col < N){
                float bv = bias[col];
                #pragma unroll
                for (int r=0; r<4; r++){
                    int row = crow0 + mt*16 + r;
                    float v = acc[mt][nt][r] + bv;
                    if (ACT == 1){
                        float t = fminf(fmaxf(v + 3.f, 0.f), 6.f);
                        v = v * t * (1.f/6.f);
                    }
                    if (OUT_BF16) Cb[(size_t)row*ldc + col] = f2b(v);
                    else          Cf[(size_t)row*ldc + col] = v;
                }
            }
        }
    }
}

// -------------------- W[K,N] f32  ->  Wt[Npad,K] bf16 (zero-pad n >= N)
__global__ __launch_bounds__(256) void transpose_bf_k(const float* __restrict__ W,
                                                      ushort_t* __restrict__ Wt,
                                                      int K, int N){
    __shared__ ushort_t tile[32][33];
    int n0 = blockIdx.x*32, k0 = blockIdx.y*32;
    int tx = threadIdx.x & 31, ty = threadIdx.x >> 5;   // ty 0..7
    #pragma unroll
    for (int i = 0; i < 4; i++){
        int k = k0 + ty + i*8;
        int n = n0 + tx;
        float v = (n < N) ? W[(size_t)k*N + n] : 0.f;
        tile[ty + i*8][tx] = f2b(v);
    }
    __syncthreads();
    #pragma unroll
    for (int i = 0; i < 4; i++){
        Wt[(size_t)(n0 + ty + i*8)*K + k0 + tx] = tile[tx][ty + i*8];
    }
}

__global__ __launch_bounds__(256) void f2b_k(const float* __restrict__ in,
                                             ushort_t* __restrict__ outp, int n){
    int idx = blockIdx.x*256 + threadIdx.x;
    if (idx < n) outp[idx] = f2b(in[idx]);
}

// ------------------------------------------------- depthwise causal conv + SiLU
__global__ __launch_bounds__(256) void conv_silu_k(const float* __restrict__ zx,
                                                   const float* __restrict__ conv_w,
                                                   const float* __restrict__ conv_b,
                                                   float* __restrict__ outp){
    int idx = blockIdx.x*256 + threadIdx.x;       // ROWS*CONVD total
    int c = idx % CONVD;
    int row = idx / CONVD;                        // b*SEQL + t
    int t = row & (SEQL-1);
    float acc = conv_b[c];
    #pragma unroll
    for (int k = 0; k < 4; k++){
        int tt = t + k - 3;
        if (tt >= 0)
            acc += zx[((size_t)(row + k - 3))*DPROJ + DI + c] * conv_w[c*4 + k];
    }
    outp[idx] = silu_f(acc);
}

// --------------------------------- dt = softplus(dt_raw+bias); dA; chunk cumsum
__global__ __launch_bounds__(256) void dt_scan_k(const float* __restrict__ zx,
                                                 const float* __restrict__ time_diff,
                                                 const float* __restrict__ A_log,
                                                 const float* __restrict__ dt_bias,
                                                 const float* __restrict__ time_decay,
                                                 float* __restrict__ dt_out,
                                                 float* __restrict__ Acum){
    __shared__ float s[CHUNK];
    int bid = blockIdx.x;                          // b*NHEADS*NC
    int c = bid % NC;
    int h = (bid / NC) % NHEADS;
    int b = bid / (NC*NHEADS);
    int l = threadIdx.x;
    int t = c*CHUNK + l;
    float dtr = zx[((size_t)(b*SEQL + t))*DPROJ + (DPROJ-NHEADS) + h];
    float dtv = softplus_f(dtr + dt_bias[h]);
    float A = -expf(A_log[h]);
    float dA = dtv*A - softplus_f(time_decay[h]) * time_diff[b*SEQL + t];
    dt_out[(size_t)(b*SEQL + t)*NHEADS + h] = dtv;
    s[l] = dA;
    __syncthreads();
    for (int off = 1; off < CHUNK; off <<= 1){
        float v = (l >= off) ? s[l-off] : 0.f;
        __syncthreads();
        s[l] += v;
        __syncthreads();
    }
    Acum[((size_t)(b*NHEADS + h))*SEQL + t] = s[l];
}

// ------------------------------------------------------------------ xdt = xs * dt
__global__ __launch_bounds__(256) void xdt_k(const float* __restrict__ convb,
                                             const float* __restrict__ dt,
                                             float* __restrict__ xdt){
    int idx = blockIdx.x*256 + threadIdx.x;        // ROWS*DI total
    int d = idx & (DI-1);
    int row = idx >> 11;
    int h = d >> 6;
    xdt[idx] = convb[(size_t)row*CONVD + d] * dt[(size_t)row*NHEADS + h];
}

// ------------------------------------------------------- G[b,c,l,s] = C_l . B_s
__global__ __launch_bounds__(256) void g_nt_k(const float* __restrict__ convb,
                                              float* __restrict__ G){
    int bz = blockIdx.z;                   // b*NC + c
    int s0 = blockIdx.x * 64, l0 = blockIdx.y * 64;
    __shared__ float As[64][33];
    __shared__ float Bs[64][33];
    int tid = threadIdx.x;
    int tx = tid & 15, ty = tid >> 4;
    float acc[4][4] = {};
    const float* base = convb + ((size_t)bz*CHUNK)*CONVD;
    for (int k0 = 0; k0 < DSTATE; k0 += 32){
        #pragma unroll
        for (int i = 0; i < 8; i++){
            int e = tid + i*256;
            int r = e >> 5, cc = e & 31;
            As[r][cc] = base[(size_t)(l0+r)*CONVD + (DI+DSTATE) + k0 + cc];  // C rows
            Bs[r][cc] = base[(size_t)(s0+r)*CONVD + DI + k0 + cc];           // B rows
        }
        __syncthreads();
        #pragma unroll
        for (int kk = 0; kk < 32; kk++){
            float a[4], b[4];
            #pragma unroll
            for (int i = 0; i < 4; i++) a[i] = As[ty*4+i][kk];
            #pragma unroll
            for (int j = 0; j < 4; j++) b[j] = Bs[tx*4+j][kk];
            #pragma unroll
            for (int i = 0; i < 4; i++)
                #pragma unroll
                for (int j = 0; j < 4; j++)
                    acc[i][j] += a[i]*b[j];
        }
        __syncthreads();
    }
    float* g = G + (size_t)bz*CHUNK*CHUNK;
    #pragma unroll
    for (int i = 0; i < 4; i++)
        #pragma unroll
        for (int j = 0; j < 4; j++)
            g[(size_t)(l0+ty*4+i)*CHUNK + s0+tx*4+j] = acc[i][j];
}

// --------------- states[b,c,h,p,n] = sum_l B[l,n]*exp(AcL-Ac[l])*xdt[l,p]
__global__ __launch_bounds__(256) void states_k(const float* __restrict__ convb,
                                                const float* __restrict__ xdt,
                                                const float* __restrict__ Acum,
                                                float* __restrict__ states){
    __shared__ float Bt[64*128];
    __shared__ float wx[64*64];
    __shared__ float Acs[CHUNK];
    int bid = blockIdx.x;
    int h = bid % NHEADS;
    int c = (bid / NHEADS) % NC;
    int b = bid / (NHEADS*NC);
    int tid = threadIdx.x;
    const float* AcB = Acum + ((size_t)(b*NHEADS + h))*SEQL + c*CHUNK;
    Acs[tid] = AcB[tid];
    __syncthreads();
    float AcL = Acs[CHUNK-1];
    int tp = tid >> 5, tn = tid & 31;
    float acc[8][4] = {};
    const float* bbase = convb + ((size_t)(b*SEQL + c*CHUNK))*CONVD + DI;
    const float* xbase = xdt + ((size_t)(b*SEQL + c*CHUNK))*DI + h*HD;
    for (int l0 = 0; l0 < CHUNK; l0 += 64){
        #pragma unroll
        for (int i = 0; i < 32; i++){
            int e = tid + i*256; int l = e >> 7, n = e & 127;
            Bt[e] = bbase[(size_t)(l0+l)*CONVD + n];
        }
        #pragma unroll
        for (int i = 0; i < 16; i++){
            int e = tid + i*256; int l = e >> 6, p = e & 63;
            wx[e] = expf(AcL - Acs[l0+l]) * xbase[(size_t)(l0+l)*DI + p];
        }
        __syncthreads();
        for (int l = 0; l < 64; l++){
            float4 bv = ((const float4*)(Bt + l*128))[tn];
            #pragma unroll
            for (int i = 0; i < 8; i++){
                float w = wx[l*64 + tp*8 + i];
                acc[i][0] += w*bv.x; acc[i][1] += w*bv.y;
                acc[i][2] += w*bv.z; acc[i][3] += w*bv.w;
            }
        }
        __syncthreads();
    }
    float* outp = states + ((size_t)((b*NC + c)*NHEADS + h))*(HD*DSTATE);
    #pragma unroll
    for (int i = 0; i < 8; i++)
        #pragma unroll
        for (int j = 0; j < 4; j++)
            outp[(size_t)(tp*8+i)*DSTATE + tn*4 + j] = acc[i][j];
}

// ------------------------- inter-chunk recurrence: prev[c] = scan carry (8 steps)
__global__ __launch_bounds__(256) void prev_scan_k(const float* __restrict__ states,
                                                   const float* __restrict__ Acum,
                                                   float* __restrict__ prev){
    int bid = blockIdx.x;                  // B*NHEADS
    int h = bid % NHEADS, b = bid / NHEADS;
    int tid = threadIdx.x;
    const float* AcB = Acum + ((size_t)(b*NHEADS + h))*SEQL;
    float dec[NC];
    #pragma unroll
    for (int c = 0; c < NC; c++) dec[c] = expf(AcB[c*CHUNK + CHUNK-1]);
    for (int j = 0; j < 32; j++){
        int e = tid + j*256;
        float carry = 0.f;
        #pragma unroll
        for (int c = 0; c < NC; c++){
            size_t idx = ((size_t)((b*NC + c)*NHEADS + h))*(HD*DSTATE) + e;
            prev[idx] = carry;
            carry = carry*dec[c] + states[idx];
        }
    }
}

// ================= MFMA SSD output: Y = P@xdt + (e^A C)@prev^T + D*xs (in-place)
#define RLX 264   // xdtT row len (shorts): stride%8==4 -> even bank spread
#define RLP 136   // prev row len (shorts)
__global__ __launch_bounds__(256) void y_mfma_k(const float* __restrict__ convb,
                                                const float* __restrict__ G,
                                                const float* __restrict__ Acum,
                                                const float* __restrict__ prev,
                                                const float* __restrict__ Dp,
                                                float* __restrict__ Y){
    __shared__ ushort_t xdtT[64*RLX];
    __shared__ ushort_t prevs[64*RLP];
    __shared__ float Acs[CHUNK];
    int bid = blockIdx.x;
    int h = bid % NHEADS;
    int c = (bid / NHEADS) % NC;
    int b = bid / (NHEADS*NC);
    int tid = threadIdx.x;
    int lane = tid & 63, wave = tid >> 6;
    int lm = lane & 15, quad = lane >> 4;

    Acs[tid] = Acum[((size_t)(b*NHEADS + h))*SEQL + c*CHUNK + tid];
    {
        const float* pv = prev + ((size_t)((b*NC + c)*NHEADS + h))*(HD*DSTATE);
        #pragma unroll
        for (int i = 0; i < 32; i++){
            int e = tid + i*256; int p = e >> 7, n = e & 127;
            prevs[p*RLP + n] = f2b(pv[e]);
        }
    }
    {
        const float* xg = Y + ((size_t)(b*SEQL + c*CHUNK))*DI + h*HD;
        #pragma unroll
        for (int j8 = 0; j8 < 8; j8++){
            int s0 = wave*64 + j8*8;
            bf16x8 pk;
            #pragma unroll
            for (int j = 0; j < 8; j++)
                pk[j] = (short)f2b(xg[(size_t)(s0+j)*DI + lane]);
            *(bf16x8*)&xdtT[lane*RLX + s0] = pk;
        }
    }
    __syncthreads();

    int   lrow[4];  float Alr[4], eAlr[4];
    #pragma unroll
    for (int mt = 0; mt < 4; mt++){
        lrow[mt] = (mt*4 + wave)*16 + lm;
        Alr[mt]  = Acs[lrow[mt]];
        eAlr[mt] = expf(Alr[mt]);
    }
    const float* Gbase = G + ((size_t)(b*NC + c))*(CHUNK*CHUNK);

    f32x4 acc[4][4];
    #pragma unroll
    for (int i=0;i<4;i++)
        #pragma unroll
        for (int j=0;j<4;j++) acc[i][j] = (f32x4){0.f,0.f,0.f,0.f};

    for (int ks = 0; ks < 8; ks++){
        bf16x8 bfr[4];
        #pragma unroll
        for (int nt = 0; nt < 4; nt++)
            bfr[nt] = *(const bf16x8*)&xdtT[(nt*16+lm)*RLX + ks*32 + quad*8];
        #pragma unroll
        for (int mt = 0; mt < 4; mt++){
            int rblk = mt*4 + wave;
            int nst = rblk/2 + 1;
            if (ks < nst){
                int sbase = ks*32 + quad*8;
                const float4* G4 = (const float4*)(Gbase + (size_t)lrow[mt]*CHUNK + sbase);
                float4 g0 = G4[0], g1 = G4[1];
                const float4* A4 = (const float4*)(&Acs[sbase]);
                float4 a0 = A4[0], a1 = A4[1];
                float Al = Alr[mt]; int l = lrow[mt];
                float pv[8];
                pv[0] = (sbase+0 <= l) ? g0.x*expf(Al - a0.x) : 0.f;
                pv[1] = (sbase+1 <= l) ? g0.y*expf(Al - a0.y) : 0.f;
                pv[2] = (sbase+2 <= l) ? g0.z*expf(Al - a0.z) : 0.f;
                pv[3] = (sbase+3 <= l) ? g0.w*expf(Al - a0.w) : 0.f;
                pv[4] = (sbase+4 <= l) ? g1.x*expf(Al - a1.x) : 0.f;
                pv[5] = (sbase+5 <= l) ? g1.y*expf(Al - a1.y) : 0.f;
                pv[6] = (sbase+6 <= l) ? g1.z*expf(Al - a1.z) : 0.f;
                pv[7] = (sbase+7 <= l) ? g1.w*expf(Al - a1.w) : 0.f;
                bf16x8 af;
                #pragma unroll
                for (int j = 0; j < 8; j++) af[j] = (short)f2b(pv[j]);
                #pragma unroll
                for (int nt = 0; nt < 4; nt++)
                    acc[mt][nt] = __builtin_amdgcn_mfma_f32_16x16x32_bf16(af, bfr[nt], acc[mt][nt], 0, 0, 0);
            }
        }
    }
    for (int kc = 0; kc < 4; kc++){
        bf16x8 bfr[4];
        #pragma unroll
        for (int nt = 0; nt < 4; nt++)
            bfr[nt] = *(const bf16x8*)&prevs[(nt*16+lm)*RLP + kc*32 + quad*8];
        #pragma unroll
        for (int mt = 0; mt < 4; mt++){
            int rowg = b*SEQL + c*CHUNK + lrow[mt];
            const float4* C4 = (const float4*)(convb + (size_t)rowg*CONVD + DI + DSTATE + kc*32 + quad*8);
            float4 c0 = C4[0], c1 = C4[1];
            float e = eAlr[mt];
            bf16x8 af;
            af[0] = (short)f2b(e*c0.x); af[1] = (short)f2b(e*c0.y);
            af[2] = (short)f2b(e*c0.z); af[3] = (short)f2b(e*c0.w);
            af[4] = (short)f2b(e*c1.x); af[5] = (short)f2b(e*c1.y);
            af[6] = (short)f2b(e*c1.z); af[7] = (short)f2b(e*c1.w);
            #pragma unroll
            for (int nt = 0; nt < 4; nt++)
                acc[mt][nt] = __builtin_amdgcn_mfma_f32_16x16x32_bf16(af, bfr[nt], acc[mt][nt], 0, 0, 0);
        }
    }
    float Dv = Dp[h];
    #pragma unroll
    for (int mt = 0; mt < 4; mt++){
        int l0 = (mt*4 + wave)*16 + quad*4;
        #pragma unroll
        for (int nt = 0; nt < 4; nt++){
            int p = nt*16 + lm;
            #pragma unroll
            for (int r = 0; r < 4; r++){
                int rowg = b*SEQL + c*CHUNK + l0 + r;
                float xs = convb[(size_t)rowg*CONVD + h*HD + p];
                Y[(size_t)rowg*DI + h*HD + p] = acc[mt][nt][r] + Dv*xs;
            }
        }
    }
}

// ------------------------------- y = Y*silu(z); RMSNorm; * rms_w ; -> bf16
__global__ __launch_bounds__(256) void gate_rms_k(const float* __restrict__ Yb,
                                                  const float* __restrict__ zx,
                                                  const float* __restrict__ rms_w,
                                                  ushort_t* __restrict__ yn){
    __shared__ float red[4];
    __shared__ float scale_s;
    int row = blockIdx.x; int tid = threadIdx.x;
    float v[8]; float ss = 0.f;
    #pragma unroll
    for (int i = 0; i < 8; i++){
        int d = tid + i*256;
        float g = Yb[(size_t)row*DI + d] * silu_f(zx[(size_t)row*DPROJ + d]);
        v[i] = g; ss += g*g;
    }
    #pragma unroll
    for (int off = 32; off > 0; off >>= 1) ss += __shfl_down(ss, off);
    int lane = tid & 63, wid = tid >> 6;
    if (lane == 0) red[wid] = ss;
    __syncthreads();
    if (tid == 0) scale_s = rsqrtf((red[0]+red[1]+red[2]+red[3])*(1.f/DI) + 1e-12f);
    __syncthreads();
    float sc = scale_s;
    #pragma unroll
    for (int i = 0; i < 8; i++){
        int d = tid + i*256;
        yn[(size_t)row*DI + d] = f2b(v[i]*sc*rms_w[d]);
    }
}

// ----------------------------- LayerNorm(a + resid)*g + b (+ optional bf16 copy)
template<int WB>
__global__ __launch_bounds__(256) void ln_k(const float* __restrict__ a,
                                            const float* __restrict__ resid,
                                            const float* __restrict__ g,
                                            const float* __restrict__ bw,
                                            float* __restrict__ outp,
                                            ushort_t* __restrict__ bfout){
    __shared__ float redA[4], redB[4];
    __shared__ float mu_s, rs_s;
    int row = blockIdx.x; int tid = threadIdx.x;
    float u[4]; float s = 0.f, s2 = 0.f;
    #pragma unroll
    for (int i = 0; i < 4; i++){
        int d = tid + i*256;
        float val = a[(size_t)row*DM + d] + resid[(size_t)row*DM + d];
        u[i] = val; s += val; s2 += val*val;
    }
    #pragma unroll
    for (int off = 32; off > 0; off >>= 1){
        s  += __shfl_down(s,  off);
        s2 += __shfl_down(s2, off);
    }
    int lane = tid & 63, wid = tid >> 6;
    if (lane == 0){ redA[wid] = s; redB[wid] = s2; }
    __syncthreads();
    if (tid == 0){
        float S  = redA[0]+redA[1]+redA[2]+redA[3];
        float S2 = redB[0]+redB[1]+redB[2]+redB[3];
        float mu = S*(1.f/DM);
        float var = S2*(1.f/DM) - mu*mu;
        mu_s = mu; rs_s = rsqrtf(var + 1e-12f);
    }
    __syncthreads();
    float mu = mu_s, rs = rs_s;
    #pragma unroll
    for (int i = 0; i < 4; i++){
        int d = tid + i*256;
        float o = (u[i]-mu)*rs*g[d] + bw[d];
        outp[(size_t)row*DM + d] = o;
        if (WB) bfout[(size_t)row*DM + d] = f2b(o);
    }
}

__global__ __launch_bounds__(256) void copy_td_k(const float* __restrict__ td,
                                                 float* __restrict__ outp){
    int idx = blockIdx.x*256 + threadIdx.x;
    outp[idx] = td[idx];
}

extern "C" void kernel_launch(void* const* d_in, const int* in_sizes, int n_in,
                              void* d_out, int out_size, void* d_ws, size_t ws_size,
                              hipStream_t stream){
    const float* x         = (const float*)d_in[0];
    const float* time_diff = (const float*)d_in[1];
    const float* W_in      = (const float*)d_in[2];
    const float* b_in      = (const float*)d_in[3];
    const float* conv_w    = (const float*)d_in[4];
    const float* conv_b    = (const float*)d_in[5];
    const float* A_log     = (const float*)d_in[6];
    const float* dt_bias   = (const float*)d_in[7];
    const float* Dp        = (const float*)d_in[8];
    const float* time_dec  = (const float*)d_in[9];
    const float* rms_w     = (const float*)d_in[10];
    const float* W_out     = (const float*)d_in[11];
    const float* b_out     = (const float*)d_in[12];
    const float* ln_g      = (const float*)d_in[13];
    const float* ln_b      = (const float*)d_in[14];
    const float* fc1_w     = (const float*)d_in[15];
    const float* fc1_b     = (const float*)d_in[16];
    const float* fc2_w     = (const float*)d_in[17];
    const float* fc2_b     = (const float*)d_in[18];
    const float* ln2_g     = (const float*)d_in[19];
    const float* ln2_b     = (const float*)d_in[20];

    float* ws = (float*)d_ws;
    float* zx    = ws;                       // 17,956,864  region1
    float* convb = zx    + 17956864;         //  9,437,184  region2 (later: hidden)
    float* dt    = convb + 9437184;          //    131,072
    float* Acum  = dt    + 131072;           //    131,072
    float* xdt   = Acum  + 131072;           //  8,388,608  region4 (Y in-place)
    float* r5    = xdt   + 8388608;          //  9,437,184  region5 (G/stat/prev)
    float* hbuf  = r5    + 9437184;          //  4,194,304  region6
    ushort_t* x_bf  = (ushort_t*)xdt;                 // region4 aliases
    ushort_t* WinT  = (ushort_t*)(xdt + 2097152);
    ushort_t* WoutT = (ushort_t*)(xdt + 4194304);
    float*    hid2  = xdt;
    float* Gbuf = r5;                                 // region5 aliases
    float* stat = r5 + 1048576;
    float* prev = stat + 4194304;
    ushort_t* yn_bf = (ushort_t*)r5;
    ushort_t* fc1T  = (ushort_t*)(r5 + 4194304);
    ushort_t* fc2T  = (ushort_t*)(r5 + 6291456);
    ushort_t* mid_bf = (ushort_t*)zx;                 // region1 aliases
    ushort_t* h_bf   = (ushort_t*)(zx + 8388608);
    float* hidden = convb;
    float* outp   = (float*)d_out;

    // 1. bf16 conversions for in-proj
    f2b_k<<<(ROWS*DM)/256, 256, 0, stream>>>(x, x_bf, ROWS*DM);
    transpose_bf_k<<<dim3(4480/32, DM/32), 256, 0, stream>>>(W_in, WinT, DM, DPROJ);
    // 2. in-proj (M=4096,N=4384,K=1024)
    mfma_gemm_k<0,0,128><<<dim3(35, ROWS/128), 256, 0, stream>>>(x_bf, WinT, b_in, zx, nullptr, ROWS, DPROJ, DM, DPROJ);
    // 3. causal conv + SiLU
    conv_silu_k<<<ROWS*CONVD/256, 256, 0, stream>>>(zx, conv_w, conv_b, convb);
    // 4. dt / dA / per-chunk cumsum
    dt_scan_k<<<BATCH*NHEADS*NC, 256, 0, stream>>>(zx, time_diff, A_log, dt_bias, time_dec, dt, Acum);
    // 5. xdt = xs * dt
    xdt_k<<<ROWS*DI/256, 256, 0, stream>>>(convb, dt, xdt);
    // 6. G = C @ B^T per (b,c)
    g_nt_k<<<dim3(4,4,BATCH*NC), 256, 0, stream>>>(convb, Gbuf);
    // 7. per-chunk states
    states_k<<<BATCH*NC*NHEADS, 256, 0, stream>>>(convb, xdt, Acum, stat);
    // 8. inter-chunk scan
    prev_scan_k<<<BATCH*NHEADS, 256, 0, stream>>>(stat, Acum, prev);
    // 9. MFMA SSD output (in place over xdt)
    y_mfma_k<<<BATCH*NC*NHEADS, 256, 0, stream>>>(convb, Gbuf, Acum, prev, Dp, xdt);
    // 10. gate + RMSNorm -> bf16
    gate_rms_k<<<ROWS, 256, 0, stream>>>(xdt, zx, rms_w, yn_bf);
    // 11. W_out transpose
    transpose_bf_k<<<dim3(DM/32, DI/32), 256, 0, stream>>>(W_out, WoutT, DI, DM);
    // 12. out-proj (M=4096,N=1024,K=2048) — BN=64 tile: 512 blocks
    mfma_gemm_k<0,0,64><<<dim3(DM/64, ROWS/128), 256, 0, stream>>>(yn_bf, WoutT, b_out, hidden, nullptr, ROWS, DM, DI, DM);
    // 13. h = LN(hidden + x) + bf16 copy
    ln_k<1><<<ROWS, 256, 0, stream>>>(hidden, x, ln_g, ln_b, hbuf, h_bf);
    // 14. FFN weight transposes
    transpose_bf_k<<<dim3(DFF/32, DM/32), 256, 0, stream>>>(fc1_w, fc1T, DM, DFF);
    transpose_bf_k<<<dim3(DM/32, DFF/32), 256, 0, stream>>>(fc2_w, fc2T, DFF, DM);
    // 15. fc1 + hardswish -> bf16 mid (M=4096,N=4096,K=1024)
    mfma_gemm_k<1,1,128><<<dim3(DFF/128, ROWS/128), 256, 0, stream>>>(h_bf, fc1T, fc1_b, nullptr, mid_bf, ROWS, DFF, DM, DFF);
    // 16. fc2 (M=4096,N=1024,K=4096) — BN=64 tile: 512 blocks
    mfma_gemm_k<0,0,64><<<dim3(DM/64, ROWS/128), 256, 0, stream>>>(mid_bf, fc2T, fc2_b, hid2, nullptr, ROWS, DM, DFF, DM);
    // 17. out = LN(hid2 + h)
    ln_k<0><<<ROWS, 256, 0, stream>>>(hid2, hbuf, ln2_g, ln2_b, outp, nullptr);
    // 18. time_diff passthrough
    copy_td_k<<<ROWS/256, 256, 0, stream>>>(time_diff, outp + (size_t)ROWS*DM);
}

// Round 5
// 537.946 us; speedup vs baseline: 4.6217x; 1.0696x over previous
//
#include <hip/hip_runtime.h>

#define BATCH 2
#define SEQL 2048
#define DM 1024
#define DSTATE 128
#define HD 64
#define CHUNK 256
#define DI 2048
#define NHEADS 32
#define CONVD 2304
#define DPROJ 4384
#define DFF 4096
#define NC 8
#define ROWS (BATCH*SEQL)

typedef unsigned short ushort_t;
typedef short bf16x8 __attribute__((ext_vector_type(8)));
typedef float f32x4 __attribute__((ext_vector_type(4)));

__device__ __forceinline__ float softplus_f(float v){
    return (v > 20.f) ? v : log1pf(expf(v));
}
__device__ __forceinline__ float silu_f(float v){
    return v / (1.f + expf(-v));
}
__device__ __forceinline__ ushort_t f2b(float v){
    union { float f; unsigned int u; } x; x.f = v;
    unsigned int r = x.u + 0x7fffu + ((x.u >> 16) & 1u);
    return (ushort_t)(r >> 16);
}

// ================================================================ MFMA GEMM
// C[M,N] = A[M,K](bf16) @ Bt[N,K](bf16)^T + bias.
// BM=128, BN=TN (128 or 64), BK=64, 256 threads. XOR-swizzled LDS (round-4).
// NS: split-K factor; split z writes Cf + z*M*ldc, bias only on z==0.
template<int ACT, int OUT_BF16, int TN, int NS>
__global__ __launch_bounds__(256) void mfma_gemm_k(
    const ushort_t* __restrict__ A, const ushort_t* __restrict__ Bt,
    const float* __restrict__ bias, float* __restrict__ Cf,
    ushort_t* __restrict__ Cb, int M, int N, int K, int ldc)
{
    constexpr int NT = (TN == 128) ? 4 : 2;
    constexpr int BROWS = TN / 4;
    __shared__ ushort_t As[128*64];
    __shared__ ushort_t Bs[TN*64];
    int tid = threadIdx.x;
    int lane = tid & 63, wave = tid >> 6;
    int m0 = blockIdx.y * 128, n0 = blockIdx.x * TN;
    int Ks = K / NS;
    int kb = (NS > 1) ? blockIdx.z * Ks : 0;
    int wave_m = (TN==128) ? (wave >> 1)*64 : (wave & 1)*64;
    int wave_n = (TN==128) ? (wave & 1)*64 : (wave >> 1)*32;
    int lrow = lane >> 3;
    int lcol = ((lane & 7) ^ lrow) * 8;
    const ushort_t* Abase = A  + (size_t)(m0 + wave*32    + lrow)*K + lcol + kb;
    const ushort_t* Bbase = Bt + (size_t)(n0 + wave*BROWS + lrow)*K + lcol + kb;
    ushort_t* AsW = &As[(wave*32)*64];
    ushort_t* BsW = &Bs[(wave*BROWS)*64];
    f32x4 acc[4][NT];
    #pragma unroll
    for (int i=0;i<4;i++)
        #pragma unroll
        for (int j=0;j<NT;j++) acc[i][j] = (f32x4){0.f,0.f,0.f,0.f};
    int lm = lane & 15;
    int quad = lane >> 4;
    for (int k0 = 0; k0 < Ks; k0 += 64){
        #pragma unroll
        for (int j = 0; j < 4; j++)
            __builtin_amdgcn_global_load_lds(
                (const __attribute__((address_space(1))) void*)(Abase + (size_t)(j*8)*K + k0),
                (__attribute__((address_space(3))) void*)(AsW + j*8*64), 16, 0, 0);
        #pragma unroll
        for (int j = 0; j < BROWS/8; j++)
            __builtin_amdgcn_global_load_lds(
                (const __attribute__((address_space(1))) void*)(Bbase + (size_t)(j*8)*K + k0),
                (__attribute__((address_space(3))) void*)(BsW + j*8*64), 16, 0, 0);
        __syncthreads();
        #pragma unroll
        for (int kk = 0; kk < 64; kk += 32){
            int cb = kk >> 3;
            bf16x8 af[4], bfr[NT];
            #pragma unroll
            for (int mt=0; mt<4; mt++)
                af[mt] = *(const bf16x8*)&As[(wave_m + mt*16 + lm)*64 + (((cb + quad) ^ (lm & 7))*8)];
            #pragma unroll
            for (int nt=0; nt<NT; nt++)
                bfr[nt] = *(const bf16x8*)&Bs[(wave_n + nt*16 + lm)*64 + (((cb + quad) ^ (lm & 7))*8)];
            #pragma unroll
            for (int mt=0; mt<4; mt++)
                #pragma unroll
                for (int nt=0; nt<NT; nt++)
                    acc[mt][nt] = __builtin_amdgcn_mfma_f32_16x16x32_bf16(af[mt], bfr[nt], acc[mt][nt], 0, 0, 0);
        }
        __syncthreads();
    }
    float* Cfo = Cf + (size_t)((NS > 1) ? blockIdx.z : 0) * (size_t)M * ldc;
    int addb = (NS == 1) || (blockIdx.z == 0);
    int crow0 = m0 + wave_m + quad * 4;
    int ccol0 = n0 + wave_n + lm;
    #pragma unroll
    for (int mt=0; mt<4; mt++){
        #pragma unroll
        for (int nt=0; nt<NT; nt++){
            int col = ccol0 + nt*16;
            if (col < N){
                float bv = addb ? bias[col] : 0.f;
                #pragma unroll
                for (int r=0; r<4; r++){
                    int row = crow0 + mt*16 + r;
                    float v = acc[mt][nt][r] + bv;
                    if (ACT == 1){
                        float t = fminf(fmaxf(v + 3.f, 0.f), 6.f);
                        v = v * t * (1.f/6.f);
                    }
                    if (OUT_BF16) Cb[(size_t)row*ldc + col] = f2b(v);
                    else          Cfo[(size_t)row*ldc + col] = v;
                }
            }
        }
    }
}

// -------------------- W[K,N] f32  ->  Wt[Npad,K] bf16 (zero-pad n >= N)
__global__ __launch_bounds__(256) void transpose_bf_k(const float* __restrict__ W,
                                                      ushort_t* __restrict__ Wt,
                                                      int K, int N){
    __shared__ ushort_t tile[32][33];
    int n0 = blockIdx.x*32, k0 = blockIdx.y*32;
    int tx = threadIdx.x & 31, ty = threadIdx.x >> 5;
    #pragma unroll
    for (int i = 0; i < 4; i++){
        int k = k0 + ty + i*8;
        int n = n0 + tx;
        float v = (n < N) ? W[(size_t)k*N + n] : 0.f;
        tile[ty + i*8][tx] = f2b(v);
    }
    __syncthreads();
    #pragma unroll
    for (int i = 0; i < 4; i++){
        Wt[(size_t)(n0 + ty + i*8)*K + k0 + tx] = tile[tx][ty + i*8];
    }
}

__global__ __launch_bounds__(256) void f2b_k(const float* __restrict__ in,
                                             ushort_t* __restrict__ outp, int n){
    int idx = blockIdx.x*256 + threadIdx.x;
    if (idx < n) outp[idx] = f2b(in[idx]);
}

// ----------------- depthwise causal conv + SiLU, fused xdt = xs*dt for c < DI
__global__ __launch_bounds__(256) void conv_silu_k(const float* __restrict__ zx,
                                                   const float* __restrict__ conv_w,
                                                   const float* __restrict__ conv_b,
                                                   const float* __restrict__ dt,
                                                   float* __restrict__ convb,
                                                   float* __restrict__ xdt){
    int idx = blockIdx.x*256 + threadIdx.x;       // ROWS*CONVD total
    int c = idx % CONVD;
    int row = idx / CONVD;
    int t = row & (SEQL-1);
    float acc = conv_b[c];
    #pragma unroll
    for (int k = 0; k < 4; k++){
        int tt = t + k - 3;
        if (tt >= 0)
            acc += zx[((size_t)(row + k - 3))*DPROJ + DI + c] * conv_w[c*4 + k];
    }
    float v = silu_f(acc);
    convb[idx] = v;
    if (c < DI)
        xdt[(size_t)row*DI + c] = v * dt[(size_t)row*NHEADS + (c >> 6)];
}

// --------------------------------- dt = softplus(dt_raw+bias); dA; chunk cumsum
__global__ __launch_bounds__(256) void dt_scan_k(const float* __restrict__ zx,
                                                 const float* __restrict__ time_diff,
                                                 const float* __restrict__ A_log,
                                                 const float* __restrict__ dt_bias,
                                                 const float* __restrict__ time_decay,
                                                 float* __restrict__ dt_out,
                                                 float* __restrict__ Acum){
    __shared__ float s[CHUNK];
    int bid = blockIdx.x;
    int c = bid % NC;
    int h = (bid / NC) % NHEADS;
    int b = bid / (NC*NHEADS);
    int l = threadIdx.x;
    int t = c*CHUNK + l;
    float dtr = zx[((size_t)(b*SEQL + t))*DPROJ + (DPROJ-NHEADS) + h];
    float dtv = softplus_f(dtr + dt_bias[h]);
    float A = -expf(A_log[h]);
    float dA = dtv*A - softplus_f(time_decay[h]) * time_diff[b*SEQL + t];
    dt_out[(size_t)(b*SEQL + t)*NHEADS + h] = dtv;
    s[l] = dA;
    __syncthreads();
    for (int off = 1; off < CHUNK; off <<= 1){
        float v = (l >= off) ? s[l-off] : 0.f;
        __syncthreads();
        s[l] += v;
        __syncthreads();
    }
    Acum[((size_t)(b*NHEADS + h))*SEQL + t] = s[l];
}

// ----------------------------- MFMA G[b,c,l,s] = C_l . B_s  (64x64x128 tiles)
__global__ __launch_bounds__(256) void g_mfma_k(const float* __restrict__ convb,
                                                float* __restrict__ G){
    __shared__ ushort_t As[64*136];
    __shared__ ushort_t Bs[64*136];
    int bc = blockIdx.z;
    int l0 = blockIdx.y*64, s0 = blockIdx.x*64;
    int tid = threadIdx.x;
    int lane = tid & 63, wave = tid >> 6;
    int lm = lane & 15, quad = lane >> 4;
    const float* base = convb + (size_t)bc*CHUNK*CONVD;
    #pragma unroll
    for (int i = 0; i < 32; i++){
        int e = tid + i*256; int r = e >> 7, k = e & 127;
        As[r*136 + k] = f2b(base[(size_t)(l0+r)*CONVD + DI + DSTATE + k]);  // C rows
        Bs[r*136 + k] = f2b(base[(size_t)(s0+r)*CONVD + DI + k]);           // B rows
    }
    __syncthreads();
    f32x4 acc[4];
    #pragma unroll
    for (int j=0;j<4;j++) acc[j] = (f32x4){0.f,0.f,0.f,0.f};
    #pragma unroll
    for (int kk = 0; kk < 4; kk++){
        bf16x8 af = *(const bf16x8*)&As[(wave*16+lm)*136 + kk*32 + quad*8];
        #pragma unroll
        for (int nt = 0; nt < 4; nt++){
            bf16x8 bfr = *(const bf16x8*)&Bs[(nt*16+lm)*136 + kk*32 + quad*8];
            acc[nt] = __builtin_amdgcn_mfma_f32_16x16x32_bf16(af, bfr, acc[nt], 0, 0, 0);
        }
    }
    float* g = G + (size_t)bc*CHUNK*CHUNK;
    #pragma unroll
    for (int nt = 0; nt < 4; nt++)
        #pragma unroll
        for (int r = 0; r < 4; r++)
            g[(size_t)(l0 + wave*16 + quad*4 + r)*CHUNK + s0 + nt*16 + lm] = acc[nt][r];
}

// ---------- MFMA states[b,c,h,p,n] = sum_l B[l,n]*exp(AcL-Ac[l])*xdt[l,p]
#define RSX 264
#define RSB 72
__global__ __launch_bounds__(256) void states_mfma_k(const float* __restrict__ convb,
                                                     const float* __restrict__ xdt,
                                                     const float* __restrict__ Acum,
                                                     float* __restrict__ states){
    __shared__ ushort_t xw[64*RSX];     // [p][l], exp-weighted, 33792 B
    __shared__ ushort_t Bt[128*RSB];    // [n][l-chunk], 18432 B
    __shared__ float Acs[CHUNK];
    int bid = blockIdx.x;
    int h = bid % NHEADS;
    int c = (bid / NHEADS) % NC;
    int b = bid / (NHEADS*NC);
    int tid = threadIdx.x;
    int lane = tid & 63, wave = tid >> 6;
    int lm = lane & 15, quad = lane >> 4;
    Acs[tid] = Acum[((size_t)(b*NHEADS + h))*SEQL + c*CHUNK + tid];
    __syncthreads();
    float AcL = Acs[CHUNK-1];
    // stage exp-weighted xdt^T: lane = p, wave covers l-range wave*64..+64
    {
        const float* xg = xdt + ((size_t)(b*SEQL + c*CHUNK))*DI + h*HD;
        #pragma unroll
        for (int j8 = 0; j8 < 8; j8++){
            int s0 = wave*64 + j8*8;
            bf16x8 pk;
            #pragma unroll
            for (int j = 0; j < 8; j++)
                pk[j] = (short)f2b(expf(AcL - Acs[s0+j]) * xg[(size_t)(s0+j)*DI + lane]);
            *(bf16x8*)&xw[lane*RSX + s0] = pk;
        }
    }
    f32x4 acc[8];
    #pragma unroll
    for (int j=0;j<8;j++) acc[j] = (f32x4){0.f,0.f,0.f,0.f};
    const float* bbase = convb + ((size_t)(b*SEQL + c*CHUNK))*CONVD + DI;
    for (int l0 = 0; l0 < CHUNK; l0 += 64){
        __syncthreads();
        #pragma unroll
        for (int i = 0; i < 32; i++){
            int e = tid + i*256; int l = e >> 7, n = e & 127;
            Bt[n*RSB + l] = f2b(bbase[(size_t)(l0+l)*CONVD + n]);
        }
        __syncthreads();
        #pragma unroll
        for (int kk = 0; kk < 2; kk++){
            bf16x8 af = *(const bf16x8*)&xw[(wave*16+lm)*RSX + l0 + kk*32 + quad*8];
            #pragma unroll
            for (int nt = 0; nt < 8; nt++){
                bf16x8 bfr = *(const bf16x8*)&Bt[(nt*16+lm)*RSB + kk*32 + quad*8];
                acc[nt] = __builtin_amdgcn_mfma_f32_16x16x32_bf16(af, bfr, acc[nt], 0, 0, 0);
            }
        }
    }
    float* outp = states + ((size_t)((b*NC + c)*NHEADS + h))*(HD*DSTATE);
    #pragma unroll
    for (int nt = 0; nt < 8; nt++)
        #pragma unroll
        for (int r = 0; r < 4; r++)
            outp[(size_t)(wave*16 + quad*4 + r)*DSTATE + nt*16 + lm] = acc[nt][r];
}

// ------------------------- inter-chunk recurrence: prev[c] = scan carry (8 steps)
__global__ __launch_bounds__(256) void prev_scan_k(const float* __restrict__ states,
                                                   const float* __restrict__ Acum,
                                                   float* __restrict__ prev){
    int bid = blockIdx.x;                  // B*NHEADS
    int h = bid % NHEADS, b = bid / NHEADS;
    int tid = threadIdx.x;
    const float* AcB = Acum + ((size_t)(b*NHEADS + h))*SEQL;
    float dec[NC];
    #pragma unroll
    for (int c = 0; c < NC; c++) dec[c] = expf(AcB[c*CHUNK + CHUNK-1]);
    for (int j = 0; j < 32; j++){
        int e = tid + j*256;
        float carry = 0.f;
        #pragma unroll
        for (int c = 0; c < NC; c++){
            size_t idx = ((size_t)((b*NC + c)*NHEADS + h))*(HD*DSTATE) + e;
            prev[idx] = carry;
            carry = carry*dec[c] + states[idx];
        }
    }
}

// ================= MFMA SSD output: Y = P@xdt + (e^A C)@prev^T + D*xs (in-place)
#define RLX 264
#define RLP 136
__global__ __launch_bounds__(256) void y_mfma_k(const float* __restrict__ convb,
                                                const float* __restrict__ G,
                                                const float* __restrict__ Acum,
                                                const float* __restrict__ prev,
                                                const float* __restrict__ Dp,
                                                float* __restrict__ Y){
    __shared__ ushort_t xdtT[64*RLX];
    __shared__ ushort_t prevs[64*RLP];
    __shared__ float Acs[CHUNK];
    int bid = blockIdx.x;
    int h = bid % NHEADS;
    int c = (bid / NHEADS) % NC;
    int b = bid / (NHEADS*NC);
    int tid = threadIdx.x;
    int lane = tid & 63, wave = tid >> 6;
    int lm = lane & 15, quad = lane >> 4;

    Acs[tid] = Acum[((size_t)(b*NHEADS + h))*SEQL + c*CHUNK + tid];
    {
        const float* pv = prev + ((size_t)((b*NC + c)*NHEADS + h))*(HD*DSTATE);
        #pragma unroll
        for (int i = 0; i < 32; i++){
            int e = tid + i*256; int p = e >> 7, n = e & 127;
            prevs[p*RLP + n] = f2b(pv[e]);
        }
    }
    {
        const float* xg = Y + ((size_t)(b*SEQL + c*CHUNK))*DI + h*HD;
        #pragma unroll
        for (int j8 = 0; j8 < 8; j8++){
            int s0 = wave*64 + j8*8;
            bf16x8 pk;
            #pragma unroll
            for (int j = 0; j < 8; j++)
                pk[j] = (short)f2b(xg[(size_t)(s0+j)*DI + lane]);
            *(bf16x8*)&xdtT[lane*RLX + s0] = pk;
        }
    }
    __syncthreads();

    int   lrow[4];  float Alr[4], eAlr[4];
    #pragma unroll
    for (int mt = 0; mt < 4; mt++){
        lrow[mt] = (mt*4 + wave)*16 + lm;
        Alr[mt]  = Acs[lrow[mt]];
        eAlr[mt] = expf(Alr[mt]);
    }
    const float* Gbase = G + ((size_t)(b*NC + c))*(CHUNK*CHUNK);

    f32x4 acc[4][4];
    #pragma unroll
    for (int i=0;i<4;i++)
        #pragma unroll
        for (int j=0;j<4;j++) acc[i][j] = (f32x4){0.f,0.f,0.f,0.f};

    for (int ks = 0; ks < 8; ks++){
        bf16x8 bfr[4];
        #pragma unroll
        for (int nt = 0; nt < 4; nt++)
            bfr[nt] = *(const bf16x8*)&xdtT[(nt*16+lm)*RLX + ks*32 + quad*8];
        #pragma unroll
        for (int mt = 0; mt < 4; mt++){
            int rblk = mt*4 + wave;
            int nst = rblk/2 + 1;
            if (ks < nst){
                int sbase = ks*32 + quad*8;
                const float4* G4 = (const float4*)(Gbase + (size_t)lrow[mt]*CHUNK + sbase);
                float4 g0 = G4[0], g1 = G4[1];
                const float4* A4 = (const float4*)(&Acs[sbase]);
                float4 a0 = A4[0], a1 = A4[1];
                float Al = Alr[mt]; int l = lrow[mt];
                float pv[8];
                pv[0] = (sbase+0 <= l) ? g0.x*expf(Al - a0.x) : 0.f;
                pv[1] = (sbase+1 <= l) ? g0.y*expf(Al - a0.y) : 0.f;
                pv[2] = (sbase+2 <= l) ? g0.z*expf(Al - a0.z) : 0.f;
                pv[3] = (sbase+3 <= l) ? g0.w*expf(Al - a0.w) : 0.f;
                pv[4] = (sbase+4 <= l) ? g1.x*expf(Al - a1.x) : 0.f;
                pv[5] = (sbase+5 <= l) ? g1.y*expf(Al - a1.y) : 0.f;
                pv[6] = (sbase+6 <= l) ? g1.z*expf(Al - a1.z) : 0.f;
                pv[7] = (sbase+7 <= l) ? g1.w*expf(Al - a1.w) : 0.f;
                bf16x8 af;
                #pragma unroll
                for (int j = 0; j < 8; j++) af[j] = (short)f2b(pv[j]);
                #pragma unroll
                for (int nt = 0; nt < 4; nt++)
                    acc[mt][nt] = __builtin_amdgcn_mfma_f32_16x16x32_bf16(af, bfr[nt], acc[mt][nt], 0, 0, 0);
            }
        }
    }
    for (int kc = 0; kc < 4; kc++){
        bf16x8 bfr[4];
        #pragma unroll
        for (int nt = 0; nt < 4; nt++)
            bfr[nt] = *(const bf16x8*)&prevs[(nt*16+lm)*RLP + kc*32 + quad*8];
        #pragma unroll
        for (int mt = 0; mt < 4; mt++){
            int rowg = b*SEQL + c*CHUNK + lrow[mt];
            const float4* C4 = (const float4*)(convb + (size_t)rowg*CONVD + DI + DSTATE + kc*32 + quad*8);
            float4 c0 = C4[0], c1 = C4[1];
            float e = eAlr[mt];
            bf16x8 af;
            af[0] = (short)f2b(e*c0.x); af[1] = (short)f2b(e*c0.y);
            af[2] = (short)f2b(e*c0.z); af[3] = (short)f2b(e*c0.w);
            af[4] = (short)f2b(e*c1.x); af[5] = (short)f2b(e*c1.y);
            af[6] = (short)f2b(e*c1.z); af[7] = (short)f2b(e*c1.w);
            #pragma unroll
            for (int nt = 0; nt < 4; nt++)
                acc[mt][nt] = __builtin_amdgcn_mfma_f32_16x16x32_bf16(af, bfr[nt], acc[mt][nt], 0, 0, 0);
        }
    }
    float Dv = Dp[h];
    #pragma unroll
    for (int mt = 0; mt < 4; mt++){
        int l0 = (mt*4 + wave)*16 + quad*4;
        #pragma unroll
        for (int nt = 0; nt < 4; nt++){
            int p = nt*16 + lm;
            #pragma unroll
            for (int r = 0; r < 4; r++){
                int rowg = b*SEQL + c*CHUNK + l0 + r;
                float xs = convb[(size_t)rowg*CONVD + h*HD + p];
                Y[(size_t)rowg*DI + h*HD + p] = acc[mt][nt][r] + Dv*xs;
            }
        }
    }
}

// ------------------------------- y = Y*silu(z); RMSNorm; * rms_w ; -> bf16
__global__ __launch_bounds__(256) void gate_rms_k(const float* __restrict__ Yb,
                                                  const float* __restrict__ zx,
                                                  const float* __restrict__ rms_w,
                                                  ushort_t* __restrict__ yn){
    __shared__ float red[4];
    __shared__ float scale_s;
    int row = blockIdx.x; int tid = threadIdx.x;
    float v[8]; float ss = 0.f;
    #pragma unroll
    for (int i = 0; i < 8; i++){
        int d = tid + i*256;
        float g = Yb[(size_t)row*DI + d] * silu_f(zx[(size_t)row*DPROJ + d]);
        v[i] = g; ss += g*g;
    }
    #pragma unroll
    for (int off = 32; off > 0; off >>= 1) ss += __shfl_down(ss, off);
    int lane = tid & 63, wid = tid >> 6;
    if (lane == 0) red[wid] = ss;
    __syncthreads();
    if (tid == 0) scale_s = rsqrtf((red[0]+red[1]+red[2]+red[3])*(1.f/DI) + 1e-12f);
    __syncthreads();
    float sc = scale_s;
    #pragma unroll
    for (int i = 0; i < 8; i++){
        int d = tid + i*256;
        yn[(size_t)row*DI + d] = f2b(v[i]*sc*rms_w[d]);
    }
}

// -------- LayerNorm(a [+ a2] + resid)*g + b (+ optional bf16 copy)
template<int WB, int TWO>
__global__ __launch_bounds__(256) void ln_k(const float* __restrict__ a,
                                            const float* __restrict__ a2,
                                            const float* __restrict__ resid,
                                            const float* __restrict__ g,
                                            const float* __restrict__ bw,
                                            float* __restrict__ outp,
                                            ushort_t* __restrict__ bfout){
    __shared__ float redA[4], redB[4];
    __shared__ float mu_s, rs_s;
    int row = blockIdx.x; int tid = threadIdx.x;
    float u[4]; float s = 0.f, s2 = 0.f;
    #pragma unroll
    for (int i = 0; i < 4; i++){
        int d = tid + i*256;
        float val = a[(size_t)row*DM + d] + resid[(size_t)row*DM + d];
        if (TWO) val += a2[(size_t)row*DM + d];
        u[i] = val; s += val; s2 += val*val;
    }
    #pragma unroll
    for (int off = 32; off > 0; off >>= 1){
        s  += __shfl_down(s,  off);
        s2 += __shfl_down(s2, off);
    }
    int lane = tid & 63, wid = tid >> 6;
    if (lane == 0){ redA[wid] = s; redB[wid] = s2; }
    __syncthreads();
    if (tid == 0){
        float S  = redA[0]+redA[1]+redA[2]+redA[3];
        float S2 = redB[0]+redB[1]+redB[2]+redB[3];
        float mu = S*(1.f/DM);
        float var = S2*(1.f/DM) - mu*mu;
        mu_s = mu; rs_s = rsqrtf(var + 1e-12f);
    }
    __syncthreads();
    float mu = mu_s, rs = rs_s;
    #pragma unroll
    for (int i = 0; i < 4; i++){
        int d = tid + i*256;
        float o = (u[i]-mu)*rs*g[d] + bw[d];
        outp[(size_t)row*DM + d] = o;
        if (WB) bfout[(size_t)row*DM + d] = f2b(o);
    }
}

__global__ __launch_bounds__(256) void copy_td_k(const float* __restrict__ td,
                                                 float* __restrict__ outp){
    int idx = blockIdx.x*256 + threadIdx.x;
    outp[idx] = td[idx];
}

extern "C" void kernel_launch(void* const* d_in, const int* in_sizes, int n_in,
                              void* d_out, int out_size, void* d_ws, size_t ws_size,
                              hipStream_t stream){
    const float* x         = (const float*)d_in[0];
    const float* time_diff = (const float*)d_in[1];
    const float* W_in      = (const float*)d_in[2];
    const float* b_in      = (const float*)d_in[3];
    const float* conv_w    = (const float*)d_in[4];
    const float* conv_b    = (const float*)d_in[5];
    const float* A_log     = (const float*)d_in[6];
    const float* dt_bias   = (const float*)d_in[7];
    const float* Dp        = (const float*)d_in[8];
    const float* time_dec  = (const float*)d_in[9];
    const float* rms_w     = (const float*)d_in[10];
    const float* W_out     = (const float*)d_in[11];
    const float* b_out     = (const float*)d_in[12];
    const float* ln_g      = (const float*)d_in[13];
    const float* ln_b      = (const float*)d_in[14];
    const float* fc1_w     = (const float*)d_in[15];
    const float* fc1_b     = (const float*)d_in[16];
    const float* fc2_w     = (const float*)d_in[17];
    const float* fc2_b     = (const float*)d_in[18];
    const float* ln2_g     = (const float*)d_in[19];
    const float* ln2_b     = (const float*)d_in[20];

    float* ws = (float*)d_ws;
    float* zx    = ws;                       // 17,956,864  region1
    float* convb = zx    + 17956864;         //  9,437,184  region2 (later: out-proj partials)
    float* dt    = convb + 9437184;          //    131,072
    float* Acum  = dt    + 131072;           //    131,072
    float* xdt   = Acum  + 131072;           //  8,388,608  region4 (Y in-place; later fc2 partials)
    float* r5    = xdt   + 8388608;          //  9,437,184  region5
    float* hbuf  = r5    + 9437184;          //  4,194,304  region6
    ushort_t* x_bf  = (ushort_t*)xdt;
    ushort_t* WinT  = (ushort_t*)(xdt + 2097152);
    ushort_t* WoutT = (ushort_t*)(xdt + 4194304);
    float* fc2Pa = xdt;                               // fc2 split partials
    float* Gbuf = r5;
    float* stat = r5 + 1048576;
    float* prev = stat + 4194304;
    ushort_t* yn_bf = (ushort_t*)r5;
    ushort_t* fc1T  = (ushort_t*)(r5 + 4194304);
    ushort_t* fc2T  = (ushort_t*)(r5 + 6291456);
    ushort_t* mid_bf = (ushort_t*)zx;
    ushort_t* h_bf   = (ushort_t*)(zx + 8388608);
    float* outPa  = convb;                            // out-proj split partials
    float* outp   = (float*)d_out;

    // 1. bf16 conversions for in-proj
    f2b_k<<<(ROWS*DM)/256, 256, 0, stream>>>(x, x_bf, ROWS*DM);
    transpose_bf_k<<<dim3(4480/32, DM/32), 256, 0, stream>>>(W_in, WinT, DM, DPROJ);
    // 2. in-proj (M=4096,N=4384,K=1024)
    mfma_gemm_k<0,0,128,1><<<dim3(35, ROWS/128), 256, 0, stream>>>(x_bf, WinT, b_in, zx, nullptr, ROWS, DPROJ, DM, DPROJ);
    // 3. dt / dA / per-chunk cumsum (before conv: conv needs dt)
    dt_scan_k<<<BATCH*NHEADS*NC, 256, 0, stream>>>(zx, time_diff, A_log, dt_bias, time_dec, dt, Acum);
    // 4. causal conv + SiLU + fused xdt
    conv_silu_k<<<ROWS*CONVD/256, 256, 0, stream>>>(zx, conv_w, conv_b, dt, convb, xdt);
    // 5. G = C @ B^T per (b,c) — MFMA
    g_mfma_k<<<dim3(4,4,BATCH*NC), 256, 0, stream>>>(convb, Gbuf);
    // 6. per-chunk states — MFMA
    states_mfma_k<<<BATCH*NC*NHEADS, 256, 0, stream>>>(convb, xdt, Acum, stat);
    // 7. inter-chunk scan
    prev_scan_k<<<BATCH*NHEADS, 256, 0, stream>>>(stat, Acum, prev);
    // 8. MFMA SSD output (in place over xdt)
    y_mfma_k<<<BATCH*NC*NHEADS, 256, 0, stream>>>(convb, Gbuf, Acum, prev, Dp, xdt);
    // 9. gate + RMSNorm -> bf16
    gate_rms_k<<<ROWS, 256, 0, stream>>>(xdt, zx, rms_w, yn_bf);
    // 10. W_out transpose
    transpose_bf_k<<<dim3(DM/32, DI/32), 256, 0, stream>>>(W_out, WoutT, DI, DM);
    // 11. out-proj split-K=2 (M=4096,N=1024,K=2048) -> partials in convb
    mfma_gemm_k<0,0,64,2><<<dim3(DM/64, ROWS/128, 2), 256, 0, stream>>>(yn_bf, WoutT, b_out, outPa, nullptr, ROWS, DM, DI, DM);
    // 12. h = LN(Pa + Pb + x) + bf16 copy
    ln_k<1,1><<<ROWS, 256, 0, stream>>>(outPa, outPa + (size_t)ROWS*DM, x, ln_g, ln_b, hbuf, h_bf);
    // 13. FFN weight transposes
    transpose_bf_k<<<dim3(DFF/32, DM/32), 256, 0, stream>>>(fc1_w, fc1T, DM, DFF);
    transpose_bf_k<<<dim3(DM/32, DFF/32), 256, 0, stream>>>(fc2_w, fc2T, DFF, DM);
    // 14. fc1 + hardswish -> bf16 mid (M=4096,N=4096,K=1024)
    mfma_gemm_k<1,1,128,1><<<dim3(DFF/128, ROWS/128), 256, 0, stream>>>(h_bf, fc1T, fc1_b, nullptr, mid_bf, ROWS, DFF, DM, DFF);
    // 15. fc2 split-K=2 (M=4096,N=1024,K=4096) -> partials in xdt region
    mfma_gemm_k<0,0,64,2><<<dim3(DM/64, ROWS/128, 2), 256, 0, stream>>>(mid_bf, fc2T, fc2_b, fc2Pa, nullptr, ROWS, DM, DFF, DM);
    // 16. out = LN(Pa + Pb + h)
    ln_k<0,1><<<ROWS, 256, 0, stream>>>(fc2Pa, fc2Pa + (size_t)ROWS*DM, hbuf, ln2_g, ln2_b, outp, nullptr);
    // 17. time_diff passthrough
    copy_td_k<<<ROWS/256, 256, 0, stream>>>(time_diff, outp + (size_t)ROWS*DM);
}

// Round 6
// 523.805 us; speedup vs baseline: 4.7465x; 1.0270x over previous
//
#include <hip/hip_runtime.h>

#define BATCH 2
#define SEQL 2048
#define DM 1024
#define DSTATE 128
#define HD 64
#define CHUNK 256
#define DI 2048
#define NHEADS 32
#define CONVD 2304
#define DPROJ 4384
#define DFF 4096
#define NC 8
#define ROWS (BATCH*SEQL)

typedef unsigned short ushort_t;
typedef short bf16x8 __attribute__((ext_vector_type(8)));
typedef float f32x4 __attribute__((ext_vector_type(4)));

__device__ __forceinline__ float softplus_f(float v){
    return (v > 20.f) ? v : log1pf(expf(v));
}
__device__ __forceinline__ float silu_f(float v){
    return v / (1.f + expf(-v));
}
__device__ __forceinline__ ushort_t f2b(float v){
    union { float f; unsigned int u; } x; x.f = v;
    unsigned int r = x.u + 0x7fffu + ((x.u >> 16) & 1u);
    return (ushort_t)(r >> 16);
}
__device__ __forceinline__ float b2f(ushort_t v){
    union { unsigned int u; float f; } x; x.u = ((unsigned int)v) << 16;
    return x.f;
}

// ================================================================ MFMA GEMM
// C[M,N] = A[M,K](bf16) @ Bt[N,K](bf16)^T + bias.
// BM=128, BN=TN (128 or 64), BK=64, 256 threads. XOR-swizzled LDS (round-4).
// NS: split-K; DTX: also write fp32 sidecar for cols >= N-NHEADS (dt_raw).
template<int ACT, int OUT_BF16, int TN, int NS, int DTX>
__global__ __launch_bounds__(256) void mfma_gemm_k(
    const ushort_t* __restrict__ A, const ushort_t* __restrict__ Bt,
    const float* __restrict__ bias, float* __restrict__ Cf,
    ushort_t* __restrict__ Cb, float* __restrict__ dtaux,
    int M, int N, int K, int ldc)
{
    constexpr int NT = (TN == 128) ? 4 : 2;
    constexpr int BROWS = TN / 4;
    __shared__ ushort_t As[128*64];
    __shared__ ushort_t Bs[TN*64];
    int tid = threadIdx.x;
    int lane = tid & 63, wave = tid >> 6;
    int m0 = blockIdx.y * 128, n0 = blockIdx.x * TN;
    int Ks = K / NS;
    int kb = (NS > 1) ? blockIdx.z * Ks : 0;
    int wave_m = (TN==128) ? (wave >> 1)*64 : (wave & 1)*64;
    int wave_n = (TN==128) ? (wave & 1)*64 : (wave >> 1)*32;
    int lrow = lane >> 3;
    int lcol = ((lane & 7) ^ lrow) * 8;
    const ushort_t* Abase = A  + (size_t)(m0 + wave*32    + lrow)*K + lcol + kb;
    const ushort_t* Bbase = Bt + (size_t)(n0 + wave*BROWS + lrow)*K + lcol + kb;
    ushort_t* AsW = &As[(wave*32)*64];
    ushort_t* BsW = &Bs[(wave*BROWS)*64];
    f32x4 acc[4][NT];
    #pragma unroll
    for (int i=0;i<4;i++)
        #pragma unroll
        for (int j=0;j<NT;j++) acc[i][j] = (f32x4){0.f,0.f,0.f,0.f};
    int lm = lane & 15;
    int quad = lane >> 4;
    for (int k0 = 0; k0 < Ks; k0 += 64){
        #pragma unroll
        for (int j = 0; j < 4; j++)
            __builtin_amdgcn_global_load_lds(
                (const __attribute__((address_space(1))) void*)(Abase + (size_t)(j*8)*K + k0),
                (__attribute__((address_space(3))) void*)(AsW + j*8*64), 16, 0, 0);
        #pragma unroll
        for (int j = 0; j < BROWS/8; j++)
            __builtin_amdgcn_global_load_lds(
                (const __attribute__((address_space(1))) void*)(Bbase + (size_t)(j*8)*K + k0),
                (__attribute__((address_space(3))) void*)(BsW + j*8*64), 16, 0, 0);
        __syncthreads();
        #pragma unroll
        for (int kk = 0; kk < 64; kk += 32){
            int cb = kk >> 3;
            bf16x8 af[4], bfr[NT];
            #pragma unroll
            for (int mt=0; mt<4; mt++)
                af[mt] = *(const bf16x8*)&As[(wave_m + mt*16 + lm)*64 + (((cb + quad) ^ (lm & 7))*8)];
            #pragma unroll
            for (int nt=0; nt<NT; nt++)
                bfr[nt] = *(const bf16x8*)&Bs[(wave_n + nt*16 + lm)*64 + (((cb + quad) ^ (lm & 7))*8)];
            #pragma unroll
            for (int mt=0; mt<4; mt++)
                #pragma unroll
                for (int nt=0; nt<NT; nt++)
                    acc[mt][nt] = __builtin_amdgcn_mfma_f32_16x16x32_bf16(af[mt], bfr[nt], acc[mt][nt], 0, 0, 0);
        }
        __syncthreads();
    }
    float* Cfo = Cf + (size_t)((NS > 1) ? blockIdx.z : 0) * (size_t)M * ldc;
    int addb = (NS == 1) || (blockIdx.z == 0);
    int crow0 = m0 + wave_m + quad * 4;
    int ccol0 = n0 + wave_n + lm;
    #pragma unroll
    for (int mt=0; mt<4; mt++){
        #pragma unroll
        for (int nt=0; nt<NT; nt++){
            int col = ccol0 + nt*16;
            if (col < N){
                float bv = addb ? bias[col] : 0.f;
                #pragma unroll
                for (int r=0; r<4; r++){
                    int row = crow0 + mt*16 + r;
                    float v = acc[mt][nt][r] + bv;
                    if (ACT == 1){
                        float t = fminf(fmaxf(v + 3.f, 0.f), 6.f);
                        v = v * t * (1.f/6.f);
                    }
                    if (OUT_BF16){
                        Cb[(size_t)row*ldc + col] = f2b(v);
                        if (DTX && col >= N - NHEADS)
                            dtaux[(size_t)row*NHEADS + (col - (N - NHEADS))] = v;
                    } else {
                        Cfo[(size_t)row*ldc + col] = v;
                    }
                }
            }
        }
    }
}

// -------------------- W[K,N] f32  ->  Wt[Npad,K] bf16 (zero-pad n >= N)
__global__ __launch_bounds__(256) void transpose_bf_k(const float* __restrict__ W,
                                                      ushort_t* __restrict__ Wt,
                                                      int K, int N){
    __shared__ ushort_t tile[32][33];
    int n0 = blockIdx.x*32, k0 = blockIdx.y*32;
    int tx = threadIdx.x & 31, ty = threadIdx.x >> 5;
    #pragma unroll
    for (int i = 0; i < 4; i++){
        int k = k0 + ty + i*8;
        int n = n0 + tx;
        float v = (n < N) ? W[(size_t)k*N + n] : 0.f;
        tile[ty + i*8][tx] = f2b(v);
    }
    __syncthreads();
    #pragma unroll
    for (int i = 0; i < 4; i++){
        Wt[(size_t)(n0 + ty + i*8)*K + k0 + tx] = tile[tx][ty + i*8];
    }
}

__global__ __launch_bounds__(256) void f2b_k(const float* __restrict__ in,
                                             ushort_t* __restrict__ outp, int n){
    int idx = blockIdx.x*256 + threadIdx.x;
    if (idx < n) outp[idx] = f2b(in[idx]);
}

// ----------------- depthwise causal conv + SiLU, fused xdt = xs*dt for c < DI
__global__ __launch_bounds__(256) void conv_silu_k(const ushort_t* __restrict__ zx,
                                                   const float* __restrict__ conv_w,
                                                   const float* __restrict__ conv_b,
                                                   const float* __restrict__ dt,
                                                   float* __restrict__ convb,
                                                   float* __restrict__ xdt){
    int idx = blockIdx.x*256 + threadIdx.x;       // ROWS*CONVD total
    int c = idx % CONVD;
    int row = idx / CONVD;
    int t = row & (SEQL-1);
    float acc = conv_b[c];
    #pragma unroll
    for (int k = 0; k < 4; k++){
        int tt = t + k - 3;
        if (tt >= 0)
            acc += b2f(zx[((size_t)(row + k - 3))*DPROJ + DI + c]) * conv_w[c*4 + k];
    }
    float v = silu_f(acc);
    convb[idx] = v;
    if (c < DI)
        xdt[(size_t)row*DI + c] = v * dt[(size_t)row*NHEADS + (c >> 6)];
}

// ------------------ dt = softplus(dtaux+bias); dA; chunk cumsum (dtaux fp32)
__global__ __launch_bounds__(256) void dt_scan_k(const float* __restrict__ dtaux,
                                                 const float* __restrict__ time_diff,
                                                 const float* __restrict__ A_log,
                                                 const float* __restrict__ dt_bias,
                                                 const float* __restrict__ time_decay,
                                                 float* __restrict__ dt_out,
                                                 float* __restrict__ Acum){
    __shared__ float s[CHUNK];
    int bid = blockIdx.x;
    int c = bid % NC;
    int h = (bid / NC) % NHEADS;
    int b = bid / (NC*NHEADS);
    int l = threadIdx.x;
    int t = c*CHUNK + l;
    float dtr = dtaux[((size_t)(b*SEQL + t))*NHEADS + h];
    float dtv = softplus_f(dtr + dt_bias[h]);
    float A = -expf(A_log[h]);
    float dA = dtv*A - softplus_f(time_decay[h]) * time_diff[b*SEQL + t];
    dt_out[(size_t)(b*SEQL + t)*NHEADS + h] = dtv;
    s[l] = dA;
    __syncthreads();
    for (int off = 1; off < CHUNK; off <<= 1){
        float v = (l >= off) ? s[l-off] : 0.f;
        __syncthreads();
        s[l] += v;
        __syncthreads();
    }
    Acum[((size_t)(b*NHEADS + h))*SEQL + t] = s[l];
}

// ----------------------------- MFMA G[b,c,l,s] = C_l . B_s  (64x64x128 tiles)
__global__ __launch_bounds__(256) void g_mfma_k(const float* __restrict__ convb,
                                                float* __restrict__ G){
    __shared__ ushort_t As[64*136];
    __shared__ ushort_t Bs[64*136];
    int bc = blockIdx.z;
    int l0 = blockIdx.y*64, s0 = blockIdx.x*64;
    int tid = threadIdx.x;
    int lane = tid & 63, wave = tid >> 6;
    int lm = lane & 15, quad = lane >> 4;
    const float* base = convb + (size_t)bc*CHUNK*CONVD;
    #pragma unroll
    for (int i = 0; i < 32; i++){
        int e = tid + i*256; int r = e >> 7, k = e & 127;
        As[r*136 + k] = f2b(base[(size_t)(l0+r)*CONVD + DI + DSTATE + k]);  // C rows
        Bs[r*136 + k] = f2b(base[(size_t)(s0+r)*CONVD + DI + k]);           // B rows
    }
    __syncthreads();
    f32x4 acc[4];
    #pragma unroll
    for (int j=0;j<4;j++) acc[j] = (f32x4){0.f,0.f,0.f,0.f};
    #pragma unroll
    for (int kk = 0; kk < 4; kk++){
        bf16x8 af = *(const bf16x8*)&As[(wave*16+lm)*136 + kk*32 + quad*8];
        #pragma unroll
        for (int nt = 0; nt < 4; nt++){
            bf16x8 bfr = *(const bf16x8*)&Bs[(nt*16+lm)*136 + kk*32 + quad*8];
            acc[nt] = __builtin_amdgcn_mfma_f32_16x16x32_bf16(af, bfr, acc[nt], 0, 0, 0);
        }
    }
    float* g = G + (size_t)bc*CHUNK*CHUNK;
    #pragma unroll
    for (int nt = 0; nt < 4; nt++)
        #pragma unroll
        for (int r = 0; r < 4; r++)
            g[(size_t)(l0 + wave*16 + quad*4 + r)*CHUNK + s0 + nt*16 + lm] = acc[nt][r];
}

// ---------- MFMA states[b,c,h,p,n] = sum_l B[l,n]*exp(AcL-Ac[l])*xdt[l,p]
#define RSX 264
#define RSB 72
__global__ __launch_bounds__(256) void states_mfma_k(const float* __restrict__ convb,
                                                     const float* __restrict__ xdt,
                                                     const float* __restrict__ Acum,
                                                     float* __restrict__ states){
    __shared__ ushort_t xw[64*RSX];
    __shared__ ushort_t Bt[128*RSB];
    __shared__ float Acs[CHUNK];
    int bid = blockIdx.x;
    int h = bid % NHEADS;
    int c = (bid / NHEADS) % NC;
    int b = bid / (NHEADS*NC);
    int tid = threadIdx.x;
    int lane = tid & 63, wave = tid >> 6;
    int lm = lane & 15, quad = lane >> 4;
    Acs[tid] = Acum[((size_t)(b*NHEADS + h))*SEQL + c*CHUNK + tid];
    __syncthreads();
    float AcL = Acs[CHUNK-1];
    {
        const float* xg = xdt + ((size_t)(b*SEQL + c*CHUNK))*DI + h*HD;
        #pragma unroll
        for (int j8 = 0; j8 < 8; j8++){
            int s0 = wave*64 + j8*8;
            bf16x8 pk;
            #pragma unroll
            for (int j = 0; j < 8; j++)
                pk[j] = (short)f2b(expf(AcL - Acs[s0+j]) * xg[(size_t)(s0+j)*DI + lane]);
            *(bf16x8*)&xw[lane*RSX + s0] = pk;
        }
    }
    f32x4 acc[8];
    #pragma unroll
    for (int j=0;j<8;j++) acc[j] = (f32x4){0.f,0.f,0.f,0.f};
    const float* bbase = convb + ((size_t)(b*SEQL + c*CHUNK))*CONVD + DI;
    for (int l0 = 0; l0 < CHUNK; l0 += 64){
        __syncthreads();
        #pragma unroll
        for (int i = 0; i < 32; i++){
            int e = tid + i*256; int l = e >> 7, n = e & 127;
            Bt[n*RSB + l] = f2b(bbase[(size_t)(l0+l)*CONVD + n]);
        }
        __syncthreads();
        #pragma unroll
        for (int kk = 0; kk < 2; kk++){
            bf16x8 af = *(const bf16x8*)&xw[(wave*16+lm)*RSX + l0 + kk*32 + quad*8];
            #pragma unroll
            for (int nt = 0; nt < 8; nt++){
                bf16x8 bfr = *(const bf16x8*)&Bt[(nt*16+lm)*RSB + kk*32 + quad*8];
                acc[nt] = __builtin_amdgcn_mfma_f32_16x16x32_bf16(af, bfr, acc[nt], 0, 0, 0);
            }
        }
    }
    float* outp = states + ((size_t)((b*NC + c)*NHEADS + h))*(HD*DSTATE);
    #pragma unroll
    for (int nt = 0; nt < 8; nt++)
        #pragma unroll
        for (int r = 0; r < 4; r++)
            outp[(size_t)(wave*16 + quad*4 + r)*DSTATE + nt*16 + lm] = acc[nt][r];
}

// ------------------------- inter-chunk recurrence: prev[c] = scan carry (8 steps)
__global__ __launch_bounds__(256) void prev_scan_k(const float* __restrict__ states,
                                                   const float* __restrict__ Acum,
                                                   float* __restrict__ prev){
    int bid = blockIdx.x;
    int h = bid % NHEADS, b = bid / NHEADS;
    int tid = threadIdx.x;
    const float* AcB = Acum + ((size_t)(b*NHEADS + h))*SEQL;
    float dec[NC];
    #pragma unroll
    for (int c = 0; c < NC; c++) dec[c] = expf(AcB[c*CHUNK + CHUNK-1]);
    for (int j = 0; j < 32; j++){
        int e = tid + j*256;
        float carry = 0.f;
        #pragma unroll
        for (int c = 0; c < NC; c++){
            size_t idx = ((size_t)((b*NC + c)*NHEADS + h))*(HD*DSTATE) + e;
            prev[idx] = carry;
            carry = carry*dec[c] + states[idx];
        }
    }
}

// ================= MFMA SSD output: Y = P@xdt + (e^A C)@prev^T + D*xs (in-place)
#define RLX 264
#define RLP 136
__global__ __launch_bounds__(256) void y_mfma_k(const float* __restrict__ convb,
                                                const float* __restrict__ G,
                                                const float* __restrict__ Acum,
                                                const float* __restrict__ prev,
                                                const float* __restrict__ Dp,
                                                float* __restrict__ Y){
    __shared__ ushort_t xdtT[64*RLX];
    __shared__ ushort_t prevs[64*RLP];
    __shared__ float Acs[CHUNK];
    int bid = blockIdx.x;
    int h = bid % NHEADS;
    int c = (bid / NHEADS) % NC;
    int b = bid / (NHEADS*NC);
    int tid = threadIdx.x;
    int lane = tid & 63, wave = tid >> 6;
    int lm = lane & 15, quad = lane >> 4;

    Acs[tid] = Acum[((size_t)(b*NHEADS + h))*SEQL + c*CHUNK + tid];
    {
        const float* pv = prev + ((size_t)((b*NC + c)*NHEADS + h))*(HD*DSTATE);
        #pragma unroll
        for (int i = 0; i < 32; i++){
            int e = tid + i*256; int p = e >> 7, n = e & 127;
            prevs[p*RLP + n] = f2b(pv[e]);
        }
    }
    {
        const float* xg = Y + ((size_t)(b*SEQL + c*CHUNK))*DI + h*HD;
        #pragma unroll
        for (int j8 = 0; j8 < 8; j8++){
            int s0 = wave*64 + j8*8;
            bf16x8 pk;
            #pragma unroll
            for (int j = 0; j < 8; j++)
                pk[j] = (short)f2b(xg[(size_t)(s0+j)*DI + lane]);
            *(bf16x8*)&xdtT[lane*RLX + s0] = pk;
        }
    }
    __syncthreads();

    int   lrow[4];  float Alr[4], eAlr[4];
    #pragma unroll
    for (int mt = 0; mt < 4; mt++){
        lrow[mt] = (mt*4 + wave)*16 + lm;
        Alr[mt]  = Acs[lrow[mt]];
        eAlr[mt] = expf(Alr[mt]);
    }
    const float* Gbase = G + ((size_t)(b*NC + c))*(CHUNK*CHUNK);

    f32x4 acc[4][4];
    #pragma unroll
    for (int i=0;i<4;i++)
        #pragma unroll
        for (int j=0;j<4;j++) acc[i][j] = (f32x4){0.f,0.f,0.f,0.f};

    for (int ks = 0; ks < 8; ks++){
        bf16x8 bfr[4];
        #pragma unroll
        for (int nt = 0; nt < 4; nt++)
            bfr[nt] = *(const bf16x8*)&xdtT[(nt*16+lm)*RLX + ks*32 + quad*8];
        #pragma unroll
        for (int mt = 0; mt < 4; mt++){
            int rblk = mt*4 + wave;
            int nst = rblk/2 + 1;
            if (ks < nst){
                int sbase = ks*32 + quad*8;
                const float4* G4 = (const float4*)(Gbase + (size_t)lrow[mt]*CHUNK + sbase);
                float4 g0 = G4[0], g1 = G4[1];
                const float4* A4 = (const float4*)(&Acs[sbase]);
                float4 a0 = A4[0], a1 = A4[1];
                float Al = Alr[mt]; int l = lrow[mt];
                float pv[8];
                pv[0] = (sbase+0 <= l) ? g0.x*expf(Al - a0.x) : 0.f;
                pv[1] = (sbase+1 <= l) ? g0.y*expf(Al - a0.y) : 0.f;
                pv[2] = (sbase+2 <= l) ? g0.z*expf(Al - a0.z) : 0.f;
                pv[3] = (sbase+3 <= l) ? g0.w*expf(Al - a0.w) : 0.f;
                pv[4] = (sbase+4 <= l) ? g1.x*expf(Al - a1.x) : 0.f;
                pv[5] = (sbase+5 <= l) ? g1.y*expf(Al - a1.y) : 0.f;
                pv[6] = (sbase+6 <= l) ? g1.z*expf(Al - a1.z) : 0.f;
                pv[7] = (sbase+7 <= l) ? g1.w*expf(Al - a1.w) : 0.f;
                bf16x8 af;
                #pragma unroll
                for (int j = 0; j < 8; j++) af[j] = (short)f2b(pv[j]);
                #pragma unroll
                for (int nt = 0; nt < 4; nt++)
                    acc[mt][nt] = __builtin_amdgcn_mfma_f32_16x16x32_bf16(af, bfr[nt], acc[mt][nt], 0, 0, 0);
            }
        }
    }
    for (int kc = 0; kc < 4; kc++){
        bf16x8 bfr[4];
        #pragma unroll
        for (int nt = 0; nt < 4; nt++)
            bfr[nt] = *(const bf16x8*)&prevs[(nt*16+lm)*RLP + kc*32 + quad*8];
        #pragma unroll
        for (int mt = 0; mt < 4; mt++){
            int rowg = b*SEQL + c*CHUNK + lrow[mt];
            const float4* C4 = (const float4*)(convb + (size_t)rowg*CONVD + DI + DSTATE + kc*32 + quad*8);
            float4 c0 = C4[0], c1 = C4[1];
            float e = eAlr[mt];
            bf16x8 af;
            af[0] = (short)f2b(e*c0.x); af[1] = (short)f2b(e*c0.y);
            af[2] = (short)f2b(e*c0.z); af[3] = (short)f2b(e*c0.w);
            af[4] = (short)f2b(e*c1.x); af[5] = (short)f2b(e*c1.y);
            af[6] = (short)f2b(e*c1.z); af[7] = (short)f2b(e*c1.w);
            #pragma unroll
            for (int nt = 0; nt < 4; nt++)
                acc[mt][nt] = __builtin_amdgcn_mfma_f32_16x16x32_bf16(af, bfr[nt], acc[mt][nt], 0, 0, 0);
        }
    }
    float Dv = Dp[h];
    #pragma unroll
    for (int mt = 0; mt < 4; mt++){
        int l0 = (mt*4 + wave)*16 + quad*4;
        #pragma unroll
        for (int nt = 0; nt < 4; nt++){
            int p = nt*16 + lm;
            #pragma unroll
            for (int r = 0; r < 4; r++){
                int rowg = b*SEQL + c*CHUNK + l0 + r;
                float xs = convb[(size_t)rowg*CONVD + h*HD + p];
                Y[(size_t)rowg*DI + h*HD + p] = acc[mt][nt][r] + Dv*xs;
            }
        }
    }
}

// ------------------------------- y = Y*silu(z); RMSNorm; * rms_w ; -> bf16
__global__ __launch_bounds__(256) void gate_rms_k(const float* __restrict__ Yb,
                                                  const ushort_t* __restrict__ zx,
                                                  const float* __restrict__ rms_w,
                                                  ushort_t* __restrict__ yn){
    __shared__ float red[4];
    __shared__ float scale_s;
    int row = blockIdx.x; int tid = threadIdx.x;
    float v[8]; float ss = 0.f;
    #pragma unroll
    for (int i = 0; i < 8; i++){
        int d = tid + i*256;
        float g = Yb[(size_t)row*DI + d] * silu_f(b2f(zx[(size_t)row*DPROJ + d]));
        v[i] = g; ss += g*g;
    }
    #pragma unroll
    for (int off = 32; off > 0; off >>= 1) ss += __shfl_down(ss, off);
    int lane = tid & 63, wid = tid >> 6;
    if (lane == 0) red[wid] = ss;
    __syncthreads();
    if (tid == 0) scale_s = rsqrtf((red[0]+red[1]+red[2]+red[3])*(1.f/DI) + 1e-12f);
    __syncthreads();
    float sc = scale_s;
    #pragma unroll
    for (int i = 0; i < 8; i++){
        int d = tid + i*256;
        yn[(size_t)row*DI + d] = f2b(v[i]*sc*rms_w[d]);
    }
}

// -------- LayerNorm(a [+ a2] + resid)*g + b (+ optional bf16 copy)
template<int WB, int TWO>
__global__ __launch_bounds__(256) void ln_k(const float* __restrict__ a,
                                            const float* __restrict__ a2,
                                            const float* __restrict__ resid,
                                            const float* __restrict__ g,
                                            const float* __restrict__ bw,
                                            float* __restrict__ outp,
                                            ushort_t* __restrict__ bfout){
    __shared__ float redA[4], redB[4];
    __shared__ float mu_s, rs_s;
    int row = blockIdx.x; int tid = threadIdx.x;
    float u[4]; float s = 0.f, s2 = 0.f;
    #pragma unroll
    for (int i = 0; i < 4; i++){
        int d = tid + i*256;
        float val = a[(size_t)row*DM + d] + resid[(size_t)row*DM + d];
        if (TWO) val += a2[(size_t)row*DM + d];
        u[i] = val; s += val; s2 += val*val;
    }
    #pragma unroll
    for (int off = 32; off > 0; off >>= 1){
        s  += __shfl_down(s,  off);
        s2 += __shfl_down(s2, off);
    }
    int lane = tid & 63, wid = tid >> 6;
    if (lane == 0){ redA[wid] = s; redB[wid] = s2; }
    __syncthreads();
    if (tid == 0){
        float S  = redA[0]+redA[1]+redA[2]+redA[3];
        float S2 = redB[0]+redB[1]+redB[2]+redB[3];
        float mu = S*(1.f/DM);
        float var = S2*(1.f/DM) - mu*mu;
        mu_s = mu; rs_s = rsqrtf(var + 1e-12f);
    }
    __syncthreads();
    float mu = mu_s, rs = rs_s;
    #pragma unroll
    for (int i = 0; i < 4; i++){
        int d = tid + i*256;
        float o = (u[i]-mu)*rs*g[d] + bw[d];
        outp[(size_t)row*DM + d] = o;
        if (WB) bfout[(size_t)row*DM + d] = f2b(o);
    }
}

__global__ __launch_bounds__(256) void copy_td_k(const float* __restrict__ td,
                                                 float* __restrict__ outp){
    int idx = blockIdx.x*256 + threadIdx.x;
    outp[idx] = td[idx];
}

extern "C" void kernel_launch(void* const* d_in, const int* in_sizes, int n_in,
                              void* d_out, int out_size, void* d_ws, size_t ws_size,
                              hipStream_t stream){
    const float* x         = (const float*)d_in[0];
    const float* time_diff = (const float*)d_in[1];
    const float* W_in      = (const float*)d_in[2];
    const float* b_in      = (const float*)d_in[3];
    const float* conv_w    = (const float*)d_in[4];
    const float* conv_b    = (const float*)d_in[5];
    const float* A_log     = (const float*)d_in[6];
    const float* dt_bias   = (const float*)d_in[7];
    const float* Dp        = (const float*)d_in[8];
    const float* time_dec  = (const float*)d_in[9];
    const float* rms_w     = (const float*)d_in[10];
    const float* W_out     = (const float*)d_in[11];
    const float* b_out     = (const float*)d_in[12];
    const float* ln_g      = (const float*)d_in[13];
    const float* ln_b      = (const float*)d_in[14];
    const float* fc1_w     = (const float*)d_in[15];
    const float* fc1_b     = (const float*)d_in[16];
    const float* fc2_w     = (const float*)d_in[17];
    const float* fc2_b     = (const float*)d_in[18];
    const float* ln2_g     = (const float*)d_in[19];
    const float* ln2_b     = (const float*)d_in[20];

    float* ws = (float*)d_ws;
    float* zx    = ws;                       // 17,956,864  region1
    float* convb = zx    + 17956864;         //  9,437,184  region2 (later: out-proj partials)
    float* dt    = convb + 9437184;          //    131,072
    float* Acum  = dt    + 131072;           //    131,072
    float* xdt   = Acum  + 131072;           //  8,388,608  region4 (Y in-place; later fc2 partials)
    float* r5    = xdt   + 8388608;          //  9,437,184  region5
    float* hbuf  = r5    + 9437184;          //  4,194,304  region6
    // region1 aliases: zx_bf [0 .. 8,978,432 f), dtaux [10.6M .. 10.73M f)
    //                  mid_bf [0..8.4M f) step14+, h_bf [8.4M..10.5M f) step12+
    ushort_t* zx_bf  = (ushort_t*)zx;
    float*    dtaux  = zx + 10600000;
    ushort_t* mid_bf = (ushort_t*)zx;
    ushort_t* h_bf   = (ushort_t*)(zx + 8388608);
    ushort_t* x_bf  = (ushort_t*)xdt;                 // region4 aliases
    ushort_t* WinT  = (ushort_t*)(xdt + 2097152);
    ushort_t* WoutT = (ushort_t*)(xdt + 4194304);
    float* fc2Pa = xdt;
    float* Gbuf = r5;                                 // region5 aliases
    float* stat = r5 + 1048576;
    float* prev = stat + 4194304;
    ushort_t* yn_bf = (ushort_t*)r5;
    ushort_t* fc1T  = (ushort_t*)(r5 + 4194304);
    ushort_t* fc2T  = (ushort_t*)(r5 + 6291456);
    float* outPa  = convb;
    float* outp   = (float*)d_out;

    // 1. bf16 conversions for in-proj
    f2b_k<<<(ROWS*DM)/256, 256, 0, stream>>>(x, x_bf, ROWS*DM);
    transpose_bf_k<<<dim3(4480/32, DM/32), 256, 0, stream>>>(W_in, WinT, DM, DPROJ);
    // 2. in-proj (M=4096,N=4384,K=1024) -> bf16 zx + fp32 dt sidecar
    mfma_gemm_k<0,1,128,1,1><<<dim3(35, ROWS/128), 256, 0, stream>>>(x_bf, WinT, b_in, nullptr, zx_bf, dtaux, ROWS, DPROJ, DM, DPROJ);
    // 3. dt / dA / per-chunk cumsum
    dt_scan_k<<<BATCH*NHEADS*NC, 256, 0, stream>>>(dtaux, time_diff, A_log, dt_bias, time_dec, dt, Acum);
    // 4. causal conv + SiLU + fused xdt
    conv_silu_k<<<ROWS*CONVD/256, 256, 0, stream>>>(zx_bf, conv_w, conv_b, dt, convb, xdt);
    // 5. G = C @ B^T per (b,c) — MFMA
    g_mfma_k<<<dim3(4,4,BATCH*NC), 256, 0, stream>>>(convb, Gbuf);
    // 6. per-chunk states — MFMA
    states_mfma_k<<<BATCH*NC*NHEADS, 256, 0, stream>>>(convb, xdt, Acum, stat);
    // 7. inter-chunk scan
    prev_scan_k<<<BATCH*NHEADS, 256, 0, stream>>>(stat, Acum, prev);
    // 8. MFMA SSD output (in place over xdt)
    y_mfma_k<<<BATCH*NC*NHEADS, 256, 0, stream>>>(convb, Gbuf, Acum, prev, Dp, xdt);
    // 9. gate + RMSNorm -> bf16
    gate_rms_k<<<ROWS, 256, 0, stream>>>(xdt, zx_bf, rms_w, yn_bf);
    // 10. W_out transpose
    transpose_bf_k<<<dim3(DM/32, DI/32), 256, 0, stream>>>(W_out, WoutT, DI, DM);
    // 11. out-proj split-K=2 (M=4096,N=1024,K=2048) -> partials in convb
    mfma_gemm_k<0,0,64,2,0><<<dim3(DM/64, ROWS/128, 2), 256, 0, stream>>>(yn_bf, WoutT, b_out, outPa, nullptr, nullptr, ROWS, DM, DI, DM);
    // 12. h = LN(Pa + Pb + x) + bf16 copy
    ln_k<1,1><<<ROWS, 256, 0, stream>>>(outPa, outPa + (size_t)ROWS*DM, x, ln_g, ln_b, hbuf, h_bf);
    // 13. FFN weight transposes
    transpose_bf_k<<<dim3(DFF/32, DM/32), 256, 0, stream>>>(fc1_w, fc1T, DM, DFF);
    transpose_bf_k<<<dim3(DM/32, DFF/32), 256, 0, stream>>>(fc2_w, fc2T, DFF, DM);
    // 14. fc1 + hardswish -> bf16 mid (M=4096,N=4096,K=1024)
    mfma_gemm_k<1,1,128,1,0><<<dim3(DFF/128, ROWS/128), 256, 0, stream>>>(h_bf, fc1T, fc1_b, nullptr, mid_bf, nullptr, ROWS, DFF, DM, DFF);
    // 15. fc2 split-K=2 (M=4096,N=1024,K=4096) -> partials in xdt region
    mfma_gemm_k<0,0,64,2,0><<<dim3(DM/64, ROWS/128, 2), 256, 0, stream>>>(mid_bf, fc2T, fc2_b, fc2Pa, nullptr, nullptr, ROWS, DM, DFF, DM);
    // 16. out = LN(Pa + Pb + h)
    ln_k<0,1><<<ROWS, 256, 0, stream>>>(fc2Pa, fc2Pa + (size_t)ROWS*DM, hbuf, ln2_g, ln2_b, outp, nullptr);
    // 17. time_diff passthrough
    copy_td_k<<<ROWS/256, 256, 0, stream>>>(time_diff, outp + (size_t)ROWS*DM);
}

// Round 7
// 504.941 us; speedup vs baseline: 4.9238x; 1.0374x over previous
//
#include <hip/hip_runtime.h>

#define BATCH 2
#define SEQL 2048
#define DM 1024
#define DSTATE 128
#define HD 64
#define CHUNK 256
#define DI 2048
#define NHEADS 32
#define CONVD 2304
#define DPROJ 4384
#define DFF 4096
#define NC 8
#define ROWS (BATCH*SEQL)

typedef unsigned short ushort_t;
typedef short bf16x8 __attribute__((ext_vector_type(8)));
typedef float f32x4 __attribute__((ext_vector_type(4)));

__device__ __forceinline__ float softplus_f(float v){
    return (v > 20.f) ? v : log1pf(expf(v));
}
__device__ __forceinline__ float silu_f(float v){
    return v / (1.f + expf(-v));
}
__device__ __forceinline__ ushort_t f2b(float v){
    union { float f; unsigned int u; } x; x.f = v;
    unsigned int r = x.u + 0x7fffu + ((x.u >> 16) & 1u);
    return (ushort_t)(r >> 16);
}
__device__ __forceinline__ float b2f(ushort_t v){
    union { unsigned int u; float f; } x; x.u = ((unsigned int)v) << 16;
    return x.f;
}

// ================================================================ MFMA GEMM
// C[M,N] = A[M,K](bf16) @ Bt[N,K](bf16)^T + bias. BM=128, BN=TN, BK=64.
// XOR-swizzled LDS. NS split-K. DTX: fp32 sidecar for last NHEADS cols.
template<int ACT, int OUT_BF16, int TN, int NS, int DTX>
__global__ __launch_bounds__(256) void mfma_gemm_k(
    const ushort_t* __restrict__ A, const ushort_t* __restrict__ Bt,
    const float* __restrict__ bias, float* __restrict__ Cf,
    ushort_t* __restrict__ Cb, float* __restrict__ dtaux,
    int M, int N, int K, int ldc)
{
    constexpr int NT = (TN == 128) ? 4 : 2;
    constexpr int BROWS = TN / 4;
    __shared__ ushort_t As[128*64];
    __shared__ ushort_t Bs[TN*64];
    int tid = threadIdx.x;
    int lane = tid & 63, wave = tid >> 6;
    int m0 = blockIdx.y * 128, n0 = blockIdx.x * TN;
    int Ks = K / NS;
    int kb = (NS > 1) ? blockIdx.z * Ks : 0;
    int wave_m = (TN==128) ? (wave >> 1)*64 : (wave & 1)*64;
    int wave_n = (TN==128) ? (wave & 1)*64 : (wave >> 1)*32;
    int lrow = lane >> 3;
    int lcol = ((lane & 7) ^ lrow) * 8;
    const ushort_t* Abase = A  + (size_t)(m0 + wave*32    + lrow)*K + lcol + kb;
    const ushort_t* Bbase = Bt + (size_t)(n0 + wave*BROWS + lrow)*K + lcol + kb;
    ushort_t* AsW = &As[(wave*32)*64];
    ushort_t* BsW = &Bs[(wave*BROWS)*64];
    f32x4 acc[4][NT];
    #pragma unroll
    for (int i=0;i<4;i++)
        #pragma unroll
        for (int j=0;j<NT;j++) acc[i][j] = (f32x4){0.f,0.f,0.f,0.f};
    int lm = lane & 15;
    int quad = lane >> 4;
    for (int k0 = 0; k0 < Ks; k0 += 64){
        #pragma unroll
        for (int j = 0; j < 4; j++)
            __builtin_amdgcn_global_load_lds(
                (const __attribute__((address_space(1))) void*)(Abase + (size_t)(j*8)*K + k0),
                (__attribute__((address_space(3))) void*)(AsW + j*8*64), 16, 0, 0);
        #pragma unroll
        for (int j = 0; j < BROWS/8; j++)
            __builtin_amdgcn_global_load_lds(
                (const __attribute__((address_space(1))) void*)(Bbase + (size_t)(j*8)*K + k0),
                (__attribute__((address_space(3))) void*)(BsW + j*8*64), 16, 0, 0);
        __syncthreads();
        #pragma unroll
        for (int kk = 0; kk < 64; kk += 32){
            int cb = kk >> 3;
            bf16x8 af[4], bfr[NT];
            #pragma unroll
            for (int mt=0; mt<4; mt++)
                af[mt] = *(const bf16x8*)&As[(wave_m + mt*16 + lm)*64 + (((cb + quad) ^ (lm & 7))*8)];
            #pragma unroll
            for (int nt=0; nt<NT; nt++)
                bfr[nt] = *(const bf16x8*)&Bs[(wave_n + nt*16 + lm)*64 + (((cb + quad) ^ (lm & 7))*8)];
            #pragma unroll
            for (int mt=0; mt<4; mt++)
                #pragma unroll
                for (int nt=0; nt<NT; nt++)
                    acc[mt][nt] = __builtin_amdgcn_mfma_f32_16x16x32_bf16(af[mt], bfr[nt], acc[mt][nt], 0, 0, 0);
        }
        __syncthreads();
    }
    float* Cfo = Cf + (size_t)((NS > 1) ? blockIdx.z : 0) * (size_t)M * ldc;
    int addb = (NS == 1) || (blockIdx.z == 0);
    int crow0 = m0 + wave_m + quad * 4;
    int ccol0 = n0 + wave_n + lm;
    #pragma unroll
    for (int mt=0; mt<4; mt++){
        #pragma unroll
        for (int nt=0; nt<NT; nt++){
            int col = ccol0 + nt*16;
            if (col < N){
                float bv = addb ? bias[col] : 0.f;
                #pragma unroll
                for (int r=0; r<4; r++){
                    int row = crow0 + mt*16 + r;
                    float v = acc[mt][nt][r] + bv;
                    if (ACT == 1){
                        float t = fminf(fmaxf(v + 3.f, 0.f), 6.f);
                        v = v * t * (1.f/6.f);
                    }
                    if (OUT_BF16){
                        Cb[(size_t)row*ldc + col] = f2b(v);
                        if (DTX && col >= N - NHEADS)
                            dtaux[(size_t)row*NHEADS + (col - (N - NHEADS))] = v;
                    } else {
                        Cfo[(size_t)row*ldc + col] = v;
                    }
                }
            }
        }
    }
}

// ---------------- merged: f2b(x) [blocks 0..16383] + W_in transpose [rest]
__global__ __launch_bounds__(256) void prep_in_k(const float* __restrict__ x,
                                                 ushort_t* __restrict__ x_bf,
                                                 const float* __restrict__ W_in,
                                                 ushort_t* __restrict__ WinT){
    __shared__ ushort_t tile[32][33];
    int bid = blockIdx.x;
    if (bid < 16384){
        int idx = bid*256 + threadIdx.x;
        x_bf[idx] = f2b(x[idx]);
        return;
    }
    int id2 = bid - 16384;                  // 4480 transpose blocks (140 x 32)
    int n0 = (id2 % 140)*32, k0 = (id2 / 140)*32;
    int tx = threadIdx.x & 31, ty = threadIdx.x >> 5;
    #pragma unroll
    for (int i = 0; i < 4; i++){
        int k = k0 + ty + i*8;
        int n = n0 + tx;
        float v = (n < DPROJ) ? W_in[(size_t)k*DPROJ + n] : 0.f;
        tile[ty + i*8][tx] = f2b(v);
    }
    __syncthreads();
    #pragma unroll
    for (int i = 0; i < 4; i++)
        WinT[(size_t)(n0 + ty + i*8)*DM + k0 + tx] = tile[tx][ty + i*8];
}

// ---------------- merged: W_out / fc1 / fc2 transposes in one launch
__global__ __launch_bounds__(256) void transpose3_k(const float* __restrict__ Wout,
                                                    const float* __restrict__ fc1w,
                                                    const float* __restrict__ fc2w,
                                                    ushort_t* __restrict__ WoutT,
                                                    ushort_t* __restrict__ fc1T,
                                                    ushort_t* __restrict__ fc2T){
    __shared__ ushort_t tile[32][33];
    int bid = blockIdx.x;
    const float* W; ushort_t* Wt; int K, N, gx, id;
    if (bid < 2048){        W = Wout; Wt = WoutT; K = DI;  N = DM;  gx = 32;  id = bid; }
    else if (bid < 6144){   W = fc1w; Wt = fc1T;  K = DM;  N = DFF; gx = 128; id = bid - 2048; }
    else {                  W = fc2w; Wt = fc2T;  K = DFF; N = DM;  gx = 32;  id = bid - 6144; }
    int n0 = (id % gx)*32, k0 = (id / gx)*32;
    int tx = threadIdx.x & 31, ty = threadIdx.x >> 5;
    #pragma unroll
    for (int i = 0; i < 4; i++){
        int k = k0 + ty + i*8;
        int n = n0 + tx;
        tile[ty + i*8][tx] = f2b(W[(size_t)k*N + n]);
    }
    __syncthreads();
    #pragma unroll
    for (int i = 0; i < 4; i++)
        Wt[(size_t)(n0 + ty + i*8)*K + k0 + tx] = tile[tx][ty + i*8];
}

// ----------------- depthwise causal conv + SiLU (-> bf16), fused xdt (fp32)
__global__ __launch_bounds__(256) void conv_silu_k(const ushort_t* __restrict__ zx,
                                                   const float* __restrict__ conv_w,
                                                   const float* __restrict__ conv_b,
                                                   const float* __restrict__ dt,
                                                   ushort_t* __restrict__ convb,
                                                   float* __restrict__ xdt){
    int idx = blockIdx.x*256 + threadIdx.x;       // ROWS*CONVD total
    int c = idx % CONVD;
    int row = idx / CONVD;
    int t = row & (SEQL-1);
    float acc = conv_b[c];
    #pragma unroll
    for (int k = 0; k < 4; k++){
        int tt = t + k - 3;
        if (tt >= 0)
            acc += b2f(zx[((size_t)(row + k - 3))*DPROJ + DI + c]) * conv_w[c*4 + k];
    }
    float v = silu_f(acc);
    convb[idx] = f2b(v);
    if (c < DI)
        xdt[(size_t)row*DI + c] = v * dt[(size_t)row*NHEADS + (c >> 6)];
}

// ------------------ dt = softplus(dtaux+bias); dA; chunk cumsum
__global__ __launch_bounds__(256) void dt_scan_k(const float* __restrict__ dtaux,
                                                 const float* __restrict__ time_diff,
                                                 const float* __restrict__ A_log,
                                                 const float* __restrict__ dt_bias,
                                                 const float* __restrict__ time_decay,
                                                 float* __restrict__ dt_out,
                                                 float* __restrict__ Acum){
    __shared__ float s[CHUNK];
    int bid = blockIdx.x;
    int c = bid % NC;
    int h = (bid / NC) % NHEADS;
    int b = bid / (NC*NHEADS);
    int l = threadIdx.x;
    int t = c*CHUNK + l;
    float dtr = dtaux[((size_t)(b*SEQL + t))*NHEADS + h];
    float dtv = softplus_f(dtr + dt_bias[h]);
    float A = -expf(A_log[h]);
    float dA = dtv*A - softplus_f(time_decay[h]) * time_diff[b*SEQL + t];
    dt_out[(size_t)(b*SEQL + t)*NHEADS + h] = dtv;
    s[l] = dA;
    __syncthreads();
    for (int off = 1; off < CHUNK; off <<= 1){
        float v = (l >= off) ? s[l-off] : 0.f;
        __syncthreads();
        s[l] += v;
        __syncthreads();
    }
    Acum[((size_t)(b*NHEADS + h))*SEQL + t] = s[l];
}

// -------------------- MFMA G[b,c,l,s] = C_l . B_s (64x64x128), bf16 in/out
__global__ __launch_bounds__(256) void g_mfma_k(const ushort_t* __restrict__ convb,
                                                ushort_t* __restrict__ G){
    __shared__ ushort_t As[64*136];
    __shared__ ushort_t Bs[64*136];
    int bc = blockIdx.z;
    int l0 = blockIdx.y*64, s0 = blockIdx.x*64;
    int tid = threadIdx.x;
    int lane = tid & 63, wave = tid >> 6;
    int lm = lane & 15, quad = lane >> 4;
    const ushort_t* base = convb + (size_t)bc*CHUNK*CONVD;
    #pragma unroll
    for (int i = 0; i < 4; i++){
        int e = tid + i*256;                 // 1024 chunks of 8
        int r = e >> 4, k = (e & 15)*8;
        *(bf16x8*)&As[r*136 + k] = *(const bf16x8*)&base[(size_t)(l0+r)*CONVD + DI + DSTATE + k];
        *(bf16x8*)&Bs[r*136 + k] = *(const bf16x8*)&base[(size_t)(s0+r)*CONVD + DI + k];
    }
    __syncthreads();
    f32x4 acc[4];
    #pragma unroll
    for (int j=0;j<4;j++) acc[j] = (f32x4){0.f,0.f,0.f,0.f};
    #pragma unroll
    for (int kk = 0; kk < 4; kk++){
        bf16x8 af = *(const bf16x8*)&As[(wave*16+lm)*136 + kk*32 + quad*8];
        #pragma unroll
        for (int nt = 0; nt < 4; nt++){
            bf16x8 bfr = *(const bf16x8*)&Bs[(nt*16+lm)*136 + kk*32 + quad*8];
            acc[nt] = __builtin_amdgcn_mfma_f32_16x16x32_bf16(af, bfr, acc[nt], 0, 0, 0);
        }
    }
    ushort_t* g = G + (size_t)bc*CHUNK*CHUNK;
    #pragma unroll
    for (int nt = 0; nt < 4; nt++)
        #pragma unroll
        for (int r = 0; r < 4; r++)
            g[(size_t)(l0 + wave*16 + quad*4 + r)*CHUNK + s0 + nt*16 + lm] = f2b(acc[nt][r]);
}

// ---------- MFMA states[b,c,h,p,n] = sum_l B[l,n]*exp(AcL-Ac[l])*xdt[l,p]
#define RSX 264
#define RSB 72
__global__ __launch_bounds__(256) void states_mfma_k(const ushort_t* __restrict__ convb,
                                                     const float* __restrict__ xdt,
                                                     const float* __restrict__ Acum,
                                                     float* __restrict__ states){
    __shared__ ushort_t xw[64*RSX];
    __shared__ ushort_t Bt[128*RSB];
    __shared__ float Acs[CHUNK];
    int bid = blockIdx.x;
    int h = bid % NHEADS;
    int c = (bid / NHEADS) % NC;
    int b = bid / (NHEADS*NC);
    int tid = threadIdx.x;
    int lane = tid & 63, wave = tid >> 6;
    int lm = lane & 15, quad = lane >> 4;
    Acs[tid] = Acum[((size_t)(b*NHEADS + h))*SEQL + c*CHUNK + tid];
    __syncthreads();
    float AcL = Acs[CHUNK-1];
    {
        const float* xg = xdt + ((size_t)(b*SEQL + c*CHUNK))*DI + h*HD;
        #pragma unroll
        for (int j8 = 0; j8 < 8; j8++){
            int s0 = wave*64 + j8*8;
            bf16x8 pk;
            #pragma unroll
            for (int j = 0; j < 8; j++)
                pk[j] = (short)f2b(expf(AcL - Acs[s0+j]) * xg[(size_t)(s0+j)*DI + lane]);
            *(bf16x8*)&xw[lane*RSX + s0] = pk;
        }
    }
    f32x4 acc[8];
    #pragma unroll
    for (int j=0;j<8;j++) acc[j] = (f32x4){0.f,0.f,0.f,0.f};
    const ushort_t* bbase = convb + ((size_t)(b*SEQL + c*CHUNK))*CONVD + DI;
    for (int l0 = 0; l0 < CHUNK; l0 += 64){
        __syncthreads();
        #pragma unroll
        for (int i = 0; i < 32; i++){
            int e = tid + i*256; int l = e >> 7, n = e & 127;
            Bt[n*RSB + l] = bbase[(size_t)(l0+l)*CONVD + n];
        }
        __syncthreads();
        #pragma unroll
        for (int kk = 0; kk < 2; kk++){
            bf16x8 af = *(const bf16x8*)&xw[(wave*16+lm)*RSX + l0 + kk*32 + quad*8];
            #pragma unroll
            for (int nt = 0; nt < 8; nt++){
                bf16x8 bfr = *(const bf16x8*)&Bt[(nt*16+lm)*RSB + kk*32 + quad*8];
                acc[nt] = __builtin_amdgcn_mfma_f32_16x16x32_bf16(af, bfr, acc[nt], 0, 0, 0);
            }
        }
    }
    float* outp = states + ((size_t)((b*NC + c)*NHEADS + h))*(HD*DSTATE);
    #pragma unroll
    for (int nt = 0; nt < 8; nt++)
        #pragma unroll
        for (int r = 0; r < 4; r++)
            outp[(size_t)(wave*16 + quad*4 + r)*DSTATE + nt*16 + lm] = acc[nt][r];
}

// ------------------------- inter-chunk recurrence (8 sequential chunk steps)
__global__ __launch_bounds__(256) void prev_scan_k(const float* __restrict__ states,
                                                   const float* __restrict__ Acum,
                                                   float* __restrict__ prev){
    int bid = blockIdx.x;
    int h = bid % NHEADS, b = bid / NHEADS;
    int tid = threadIdx.x;
    const float* AcB = Acum + ((size_t)(b*NHEADS + h))*SEQL;
    float dec[NC];
    #pragma unroll
    for (int c = 0; c < NC; c++) dec[c] = expf(AcB[c*CHUNK + CHUNK-1]);
    for (int j = 0; j < 32; j++){
        int e = tid + j*256;
        float carry = 0.f;
        #pragma unroll
        for (int c = 0; c < NC; c++){
            size_t idx = ((size_t)((b*NC + c)*NHEADS + h))*(HD*DSTATE) + e;
            prev[idx] = carry;
            carry = carry*dec[c] + states[idx];
        }
    }
}

// ===== MFMA SSD output: Y = P@xdt + (e^A C)@prev^T + D*xs  -> bf16 Ybf
#define RLX 264
#define RLP 136
__global__ __launch_bounds__(256) void y_mfma_k(const ushort_t* __restrict__ convb,
                                                const ushort_t* __restrict__ G,
                                                const float* __restrict__ Acum,
                                                const float* __restrict__ prev,
                                                const float* __restrict__ Dp,
                                                const float* __restrict__ xdt,
                                                ushort_t* __restrict__ Ybf){
    __shared__ ushort_t xdtT[64*RLX];
    __shared__ ushort_t prevs[64*RLP];
    __shared__ float Acs[CHUNK];
    int bid = blockIdx.x;
    int h = bid % NHEADS;
    int c = (bid / NHEADS) % NC;
    int b = bid / (NHEADS*NC);
    int tid = threadIdx.x;
    int lane = tid & 63, wave = tid >> 6;
    int lm = lane & 15, quad = lane >> 4;

    Acs[tid] = Acum[((size_t)(b*NHEADS + h))*SEQL + c*CHUNK + tid];
    {
        const float* pv = prev + ((size_t)((b*NC + c)*NHEADS + h))*(HD*DSTATE);
        #pragma unroll
        for (int i = 0; i < 32; i++){
            int e = tid + i*256; int p = e >> 7, n = e & 127;
            prevs[p*RLP + n] = f2b(pv[e]);
        }
    }
    {
        const float* xg = xdt + ((size_t)(b*SEQL + c*CHUNK))*DI + h*HD;
        #pragma unroll
        for (int j8 = 0; j8 < 8; j8++){
            int s0 = wave*64 + j8*8;
            bf16x8 pk;
            #pragma unroll
            for (int j = 0; j < 8; j++)
                pk[j] = (short)f2b(xg[(size_t)(s0+j)*DI + lane]);
            *(bf16x8*)&xdtT[lane*RLX + s0] = pk;
        }
    }
    __syncthreads();

    int   lrow[4];  float Alr[4], eAlr[4];
    #pragma unroll
    for (int mt = 0; mt < 4; mt++){
        lrow[mt] = (mt*4 + wave)*16 + lm;
        Alr[mt]  = Acs[lrow[mt]];
        eAlr[mt] = expf(Alr[mt]);
    }
    const ushort_t* Gbase = G + ((size_t)(b*NC + c))*(CHUNK*CHUNK);

    f32x4 acc[4][4];
    #pragma unroll
    for (int i=0;i<4;i++)
        #pragma unroll
        for (int j=0;j<4;j++) acc[i][j] = (f32x4){0.f,0.f,0.f,0.f};

    for (int ks = 0; ks < 8; ks++){
        bf16x8 bfr[4];
        #pragma unroll
        for (int nt = 0; nt < 4; nt++)
            bfr[nt] = *(const bf16x8*)&xdtT[(nt*16+lm)*RLX + ks*32 + quad*8];
        #pragma unroll
        for (int mt = 0; mt < 4; mt++){
            int rblk = mt*4 + wave;
            int nst = rblk/2 + 1;
            if (ks < nst){
                int sbase = ks*32 + quad*8;
                bf16x8 g8 = *(const bf16x8*)&Gbase[(size_t)lrow[mt]*CHUNK + sbase];
                const float4* A4 = (const float4*)(&Acs[sbase]);
                float4 a0 = A4[0], a1 = A4[1];
                float Al = Alr[mt]; int l = lrow[mt];
                float pv[8];
                pv[0] = (sbase+0 <= l) ? b2f((ushort_t)g8[0])*expf(Al - a0.x) : 0.f;
                pv[1] = (sbase+1 <= l) ? b2f((ushort_t)g8[1])*expf(Al - a0.y) : 0.f;
                pv[2] = (sbase+2 <= l) ? b2f((ushort_t)g8[2])*expf(Al - a0.z) : 0.f;
                pv[3] = (sbase+3 <= l) ? b2f((ushort_t)g8[3])*expf(Al - a0.w) : 0.f;
                pv[4] = (sbase+4 <= l) ? b2f((ushort_t)g8[4])*expf(Al - a1.x) : 0.f;
                pv[5] = (sbase+5 <= l) ? b2f((ushort_t)g8[5])*expf(Al - a1.y) : 0.f;
                pv[6] = (sbase+6 <= l) ? b2f((ushort_t)g8[6])*expf(Al - a1.z) : 0.f;
                pv[7] = (sbase+7 <= l) ? b2f((ushort_t)g8[7])*expf(Al - a1.w) : 0.f;
                bf16x8 af;
                #pragma unroll
                for (int j = 0; j < 8; j++) af[j] = (short)f2b(pv[j]);
                #pragma unroll
                for (int nt = 0; nt < 4; nt++)
                    acc[mt][nt] = __builtin_amdgcn_mfma_f32_16x16x32_bf16(af, bfr[nt], acc[mt][nt], 0, 0, 0);
            }
        }
    }
    for (int kc = 0; kc < 4; kc++){
        bf16x8 bfr[4];
        #pragma unroll
        for (int nt = 0; nt < 4; nt++)
            bfr[nt] = *(const bf16x8*)&prevs[(nt*16+lm)*RLP + kc*32 + quad*8];
        #pragma unroll
        for (int mt = 0; mt < 4; mt++){
            int rowg = b*SEQL + c*CHUNK + lrow[mt];
            bf16x8 c8 = *(const bf16x8*)&convb[(size_t)rowg*CONVD + DI + DSTATE + kc*32 + quad*8];
            float e = eAlr[mt];
            bf16x8 af;
            #pragma unroll
            for (int j = 0; j < 8; j++) af[j] = (short)f2b(e * b2f((ushort_t)c8[j]));
            #pragma unroll
            for (int nt = 0; nt < 4; nt++)
                acc[mt][nt] = __builtin_amdgcn_mfma_f32_16x16x32_bf16(af, bfr[nt], acc[mt][nt], 0, 0, 0);
        }
    }
    float Dv = Dp[h];
    #pragma unroll
    for (int mt = 0; mt < 4; mt++){
        int l0 = (mt*4 + wave)*16 + quad*4;
        #pragma unroll
        for (int nt = 0; nt < 4; nt++){
            int p = nt*16 + lm;
            #pragma unroll
            for (int r = 0; r < 4; r++){
                int rowg = b*SEQL + c*CHUNK + l0 + r;
                float xs = b2f(convb[(size_t)rowg*CONVD + h*HD + p]);
                Ybf[(size_t)rowg*DI + h*HD + p] = f2b(acc[mt][nt][r] + Dv*xs);
            }
        }
    }
}

// ------------------------------- y = Y*silu(z); RMSNorm; * rms_w ; -> bf16
__global__ __launch_bounds__(256) void gate_rms_k(const ushort_t* __restrict__ Yb,
                                                  const ushort_t* __restrict__ zx,
                                                  const float* __restrict__ rms_w,
                                                  ushort_t* __restrict__ yn){
    __shared__ float red[4];
    __shared__ float scale_s;
    int row = blockIdx.x; int tid = threadIdx.x;
    float v[8]; float ss = 0.f;
    #pragma unroll
    for (int i = 0; i < 8; i++){
        int d = tid + i*256;
        float g = b2f(Yb[(size_t)row*DI + d]) * silu_f(b2f(zx[(size_t)row*DPROJ + d]));
        v[i] = g; ss += g*g;
    }
    #pragma unroll
    for (int off = 32; off > 0; off >>= 1) ss += __shfl_down(ss, off);
    int lane = tid & 63, wid = tid >> 6;
    if (lane == 0) red[wid] = ss;
    __syncthreads();
    if (tid == 0) scale_s = rsqrtf((red[0]+red[1]+red[2]+red[3])*(1.f/DI) + 1e-12f);
    __syncthreads();
    float sc = scale_s;
    #pragma unroll
    for (int i = 0; i < 8; i++){
        int d = tid + i*256;
        yn[(size_t)row*DI + d] = f2b(v[i]*sc*rms_w[d]);
    }
}

// -------- LN(a + a2 + resid_f32) -> bf16 only (mid LN)
__global__ __launch_bounds__(256) void ln_hbf_k(const float* __restrict__ a,
                                                const float* __restrict__ a2,
                                                const float* __restrict__ resid,
                                                const float* __restrict__ g,
                                                const float* __restrict__ bw,
                                                ushort_t* __restrict__ bfout){
    __shared__ float redA[4], redB[4];
    __shared__ float mu_s, rs_s;
    int row = blockIdx.x; int tid = threadIdx.x;
    float u[4]; float s = 0.f, s2 = 0.f;
    #pragma unroll
    for (int i = 0; i < 4; i++){
        int d = tid + i*256;
        float val = a[(size_t)row*DM + d] + a2[(size_t)row*DM + d] + resid[(size_t)row*DM + d];
        u[i] = val; s += val; s2 += val*val;
    }
    #pragma unroll
    for (int off = 32; off > 0; off >>= 1){
        s  += __shfl_down(s,  off);
        s2 += __shfl_down(s2, off);
    }
    int lane = tid & 63, wid = tid >> 6;
    if (lane == 0){ redA[wid] = s; redB[wid] = s2; }
    __syncthreads();
    if (tid == 0){
        float S  = redA[0]+redA[1]+redA[2]+redA[3];
        float S2 = redB[0]+redB[1]+redB[2]+redB[3];
        float mu = S*(1.f/DM);
        float var = S2*(1.f/DM) - mu*mu;
        mu_s = mu; rs_s = rsqrtf(var + 1e-12f);
    }
    __syncthreads();
    float mu = mu_s, rs = rs_s;
    #pragma unroll
    for (int i = 0; i < 4; i++){
        int d = tid + i*256;
        bfout[(size_t)row*DM + d] = f2b((u[i]-mu)*rs*g[d] + bw[d]);
    }
}

// -------- final LN(a + a2 + resid_bf16) -> fp32 d_out; extra blocks copy td
__global__ __launch_bounds__(256) void ln_final_k(const float* __restrict__ a,
                                                  const float* __restrict__ a2,
                                                  const ushort_t* __restrict__ residb,
                                                  const float* __restrict__ g,
                                                  const float* __restrict__ bw,
                                                  float* __restrict__ outp,
                                                  const float* __restrict__ td){
    __shared__ float redA[4], redB[4];
    __shared__ float mu_s, rs_s;
    int row = blockIdx.x; int tid = threadIdx.x;
    if (row >= ROWS){
        int idx = (row - ROWS)*256 + tid;
        outp[(size_t)ROWS*DM + idx] = td[idx];
        return;
    }
    float u[4]; float s = 0.f, s2 = 0.f;
    #pragma unroll
    for (int i = 0; i < 4; i++){
        int d = tid + i*256;
        float val = a[(size_t)row*DM + d] + a2[(size_t)row*DM + d] + b2f(residb[(size_t)row*DM + d]);
        u[i] = val; s += val; s2 += val*val;
    }
    #pragma unroll
    for (int off = 32; off > 0; off >>= 1){
        s  += __shfl_down(s,  off);
        s2 += __shfl_down(s2, off);
    }
    int lane = tid & 63, wid = tid >> 6;
    if (lane == 0){ redA[wid] = s; redB[wid] = s2; }
    __syncthreads();
    if (tid == 0){
        float S  = redA[0]+redA[1]+redA[2]+redA[3];
        float S2 = redB[0]+redB[1]+redB[2]+redB[3];
        float mu = S*(1.f/DM);
        float var = S2*(1.f/DM) - mu*mu;
        mu_s = mu; rs_s = rsqrtf(var + 1e-12f);
    }
    __syncthreads();
    float mu = mu_s, rs = rs_s;
    #pragma unroll
    for (int i = 0; i < 4; i++){
        int d = tid + i*256;
        outp[(size_t)row*DM + d] = (u[i]-mu)*rs*g[d] + bw[d];
    }
}

extern "C" void kernel_launch(void* const* d_in, const int* in_sizes, int n_in,
                              void* d_out, int out_size, void* d_ws, size_t ws_size,
                              hipStream_t stream){
    const float* x         = (const float*)d_in[0];
    const float* time_diff = (const float*)d_in[1];
    const float* W_in      = (const float*)d_in[2];
    const float* b_in      = (const float*)d_in[3];
    const float* conv_w    = (const float*)d_in[4];
    const float* conv_b    = (const float*)d_in[5];
    const float* A_log     = (const float*)d_in[6];
    const float* dt_bias   = (const float*)d_in[7];
    const float* Dp        = (const float*)d_in[8];
    const float* time_dec  = (const float*)d_in[9];
    const float* rms_w     = (const float*)d_in[10];
    const float* W_out     = (const float*)d_in[11];
    const float* b_out     = (const float*)d_in[12];
    const float* ln_g      = (const float*)d_in[13];
    const float* ln_b      = (const float*)d_in[14];
    const float* fc1_w     = (const float*)d_in[15];
    const float* fc1_b     = (const float*)d_in[16];
    const float* fc2_w     = (const float*)d_in[17];
    const float* fc2_b     = (const float*)d_in[18];
    const float* ln2_g     = (const float*)d_in[19];
    const float* ln2_b     = (const float*)d_in[20];

    float* ws = (float*)d_ws;
    float* zx    = ws;                       // region1: 17,956,864 f
    float* convb = zx    + 17956864;         // region2:  9,437,184 f
    float* dt    = convb + 9437184;
    float* Acum  = dt    + 131072;
    float* xdt   = Acum  + 131072;           // region4:  8,388,608 f
    float* r5    = xdt   + 8388608;          // region5:  9,437,184 f
    float* ybreg = r5    + 9437184;          // region6:  4,194,304 f
    // region1 aliases
    ushort_t* zx_bf  = (ushort_t*)zx;                 // steps 2-9
    float*    dtaux  = zx + 10600000;                 // steps 2-3
    ushort_t* mid_bf = (ushort_t*)zx;                 // steps 13-14 (zx dead)
    ushort_t* h_bf   = (ushort_t*)(zx + 8388608);     // steps 12-15 (zx dead)
    // region2 aliases
    ushort_t* convb_bf = (ushort_t*)convb;            // steps 4-8
    float* outPa  = convb;                            // steps 11-12 (convb dead)
    // region4 aliases
    ushort_t* x_bf  = (ushort_t*)xdt;                 // steps 1-2
    ushort_t* WinT  = (ushort_t*)(xdt + 2097152);     // steps 1-2
    ushort_t* WoutT = (ushort_t*)(xdt + 4194304);     // steps 10-11 (xdt dead)
    float* fc2Pa = xdt;                               // steps 14-15
    // region5 aliases
    ushort_t* Gb   = (ushort_t*)r5;                   // steps 5-8
    float* stat = r5 + 1048576;                       // steps 6-7
    float* prev = stat + 4194304;                     // steps 7-8
    ushort_t* yn_bf = (ushort_t*)r5;                  // steps 9-11 (G/stat dead)
    ushort_t* fc1T  = (ushort_t*)(r5 + 4194304);      // steps 10-13 (stat/prev dead)
    ushort_t* fc2T  = (ushort_t*)(r5 + 6291456);      // steps 10-14 (prev dead)
    // region6
    ushort_t* Ybf = (ushort_t*)ybreg;                 // steps 8-9
    float* outp   = (float*)d_out;

    // 1. f2b(x) + W_in^T (merged)
    prep_in_k<<<16384 + 4480, 256, 0, stream>>>(x, x_bf, W_in, WinT);
    // 2. in-proj (M=4096,N=4384,K=1024) -> bf16 zx + fp32 dt sidecar
    mfma_gemm_k<0,1,128,1,1><<<dim3(35, ROWS/128), 256, 0, stream>>>(x_bf, WinT, b_in, nullptr, zx_bf, dtaux, ROWS, DPROJ, DM, DPROJ);
    // 3. dt / dA / per-chunk cumsum
    dt_scan_k<<<BATCH*NHEADS*NC, 256, 0, stream>>>(dtaux, time_diff, A_log, dt_bias, time_dec, dt, Acum);
    // 4. causal conv + SiLU -> bf16 convb, fp32 xdt
    conv_silu_k<<<ROWS*CONVD/256, 256, 0, stream>>>(zx_bf, conv_w, conv_b, dt, convb_bf, xdt);
    // 5. G = C @ B^T (MFMA, bf16)
    g_mfma_k<<<dim3(4,4,BATCH*NC), 256, 0, stream>>>(convb_bf, Gb);
    // 6. per-chunk states (MFMA)
    states_mfma_k<<<BATCH*NC*NHEADS, 256, 0, stream>>>(convb_bf, xdt, Acum, stat);
    // 7. inter-chunk scan
    prev_scan_k<<<BATCH*NHEADS, 256, 0, stream>>>(stat, Acum, prev);
    // 8. MFMA SSD output -> bf16 Y
    y_mfma_k<<<BATCH*NC*NHEADS, 256, 0, stream>>>(convb_bf, Gb, Acum, prev, Dp, xdt, Ybf);
    // 9. gate + RMSNorm -> bf16 yn
    gate_rms_k<<<ROWS, 256, 0, stream>>>(Ybf, zx_bf, rms_w, yn_bf);
    // 10. W_out / fc1 / fc2 transposes (merged)
    transpose3_k<<<10240, 256, 0, stream>>>(W_out, fc1_w, fc2_w, WoutT, fc1T, fc2T);
    // 11. out-proj split-K=2 (M=4096,N=1024,K=2048)
    mfma_gemm_k<0,0,64,2,0><<<dim3(DM/64, ROWS/128, 2), 256, 0, stream>>>(yn_bf, WoutT, b_out, outPa, nullptr, nullptr, ROWS, DM, DI, DM);
    // 12. h = LN(Pa + Pb + x) -> bf16 only
    ln_hbf_k<<<ROWS, 256, 0, stream>>>(outPa, outPa + (size_t)ROWS*DM, x, ln_g, ln_b, h_bf);
    // 13. fc1 + hardswish -> bf16 mid (M=4096,N=4096,K=1024)
    mfma_gemm_k<1,1,128,1,0><<<dim3(DFF/128, ROWS/128), 256, 0, stream>>>(h_bf, fc1T, fc1_b, nullptr, mid_bf, nullptr, ROWS, DFF, DM, DFF);
    // 14. fc2 split-K=2 (M=4096,N=1024,K=4096)
    mfma_gemm_k<0,0,64,2,0><<<dim3(DM/64, ROWS/128, 2), 256, 0, stream>>>(mid_bf, fc2T, fc2_b, fc2Pa, nullptr, nullptr, ROWS, DM, DFF, DM);
    // 15. out = LN(Pa + Pb + h_bf) + td passthrough (merged)
    ln_final_k<<<ROWS + ROWS/256, 256, 0, stream>>>(fc2Pa, fc2Pa + (size_t)ROWS*DM, h_bf, ln2_g, ln2_b, outp, time_diff);
}

// Round 8
// 492.608 us; speedup vs baseline: 5.0471x; 1.0250x over previous
//
#include <hip/hip_runtime.h>

#define BATCH 2
#define SEQL 2048
#define DM 1024
#define DSTATE 128
#define HD 64
#define CHUNK 256
#define DI 2048
#define NHEADS 32
#define CONVD 2304
#define DPROJ 4384
#define DFF 4096
#define NC 8
#define ROWS (BATCH*SEQL)

typedef unsigned short ushort_t;
typedef short bf16x8 __attribute__((ext_vector_type(8)));
typedef float f32x4 __attribute__((ext_vector_type(4)));

__device__ __forceinline__ float softplus_f(float v){
    return (v > 20.f) ? v : log1pf(expf(v));
}
__device__ __forceinline__ float silu_f(float v){
    return v / (1.f + expf(-v));
}
__device__ __forceinline__ ushort_t f2b(float v){
    union { float f; unsigned int u; } x; x.f = v;
    unsigned int r = x.u + 0x7fffu + ((x.u >> 16) & 1u);
    return (ushort_t)(r >> 16);
}
__device__ __forceinline__ float b2f(ushort_t v){
    union { unsigned int u; float f; } x; x.u = ((unsigned int)v) << 16;
    return x.f;
}

// ================================================================ MFMA GEMM
// C[M,N] = A[M,K](bf16) @ Bt[N,K](bf16)^T + bias. BM=128, BN=TN, BK=64.
// XOR-swizzled LDS. NS split-K. DTX: fp32 sidecar for last NHEADS cols.
template<int ACT, int OUT_BF16, int TN, int NS, int DTX>
__global__ __launch_bounds__(256) void mfma_gemm_k(
    const ushort_t* __restrict__ A, const ushort_t* __restrict__ Bt,
    const float* __restrict__ bias, float* __restrict__ Cf,
    ushort_t* __restrict__ Cb, float* __restrict__ dtaux,
    int M, int N, int K, int ldc)
{
    constexpr int NT = (TN == 128) ? 4 : 2;
    constexpr int BROWS = TN / 4;
    __shared__ ushort_t As[128*64];
    __shared__ ushort_t Bs[TN*64];
    int tid = threadIdx.x;
    int lane = tid & 63, wave = tid >> 6;
    int m0 = blockIdx.y * 128, n0 = blockIdx.x * TN;
    int Ks = K / NS;
    int kb = (NS > 1) ? blockIdx.z * Ks : 0;
    int wave_m = (TN==128) ? (wave >> 1)*64 : (wave & 1)*64;
    int wave_n = (TN==128) ? (wave & 1)*64 : (wave >> 1)*32;
    int lrow = lane >> 3;
    int lcol = ((lane & 7) ^ lrow) * 8;
    const ushort_t* Abase = A  + (size_t)(m0 + wave*32    + lrow)*K + lcol + kb;
    const ushort_t* Bbase = Bt + (size_t)(n0 + wave*BROWS + lrow)*K + lcol + kb;
    ushort_t* AsW = &As[(wave*32)*64];
    ushort_t* BsW = &Bs[(wave*BROWS)*64];
    f32x4 acc[4][NT];
    #pragma unroll
    for (int i=0;i<4;i++)
        #pragma unroll
        for (int j=0;j<NT;j++) acc[i][j] = (f32x4){0.f,0.f,0.f,0.f};
    int lm = lane & 15;
    int quad = lane >> 4;
    for (int k0 = 0; k0 < Ks; k0 += 64){
        #pragma unroll
        for (int j = 0; j < 4; j++)
            __builtin_amdgcn_global_load_lds(
                (const __attribute__((address_space(1))) void*)(Abase + (size_t)(j*8)*K + k0),
                (__attribute__((address_space(3))) void*)(AsW + j*8*64), 16, 0, 0);
        #pragma unroll
        for (int j = 0; j < BROWS/8; j++)
            __builtin_amdgcn_global_load_lds(
                (const __attribute__((address_space(1))) void*)(Bbase + (size_t)(j*8)*K + k0),
                (__attribute__((address_space(3))) void*)(BsW + j*8*64), 16, 0, 0);
        __syncthreads();
        #pragma unroll
        for (int kk = 0; kk < 64; kk += 32){
            int cb = kk >> 3;
            bf16x8 af[4], bfr[NT];
            #pragma unroll
            for (int mt=0; mt<4; mt++)
                af[mt] = *(const bf16x8*)&As[(wave_m + mt*16 + lm)*64 + (((cb + quad) ^ (lm & 7))*8)];
            #pragma unroll
            for (int nt=0; nt<NT; nt++)
                bfr[nt] = *(const bf16x8*)&Bs[(wave_n + nt*16 + lm)*64 + (((cb + quad) ^ (lm & 7))*8)];
            #pragma unroll
            for (int mt=0; mt<4; mt++)
                #pragma unroll
                for (int nt=0; nt<NT; nt++)
                    acc[mt][nt] = __builtin_amdgcn_mfma_f32_16x16x32_bf16(af[mt], bfr[nt], acc[mt][nt], 0, 0, 0);
        }
        __syncthreads();
    }
    float* Cfo = Cf + (size_t)((NS > 1) ? blockIdx.z : 0) * (size_t)M * ldc;
    int addb = (NS == 1) || (blockIdx.z == 0);
    int crow0 = m0 + wave_m + quad * 4;
    int ccol0 = n0 + wave_n + lm;
    #pragma unroll
    for (int mt=0; mt<4; mt++){
        #pragma unroll
        for (int nt=0; nt<NT; nt++){
            int col = ccol0 + nt*16;
            if (col < N){
                float bv = addb ? bias[col] : 0.f;
                #pragma unroll
                for (int r=0; r<4; r++){
                    int row = crow0 + mt*16 + r;
                    float v = acc[mt][nt][r] + bv;
                    if (ACT == 1){
                        float t = fminf(fmaxf(v + 3.f, 0.f), 6.f);
                        v = v * t * (1.f/6.f);
                    }
                    if (OUT_BF16){
                        Cb[(size_t)row*ldc + col] = f2b(v);
                        if (DTX && col >= N - NHEADS)
                            dtaux[(size_t)row*NHEADS + (col - (N - NHEADS))] = v;
                    } else {
                        Cfo[(size_t)row*ldc + col] = v;
                    }
                }
            }
        }
    }
}

// ---------------- merged: f2b(x) [blocks 0..16383] + W_in transpose [rest]
__global__ __launch_bounds__(256) void prep_in_k(const float* __restrict__ x,
                                                 ushort_t* __restrict__ x_bf,
                                                 const float* __restrict__ W_in,
                                                 ushort_t* __restrict__ WinT){
    __shared__ ushort_t tile[32][33];
    int bid = blockIdx.x;
    if (bid < 16384){
        int idx = bid*256 + threadIdx.x;
        x_bf[idx] = f2b(x[idx]);
        return;
    }
    int id2 = bid - 16384;                  // 4480 transpose blocks (140 x 32)
    int n0 = (id2 % 140)*32, k0 = (id2 / 140)*32;
    int tx = threadIdx.x & 31, ty = threadIdx.x >> 5;
    #pragma unroll
    for (int i = 0; i < 4; i++){
        int k = k0 + ty + i*8;
        int n = n0 + tx;
        float v = (n < DPROJ) ? W_in[(size_t)k*DPROJ + n] : 0.f;
        tile[ty + i*8][tx] = f2b(v);
    }
    __syncthreads();
    #pragma unroll
    for (int i = 0; i < 4; i++)
        WinT[(size_t)(n0 + ty + i*8)*DM + k0 + tx] = tile[tx][ty + i*8];
}

// ---------------- merged: W_out / fc1 / fc2 transposes in one launch
__global__ __launch_bounds__(256) void transpose3_k(const float* __restrict__ Wout,
                                                    const float* __restrict__ fc1w,
                                                    const float* __restrict__ fc2w,
                                                    ushort_t* __restrict__ WoutT,
                                                    ushort_t* __restrict__ fc1T,
                                                    ushort_t* __restrict__ fc2T){
    __shared__ ushort_t tile[32][33];
    int bid = blockIdx.x;
    const float* W; ushort_t* Wt; int K, N, gx, id;
    if (bid < 2048){        W = Wout; Wt = WoutT; K = DI;  N = DM;  gx = 32;  id = bid; }
    else if (bid < 6144){   W = fc1w; Wt = fc1T;  K = DM;  N = DFF; gx = 128; id = bid - 2048; }
    else {                  W = fc2w; Wt = fc2T;  K = DFF; N = DM;  gx = 32;  id = bid - 6144; }
    int n0 = (id % gx)*32, k0 = (id / gx)*32;
    int tx = threadIdx.x & 31, ty = threadIdx.x >> 5;
    #pragma unroll
    for (int i = 0; i < 4; i++){
        int k = k0 + ty + i*8;
        int n = n0 + tx;
        tile[ty + i*8][tx] = f2b(W[(size_t)k*N + n]);
    }
    __syncthreads();
    #pragma unroll
    for (int i = 0; i < 4; i++)
        Wt[(size_t)(n0 + ty + i*8)*K + k0 + tx] = tile[tx][ty + i*8];
}

// ---- merged: [0, 36864) depthwise conv+SiLU -> bf16; [36864, +512) dt-scan
#define CONVBLKS (ROWS*CONVD/256)
__global__ __launch_bounds__(256) void conv_dt_k(const ushort_t* __restrict__ zx,
                                                 const float* __restrict__ conv_w,
                                                 const float* __restrict__ conv_b,
                                                 ushort_t* __restrict__ convb,
                                                 const float* __restrict__ dtaux,
                                                 const float* __restrict__ time_diff,
                                                 const float* __restrict__ A_log,
                                                 const float* __restrict__ dt_bias,
                                                 const float* __restrict__ time_decay,
                                                 float* __restrict__ dtH,
                                                 float* __restrict__ Acum){
    __shared__ float s[CHUNK];
    int bid = blockIdx.x;
    if (bid < CONVBLKS){
        int idx = bid*256 + threadIdx.x;
        int c = idx % CONVD;
        int row = idx / CONVD;
        int t = row & (SEQL-1);
        float acc = conv_b[c];
        #pragma unroll
        for (int k = 0; k < 4; k++){
            int tt = t + k - 3;
            if (tt >= 0)
                acc += b2f(zx[((size_t)(row + k - 3))*DPROJ + DI + c]) * conv_w[c*4 + k];
        }
        convb[idx] = f2b(silu_f(acc));
        return;
    }
    int id2 = bid - CONVBLKS;                  // 512 dt blocks
    int c = id2 % NC;
    int h = (id2 / NC) % NHEADS;
    int b = id2 / (NC*NHEADS);
    int l = threadIdx.x;
    int t = c*CHUNK + l;
    float dtr = dtaux[((size_t)(b*SEQL + t))*NHEADS + h];
    float dtv = softplus_f(dtr + dt_bias[h]);
    float A = -expf(A_log[h]);
    float dA = dtv*A - softplus_f(time_decay[h]) * time_diff[b*SEQL + t];
    dtH[((size_t)(b*NHEADS + h))*SEQL + t] = dtv;        // [h][row] layout
    s[l] = dA;
    __syncthreads();
    for (int off = 1; off < CHUNK; off <<= 1){
        float v = (l >= off) ? s[l-off] : 0.f;
        __syncthreads();
        s[l] += v;
        __syncthreads();
    }
    Acum[((size_t)(b*NHEADS + h))*SEQL + t] = s[l];
}

// -------------------- MFMA G[b,c,l,s] = C_l . B_s (64x64x128), bf16 in/out
__global__ __launch_bounds__(256) void g_mfma_k(const ushort_t* __restrict__ convb,
                                                ushort_t* __restrict__ G){
    __shared__ ushort_t As[64*136];
    __shared__ ushort_t Bs[64*136];
    int bc = blockIdx.z;
    int l0 = blockIdx.y*64, s0 = blockIdx.x*64;
    int tid = threadIdx.x;
    int lane = tid & 63, wave = tid >> 6;
    int lm = lane & 15, quad = lane >> 4;
    const ushort_t* base = convb + (size_t)bc*CHUNK*CONVD;
    #pragma unroll
    for (int i = 0; i < 4; i++){
        int e = tid + i*256;
        int r = e >> 4, k = (e & 15)*8;
        *(bf16x8*)&As[r*136 + k] = *(const bf16x8*)&base[(size_t)(l0+r)*CONVD + DI + DSTATE + k];
        *(bf16x8*)&Bs[r*136 + k] = *(const bf16x8*)&base[(size_t)(s0+r)*CONVD + DI + k];
    }
    __syncthreads();
    f32x4 acc[4];
    #pragma unroll
    for (int j=0;j<4;j++) acc[j] = (f32x4){0.f,0.f,0.f,0.f};
    #pragma unroll
    for (int kk = 0; kk < 4; kk++){
        bf16x8 af = *(const bf16x8*)&As[(wave*16+lm)*136 + kk*32 + quad*8];
        #pragma unroll
        for (int nt = 0; nt < 4; nt++){
            bf16x8 bfr = *(const bf16x8*)&Bs[(nt*16+lm)*136 + kk*32 + quad*8];
            acc[nt] = __builtin_amdgcn_mfma_f32_16x16x32_bf16(af, bfr, acc[nt], 0, 0, 0);
        }
    }
    ushort_t* g = G + (size_t)bc*CHUNK*CHUNK;
    #pragma unroll
    for (int nt = 0; nt < 4; nt++)
        #pragma unroll
        for (int r = 0; r < 4; r++)
            g[(size_t)(l0 + wave*16 + quad*4 + r)*CHUNK + s0 + nt*16 + lm] = f2b(acc[nt][r]);
}

// ---- MFMA states[b,c,h,p,n] = sum_l B[l,n]*exp(AcL-Ac[l])*dt[l]*xs[l,p]
#define RSX 264
#define RSB 72
__global__ __launch_bounds__(256) void states_mfma_k(const ushort_t* __restrict__ convb,
                                                     const float* __restrict__ dtH,
                                                     const float* __restrict__ Acum,
                                                     float* __restrict__ states){
    __shared__ ushort_t xw[64*RSX];
    __shared__ ushort_t Bt[128*RSB];
    __shared__ float Acs[CHUNK];
    __shared__ float dts[CHUNK];
    int bid = blockIdx.x;
    int h = bid % NHEADS;
    int c = (bid / NHEADS) % NC;
    int b = bid / (NHEADS*NC);
    int tid = threadIdx.x;
    int lane = tid & 63, wave = tid >> 6;
    int lm = lane & 15, quad = lane >> 4;
    Acs[tid] = Acum[((size_t)(b*NHEADS + h))*SEQL + c*CHUNK + tid];
    dts[tid] = dtH[((size_t)(b*NHEADS + h))*SEQL + c*CHUNK + tid];
    __syncthreads();
    float AcL = Acs[CHUNK-1];
    {
        const ushort_t* xg = convb + ((size_t)(b*SEQL + c*CHUNK))*CONVD + h*HD;
        #pragma unroll
        for (int j8 = 0; j8 < 8; j8++){
            int s0 = wave*64 + j8*8;
            bf16x8 pk;
            #pragma unroll
            for (int j = 0; j < 8; j++){
                int l = s0 + j;
                pk[j] = (short)f2b(expf(AcL - Acs[l]) * dts[l] * b2f(xg[(size_t)l*CONVD + lane]));
            }
            *(bf16x8*)&xw[lane*RSX + s0] = pk;
        }
    }
    f32x4 acc[8];
    #pragma unroll
    for (int j=0;j<8;j++) acc[j] = (f32x4){0.f,0.f,0.f,0.f};
    const ushort_t* bbase = convb + ((size_t)(b*SEQL + c*CHUNK))*CONVD + DI;
    for (int l0 = 0; l0 < CHUNK; l0 += 64){
        __syncthreads();
        #pragma unroll
        for (int i = 0; i < 32; i++){
            int e = tid + i*256; int l = e >> 7, n = e & 127;
            Bt[n*RSB + l] = bbase[(size_t)(l0+l)*CONVD + n];
        }
        __syncthreads();
        #pragma unroll
        for (int kk = 0; kk < 2; kk++){
            bf16x8 af = *(const bf16x8*)&xw[(wave*16+lm)*RSX + l0 + kk*32 + quad*8];
            #pragma unroll
            for (int nt = 0; nt < 8; nt++){
                bf16x8 bfr = *(const bf16x8*)&Bt[(nt*16+lm)*RSB + kk*32 + quad*8];
                acc[nt] = __builtin_amdgcn_mfma_f32_16x16x32_bf16(af, bfr, acc[nt], 0, 0, 0);
            }
        }
    }
    float* outp = states + ((size_t)((b*NC + c)*NHEADS + h))*(HD*DSTATE);
    #pragma unroll
    for (int nt = 0; nt < 8; nt++)
        #pragma unroll
        for (int r = 0; r < 4; r++)
            outp[(size_t)(wave*16 + quad*4 + r)*DSTATE + nt*16 + lm] = acc[nt][r];
}

// ------------- inter-chunk recurrence, 16-way split over (p,n) elements
__global__ __launch_bounds__(256) void prev_scan_k(const float* __restrict__ states,
                                                   const float* __restrict__ Acum,
                                                   float* __restrict__ prev){
    int bid = blockIdx.x;                  // B*NHEADS*16
    int part = bid & 15;
    int h = (bid >> 4) & (NHEADS-1);
    int b = bid >> 9;
    int tid = threadIdx.x;
    const float* AcB = Acum + ((size_t)(b*NHEADS + h))*SEQL;
    float dec[NC];
    #pragma unroll
    for (int c = 0; c < NC; c++) dec[c] = expf(AcB[c*CHUNK + CHUNK-1]);
    #pragma unroll
    for (int j = 0; j < 2; j++){
        int e = part*512 + j*256 + tid;
        float carry = 0.f;
        #pragma unroll
        for (int c = 0; c < NC; c++){
            size_t idx = ((size_t)((b*NC + c)*NHEADS + h))*(HD*DSTATE) + e;
            prev[idx] = carry;
            carry = carry*dec[c] + states[idx];
        }
    }
}

// ===== MFMA SSD output: Y = P@(dt*xs) + (e^A C)@prev^T + D*xs  -> bf16 Ybf
#define RLX 264
#define RLP 136
__global__ __launch_bounds__(256) void y_mfma_k(const ushort_t* __restrict__ convb,
                                                const ushort_t* __restrict__ G,
                                                const float* __restrict__ Acum,
                                                const float* __restrict__ dtH,
                                                const float* __restrict__ prev,
                                                const float* __restrict__ Dp,
                                                ushort_t* __restrict__ Ybf){
    __shared__ ushort_t xdtT[64*RLX];
    __shared__ ushort_t prevs[64*RLP];
    __shared__ float Acs[CHUNK];
    __shared__ float dts[CHUNK];
    int bid = blockIdx.x;
    int h = bid % NHEADS;
    int c = (bid / NHEADS) % NC;
    int b = bid / (NHEADS*NC);
    int tid = threadIdx.x;
    int lane = tid & 63, wave = tid >> 6;
    int lm = lane & 15, quad = lane >> 4;

    Acs[tid] = Acum[((size_t)(b*NHEADS + h))*SEQL + c*CHUNK + tid];
    dts[tid] = dtH[((size_t)(b*NHEADS + h))*SEQL + c*CHUNK + tid];
    {
        const float* pv = prev + ((size_t)((b*NC + c)*NHEADS + h))*(HD*DSTATE);
        #pragma unroll
        for (int i = 0; i < 32; i++){
            int e = tid + i*256; int p = e >> 7, n = e & 127;
            prevs[p*RLP + n] = f2b(pv[e]);
        }
    }
    __syncthreads();
    {
        const ushort_t* xg = convb + ((size_t)(b*SEQL + c*CHUNK))*CONVD + h*HD;
        #pragma unroll
        for (int j8 = 0; j8 < 8; j8++){
            int s0 = wave*64 + j8*8;
            bf16x8 pk;
            #pragma unroll
            for (int j = 0; j < 8; j++){
                int l = s0 + j;
                pk[j] = (short)f2b(b2f(xg[(size_t)l*CONVD + lane]) * dts[l]);
            }
            *(bf16x8*)&xdtT[lane*RLX + s0] = pk;
        }
    }
    __syncthreads();

    int   lrow[4];  float Alr[4], eAlr[4];
    #pragma unroll
    for (int mt = 0; mt < 4; mt++){
        lrow[mt] = (mt*4 + wave)*16 + lm;
        Alr[mt]  = Acs[lrow[mt]];
        eAlr[mt] = expf(Alr[mt]);
    }
    const ushort_t* Gbase = G + ((size_t)(b*NC + c))*(CHUNK*CHUNK);

    f32x4 acc[4][4];
    #pragma unroll
    for (int i=0;i<4;i++)
        #pragma unroll
        for (int j=0;j<4;j++) acc[i][j] = (f32x4){0.f,0.f,0.f,0.f};

    for (int ks = 0; ks < 8; ks++){
        bf16x8 bfr[4];
        #pragma unroll
        for (int nt = 0; nt < 4; nt++)
            bfr[nt] = *(const bf16x8*)&xdtT[(nt*16+lm)*RLX + ks*32 + quad*8];
        #pragma unroll
        for (int mt = 0; mt < 4; mt++){
            int rblk = mt*4 + wave;
            int nst = rblk/2 + 1;
            if (ks < nst){
                int sbase = ks*32 + quad*8;
                bf16x8 g8 = *(const bf16x8*)&Gbase[(size_t)lrow[mt]*CHUNK + sbase];
                const float4* A4 = (const float4*)(&Acs[sbase]);
                float4 a0 = A4[0], a1 = A4[1];
                float Al = Alr[mt]; int l = lrow[mt];
                float pv[8];
                pv[0] = (sbase+0 <= l) ? b2f((ushort_t)g8[0])*expf(Al - a0.x) : 0.f;
                pv[1] = (sbase+1 <= l) ? b2f((ushort_t)g8[1])*expf(Al - a0.y) : 0.f;
                pv[2] = (sbase+2 <= l) ? b2f((ushort_t)g8[2])*expf(Al - a0.z) : 0.f;
                pv[3] = (sbase+3 <= l) ? b2f((ushort_t)g8[3])*expf(Al - a0.w) : 0.f;
                pv[4] = (sbase+4 <= l) ? b2f((ushort_t)g8[4])*expf(Al - a1.x) : 0.f;
                pv[5] = (sbase+5 <= l) ? b2f((ushort_t)g8[5])*expf(Al - a1.y) : 0.f;
                pv[6] = (sbase+6 <= l) ? b2f((ushort_t)g8[6])*expf(Al - a1.z) : 0.f;
                pv[7] = (sbase+7 <= l) ? b2f((ushort_t)g8[7])*expf(Al - a1.w) : 0.f;
                bf16x8 af;
                #pragma unroll
                for (int j = 0; j < 8; j++) af[j] = (short)f2b(pv[j]);
                #pragma unroll
                for (int nt = 0; nt < 4; nt++)
                    acc[mt][nt] = __builtin_amdgcn_mfma_f32_16x16x32_bf16(af, bfr[nt], acc[mt][nt], 0, 0, 0);
            }
        }
    }
    for (int kc = 0; kc < 4; kc++){
        bf16x8 bfr[4];
        #pragma unroll
        for (int nt = 0; nt < 4; nt++)
            bfr[nt] = *(const bf16x8*)&prevs[(nt*16+lm)*RLP + kc*32 + quad*8];
        #pragma unroll
        for (int mt = 0; mt < 4; mt++){
            int rowg = b*SEQL + c*CHUNK + lrow[mt];
            bf16x8 c8 = *(const bf16x8*)&convb[(size_t)rowg*CONVD + DI + DSTATE + kc*32 + quad*8];
            float e = eAlr[mt];
            bf16x8 af;
            #pragma unroll
            for (int j = 0; j < 8; j++) af[j] = (short)f2b(e * b2f((ushort_t)c8[j]));
            #pragma unroll
            for (int nt = 0; nt < 4; nt++)
                acc[mt][nt] = __builtin_amdgcn_mfma_f32_16x16x32_bf16(af, bfr[nt], acc[mt][nt], 0, 0, 0);
        }
    }
    float Dv = Dp[h];
    #pragma unroll
    for (int mt = 0; mt < 4; mt++){
        int l0 = (mt*4 + wave)*16 + quad*4;
        #pragma unroll
        for (int nt = 0; nt < 4; nt++){
            int p = nt*16 + lm;
            #pragma unroll
            for (int r = 0; r < 4; r++){
                int rowg = b*SEQL + c*CHUNK + l0 + r;
                float xs = b2f(convb[(size_t)rowg*CONVD + h*HD + p]);
                Ybf[(size_t)rowg*DI + h*HD + p] = f2b(acc[mt][nt][r] + Dv*xs);
            }
        }
    }
}

// ------------------------------- y = Y*silu(z); RMSNorm; * rms_w ; -> bf16
__global__ __launch_bounds__(256) void gate_rms_k(const ushort_t* __restrict__ Yb,
                                                  const ushort_t* __restrict__ zx,
                                                  const float* __restrict__ rms_w,
                                                  ushort_t* __restrict__ yn){
    __shared__ float red[4];
    __shared__ float scale_s;
    int row = blockIdx.x; int tid = threadIdx.x;
    float v[8]; float ss = 0.f;
    #pragma unroll
    for (int i = 0; i < 8; i++){
        int d = tid + i*256;
        float g = b2f(Yb[(size_t)row*DI + d]) * silu_f(b2f(zx[(size_t)row*DPROJ + d]));
        v[i] = g; ss += g*g;
    }
    #pragma unroll
    for (int off = 32; off > 0; off >>= 1) ss += __shfl_down(ss, off);
    int lane = tid & 63, wid = tid >> 6;
    if (lane == 0) red[wid] = ss;
    __syncthreads();
    if (tid == 0) scale_s = rsqrtf((red[0]+red[1]+red[2]+red[3])*(1.f/DI) + 1e-12f);
    __syncthreads();
    float sc = scale_s;
    #pragma unroll
    for (int i = 0; i < 8; i++){
        int d = tid + i*256;
        yn[(size_t)row*DI + d] = f2b(v[i]*sc*rms_w[d]);
    }
}

// -------- LN(a + a2 + resid_f32) -> bf16 only (mid LN)
__global__ __launch_bounds__(256) void ln_hbf_k(const float* __restrict__ a,
                                                const float* __restrict__ a2,
                                                const float* __restrict__ resid,
                                                const float* __restrict__ g,
                                                const float* __restrict__ bw,
                                                ushort_t* __restrict__ bfout){
    __shared__ float redA[4], redB[4];
    __shared__ float mu_s, rs_s;
    int row = blockIdx.x; int tid = threadIdx.x;
    float u[4]; float s = 0.f, s2 = 0.f;
    #pragma unroll
    for (int i = 0; i < 4; i++){
        int d = tid + i*256;
        float val = a[(size_t)row*DM + d] + a2[(size_t)row*DM + d] + resid[(size_t)row*DM + d];
        u[i] = val; s += val; s2 += val*val;
    }
    #pragma unroll
    for (int off = 32; off > 0; off >>= 1){
        s  += __shfl_down(s,  off);
        s2 += __shfl_down(s2, off);
    }
    int lane = tid & 63, wid = tid >> 6;
    if (lane == 0){ redA[wid] = s; redB[wid] = s2; }
    __syncthreads();
    if (tid == 0){
        float S  = redA[0]+redA[1]+redA[2]+redA[3];
        float S2 = redB[0]+redB[1]+redB[2]+redB[3];
        float mu = S*(1.f/DM);
        float var = S2*(1.f/DM) - mu*mu;
        mu_s = mu; rs_s = rsqrtf(var + 1e-12f);
    }
    __syncthreads();
    float mu = mu_s, rs = rs_s;
    #pragma unroll
    for (int i = 0; i < 4; i++){
        int d = tid + i*256;
        bfout[(size_t)row*DM + d] = f2b((u[i]-mu)*rs*g[d] + bw[d]);
    }
}

// -------- final LN(a + a2 + resid_bf16) -> fp32 d_out; extra blocks copy td
__global__ __launch_bounds__(256) void ln_final_k(const float* __restrict__ a,
                                                  const float* __restrict__ a2,
                                                  const ushort_t* __restrict__ residb,
                                                  const float* __restrict__ g,
                                                  const float* __restrict__ bw,
                                                  float* __restrict__ outp,
                                                  const float* __restrict__ td){
    __shared__ float redA[4], redB[4];
    __shared__ float mu_s, rs_s;
    int row = blockIdx.x; int tid = threadIdx.x;
    if (row >= ROWS){
        int idx = (row - ROWS)*256 + tid;
        outp[(size_t)ROWS*DM + idx] = td[idx];
        return;
    }
    float u[4]; float s = 0.f, s2 = 0.f;
    #pragma unroll
    for (int i = 0; i < 4; i++){
        int d = tid + i*256;
        float val = a[(size_t)row*DM + d] + a2[(size_t)row*DM + d] + b2f(residb[(size_t)row*DM + d]);
        u[i] = val; s += val; s2 += val*val;
    }
    #pragma unroll
    for (int off = 32; off > 0; off >>= 1){
        s  += __shfl_down(s,  off);
        s2 += __shfl_down(s2, off);
    }
    int lane = tid & 63, wid = tid >> 6;
    if (lane == 0){ redA[wid] = s; redB[wid] = s2; }
    __syncthreads();
    if (tid == 0){
        float S  = redA[0]+redA[1]+redA[2]+redA[3];
        float S2 = redB[0]+redB[1]+redB[2]+redB[3];
        float mu = S*(1.f/DM);
        float var = S2*(1.f/DM) - mu*mu;
        mu_s = mu; rs_s = rsqrtf(var + 1e-12f);
    }
    __syncthreads();
    float mu = mu_s, rs = rs_s;
    #pragma unroll
    for (int i = 0; i < 4; i++){
        int d = tid + i*256;
        outp[(size_t)row*DM + d] = (u[i]-mu)*rs*g[d] + bw[d];
    }
}

extern "C" void kernel_launch(void* const* d_in, const int* in_sizes, int n_in,
                              void* d_out, int out_size, void* d_ws, size_t ws_size,
                              hipStream_t stream){
    const float* x         = (const float*)d_in[0];
    const float* time_diff = (const float*)d_in[1];
    const float* W_in      = (const float*)d_in[2];
    const float* b_in      = (const float*)d_in[3];
    const float* conv_w    = (const float*)d_in[4];
    const float* conv_b    = (const float*)d_in[5];
    const float* A_log     = (const float*)d_in[6];
    const float* dt_bias   = (const float*)d_in[7];
    const float* Dp        = (const float*)d_in[8];
    const float* time_dec  = (const float*)d_in[9];
    const float* rms_w     = (const float*)d_in[10];
    const float* W_out     = (const float*)d_in[11];
    const float* b_out     = (const float*)d_in[12];
    const float* ln_g      = (const float*)d_in[13];
    const float* ln_b      = (const float*)d_in[14];
    const float* fc1_w     = (const float*)d_in[15];
    const float* fc1_b     = (const float*)d_in[16];
    const float* fc2_w     = (const float*)d_in[17];
    const float* fc2_b     = (const float*)d_in[18];
    const float* ln2_g     = (const float*)d_in[19];
    const float* ln2_b     = (const float*)d_in[20];

    float* ws = (float*)d_ws;
    float* zx    = ws;                       // region1: 17,956,864 f
    float* convb = zx    + 17956864;         // region2:  9,437,184 f
    float* dtH   = convb + 9437184;
    float* Acum  = dtH   + 131072;
    float* r4    = Acum  + 131072;           // region4:  8,388,608 f
    float* r5    = r4    + 8388608;          // region5:  9,437,184 f
    float* ybreg = r5    + 9437184;          // region6:  4,194,304 f
    // region1 aliases
    ushort_t* zx_bf  = (ushort_t*)zx;                 // steps 2-8
    float*    dtaux  = zx + 10600000;                 // steps 2-3
    ushort_t* mid_bf = (ushort_t*)zx;                 // steps 12-13 (zx dead)
    ushort_t* h_bf   = (ushort_t*)(zx + 8388608);     // steps 11-14 (zx dead)
    // region2 aliases
    ushort_t* convb_bf = (ushort_t*)convb;            // steps 3-7
    float* outPa  = convb;                            // steps 10-11 (convb dead)
    // region4 aliases
    ushort_t* x_bf  = (ushort_t*)r4;                  // steps 1-2
    ushort_t* WinT  = (ushort_t*)(r4 + 2097152);      // steps 1-2
    ushort_t* WoutT = (ushort_t*)(r4 + 4194304);      // steps 9-10
    float* fc2Pa = r4;                                // steps 13-14
    // region5 aliases
    ushort_t* Gb   = (ushort_t*)r5;                   // steps 4-7
    float* stat = r5 + 1048576;                       // steps 5-6
    float* prev = stat + 4194304;                     // steps 6-7
    ushort_t* yn_bf = (ushort_t*)r5;                  // steps 8-10 (G/stat dead)
    ushort_t* fc1T  = (ushort_t*)(r5 + 4194304);      // steps 9-12 (stat/prev dead)
    ushort_t* fc2T  = (ushort_t*)(r5 + 6291456);      // steps 9-13 (prev dead)
    // region6
    ushort_t* Ybf = (ushort_t*)ybreg;                 // steps 7-8
    float* outp   = (float*)d_out;

    // 1. f2b(x) + W_in^T (merged)
    prep_in_k<<<16384 + 4480, 256, 0, stream>>>(x, x_bf, W_in, WinT);
    // 2. in-proj (M=4096,N=4384,K=1024) -> bf16 zx + fp32 dt sidecar
    mfma_gemm_k<0,1,128,1,1><<<dim3(35, ROWS/128), 256, 0, stream>>>(x_bf, WinT, b_in, nullptr, zx_bf, dtaux, ROWS, DPROJ, DM, DPROJ);
    // 3. conv+SiLU -> bf16 convb, merged with dt/dA/cumsum scan
    conv_dt_k<<<CONVBLKS + BATCH*NHEADS*NC, 256, 0, stream>>>(zx_bf, conv_w, conv_b, convb_bf,
                                                              dtaux, time_diff, A_log, dt_bias, time_dec, dtH, Acum);
    // 4. G = C @ B^T (MFMA, bf16)
    g_mfma_k<<<dim3(4,4,BATCH*NC), 256, 0, stream>>>(convb_bf, Gb);
    // 5. per-chunk states (MFMA, xdt derived in staging)
    states_mfma_k<<<BATCH*NC*NHEADS, 256, 0, stream>>>(convb_bf, dtH, Acum, stat);
    // 6. inter-chunk scan (1024 blocks)
    prev_scan_k<<<BATCH*NHEADS*16, 256, 0, stream>>>(stat, Acum, prev);
    // 7. MFMA SSD output -> bf16 Y
    y_mfma_k<<<BATCH*NC*NHEADS, 256, 0, stream>>>(convb_bf, Gb, Acum, dtH, prev, Dp, Ybf);
    // 8. gate + RMSNorm -> bf16 yn
    gate_rms_k<<<ROWS, 256, 0, stream>>>(Ybf, zx_bf, rms_w, yn_bf);
    // 9. W_out / fc1 / fc2 transposes (merged)
    transpose3_k<<<10240, 256, 0, stream>>>(W_out, fc1_w, fc2_w, WoutT, fc1T, fc2T);
    // 10. out-proj split-K=2 (M=4096,N=1024,K=2048)
    mfma_gemm_k<0,0,64,2,0><<<dim3(DM/64, ROWS/128, 2), 256, 0, stream>>>(yn_bf, WoutT, b_out, outPa, nullptr, nullptr, ROWS, DM, DI, DM);
    // 11. h = LN(Pa + Pb + x) -> bf16 only
    ln_hbf_k<<<ROWS, 256, 0, stream>>>(outPa, outPa + (size_t)ROWS*DM, x, ln_g, ln_b, h_bf);
    // 12. fc1 + hardswish -> bf16 mid (M=4096,N=4096,K=1024)
    mfma_gemm_k<1,1,128,1,0><<<dim3(DFF/128, ROWS/128), 256, 0, stream>>>(h_bf, fc1T, fc1_b, nullptr, mid_bf, nullptr, ROWS, DFF, DM, DFF);
    // 13. fc2 split-K=2 (M=4096,N=1024,K=4096)
    mfma_gemm_k<0,0,64,2,0><<<dim3(DM/64, ROWS/128, 2), 256, 0, stream>>>(mid_bf, fc2T, fc2_b, fc2Pa, nullptr, nullptr, ROWS, DM, DFF, DM);
    // 14. out = LN(Pa + Pb + h_bf) + td passthrough (merged)
    ln_final_k<<<ROWS + ROWS/256, 256, 0, stream>>>(fc2Pa, fc2Pa + (size_t)ROWS*DM, h_bf, ln2_g, ln2_b, outp, time_diff);
}